// Round 2
// baseline (1868.839 us; speedup 1.0000x reference)
//
#include <hip/hip_runtime.h>
#include <hip/hip_bf16.h>
#include <math.h>

// Dims: L=2048 N=4 E=1024 H=16 D=128 HD=64; 2D=256; M=L*N=8192
// Reference's .view(-1,L,2D) scramble: phi's natural flat (l,n,h,d) order IS the
// (b,l',d) view, so flat indexing reproduces it exactly. v: b*64 = n*1024+h*64 (checked).
// Chunked causal linear attention: CHK=256, NC=8.

typedef __hip_bfloat16 bf16;

__global__ __launch_bounds__(256) void gemm_nt_f32(
    const float* __restrict__ A, const float* __restrict__ B,
    const float* __restrict__ bias, float* __restrict__ C)
{
    // C[m][n] = sum_k A[m][k]*B[n][k] + bias[n]; K = 1024
    __shared__ float As[16][132];
    __shared__ float Bs[16][132];
    const int t  = threadIdx.x;
    const int m0 = blockIdx.x * 128;
    const int n0 = blockIdx.y * 128;
    const int tx = t & 15, ty = t >> 4;

    float acc[8][8];
#pragma unroll
    for (int i = 0; i < 8; ++i)
#pragma unroll
        for (int j = 0; j < 8; ++j) acc[i][j] = 0.f;

    for (int k0 = 0; k0 < 1024; k0 += 16) {
#pragma unroll
        for (int i = 0; i < 2; ++i) {
            const int lin = t + i * 256;
            const int row = lin >> 2, kq = lin & 3;
            const float4 a = *reinterpret_cast<const float4*>(&A[(size_t)(m0 + row) * 1024 + k0 + kq * 4]);
            const float4 b = *reinterpret_cast<const float4*>(&B[(size_t)(n0 + row) * 1024 + k0 + kq * 4]);
            As[kq*4+0][row] = a.x; As[kq*4+1][row] = a.y; As[kq*4+2][row] = a.z; As[kq*4+3][row] = a.w;
            Bs[kq*4+0][row] = b.x; Bs[kq*4+1][row] = b.y; Bs[kq*4+2][row] = b.z; Bs[kq*4+3][row] = b.w;
        }
        __syncthreads();
#pragma unroll
        for (int k = 0; k < 16; ++k) {
            float ar[8], br[8];
            *reinterpret_cast<float4*>(&ar[0]) = *reinterpret_cast<const float4*>(&As[k][ty*8]);
            *reinterpret_cast<float4*>(&ar[4]) = *reinterpret_cast<const float4*>(&As[k][ty*8+4]);
            *reinterpret_cast<float4*>(&br[0]) = *reinterpret_cast<const float4*>(&Bs[k][tx*8]);
            *reinterpret_cast<float4*>(&br[4]) = *reinterpret_cast<const float4*>(&Bs[k][tx*8+4]);
#pragma unroll
            for (int i = 0; i < 8; ++i)
#pragma unroll
                for (int j = 0; j < 8; ++j) acc[i][j] += ar[i] * br[j];
        }
        __syncthreads();
    }
#pragma unroll
    for (int i = 0; i < 8; ++i) {
        const int m = m0 + ty*8 + i;
#pragma unroll
        for (int j = 0; j < 8; ++j)
            C[(size_t)m*1024 + n0 + tx*8 + j] = acc[i][j] + bias[n0 + tx*8 + j];
    }
}

__global__ __launch_bounds__(256) void rand_project(
    const float* __restrict__ X, const float* __restrict__ RM, bf16* __restrict__ PHI)
{
    // X: (8192,1024); head h = cols h*64..; normalize row-slice, xt = xn@rm[h]^T (128)
    // PHI[(row*16+h)*256 + d] = exp(xt)/16 ; +128+d = exp(-xt)/16   (bf16)
    __shared__ float Xs[64][68];
    __shared__ float RMs[128][68];
    __shared__ float rsc[64];
    const int h  = blockIdx.x;
    const int r0 = blockIdx.y * 64;
    const int t  = threadIdx.x;
#pragma unroll
    for (int i = 0; i < 16; ++i) {
        const int lin = t + i*256;                // 64 rows x 64 cols
        const int r = lin >> 6, c = lin & 63;
        Xs[r][c] = X[(size_t)(r0 + r)*1024 + h*64 + c];
    }
#pragma unroll
    for (int i = 0; i < 32; ++i) {
        const int lin = t + i*256;                // 128 d x 64 c
        const int d = lin >> 6, c = lin & 63;
        RMs[d][c] = RM[((size_t)h*128 + d)*64 + c];
    }
    __syncthreads();
    if (t < 64) {
        float s = 0.f;
#pragma unroll
        for (int c = 0; c < 64; ++c) { const float v = Xs[t][c]; s += v*v; }
        rsc[t] = 1.f / fmaxf(sqrtf(s), 1e-12f);
    }
    __syncthreads();
    const int rr = (t >> 4) * 4;
    const int dc = t & 15;
    float acc[4][8];
#pragma unroll
    for (int i = 0; i < 4; ++i)
#pragma unroll
        for (int j = 0; j < 8; ++j) acc[i][j] = 0.f;
    for (int c = 0; c < 64; c += 4) {
        float4 xv[4], rv[8];
#pragma unroll
        for (int i = 0; i < 4; ++i) xv[i] = *reinterpret_cast<const float4*>(&Xs[rr+i][c]);
#pragma unroll
        for (int j = 0; j < 8; ++j) rv[j] = *reinterpret_cast<const float4*>(&RMs[dc + 16*j][c]);
#pragma unroll
        for (int i = 0; i < 4; ++i)
#pragma unroll
            for (int j = 0; j < 8; ++j)
                acc[i][j] += xv[i].x*rv[j].x + xv[i].y*rv[j].y + xv[i].z*rv[j].z + xv[i].w*rv[j].w;
    }
#pragma unroll
    for (int i = 0; i < 4; ++i) {
        const float sc = rsc[rr + i];
        const size_t base = ((size_t)(r0 + rr + i)*16 + h)*256;
#pragma unroll
        for (int j = 0; j < 8; ++j) {
            const float xt = acc[i][j] * sc;
            const int d = dc + 16*j;
            PHI[base + d]       = __float2bfloat16(0.0625f * expf(xt));
            PHI[base + 128 + d] = __float2bfloat16(0.0625f * expf(-xt));
        }
    }
}

__global__ __launch_bounds__(256) void chunk_state(
    const bf16* __restrict__ PHIK, const float* __restrict__ VP, float* __restrict__ ST)
{
    // Per (b, chunk c of 256): KV[d][h] = sum_r K[r][d]*V[r][h]; z[d] = sum_r K[r][d]
    __shared__ float Vs[128][64];
    const int b = blockIdx.x, c = blockIdx.y;     // c in 0..7
    const int t = threadIdx.x;                    // t = d
    float acc[64];
#pragma unroll
    for (int hh = 0; hh < 64; ++hh) acc[hh] = 0.f;
    float zacc = 0.f;
    for (int half = 0; half < 2; ++half) {
        __syncthreads();
#pragma unroll
        for (int i = 0; i < 32; ++i) {
            const int lin = t + i*256;            // 128 x 64
            const int r = lin >> 6, hd = lin & 63;
            Vs[r][hd] = VP[(size_t)(c*256 + half*128 + r)*4096 + b*64 + hd];
        }
        __syncthreads();
        const bf16* pk = PHIK + ((size_t)b*2048 + c*256 + half*128)*256 + t;
        for (int r = 0; r < 128; ++r) {
            const float kk = __bfloat162float(pk[(size_t)r*256]);
            zacc += kk;
#pragma unroll
            for (int hh = 0; hh < 64; hh += 4) {
                const float4 v4 = *reinterpret_cast<const float4*>(&Vs[r][hh]);
                acc[hh+0] += kk*v4.x; acc[hh+1] += kk*v4.y; acc[hh+2] += kk*v4.z; acc[hh+3] += kk*v4.w;
            }
        }
    }
    float* st = ST + (size_t)(b*8 + c)*16640;
#pragma unroll
    for (int hh = 0; hh < 64; hh += 4) {
        float4 o; o.x = acc[hh]; o.y = acc[hh+1]; o.z = acc[hh+2]; o.w = acc[hh+3];
        *reinterpret_cast<float4*>(&st[(size_t)t*64 + hh]) = o;
    }
    st[16384 + t] = zacc;
}

__global__ void prefix_scan(float* __restrict__ ST)
{
    // exclusive prefix over the 8 chunks, per b
    const int b = blockIdx.x;
    const int t = threadIdx.x;
    for (int e = t; e < 16640; e += 256) {
        const size_t base = (size_t)b*8*16640 + e;
        float run = 0.f;
#pragma unroll
        for (int c = 0; c < 8; ++c) {
            const float v = ST[base + (size_t)c*16640];
            ST[base + (size_t)c*16640] = run;
            run += v;
        }
    }
}

__global__ __launch_bounds__(256) void inter_chunk(
    const bf16* __restrict__ PHIQ, const float* __restrict__ ST,
    float* __restrict__ ANUM, float* __restrict__ DEN)
{
    // 128-row block rb; chunk c = rb>>1 (intra covers the rest of the 256 tile)
    __shared__ float Qst[32][132];
    __shared__ float Ssb[32][64];
    __shared__ float zb[32];
    const int b = blockIdx.x, rb = blockIdx.y;
    const int t = threadIdx.x;
    const int tx = t & 15, ty = t >> 4;
    float acc[8][4];
    float dacc[8];
#pragma unroll
    for (int i = 0; i < 8; ++i) { dacc[i] = 0.f;
#pragma unroll
        for (int j = 0; j < 4; ++j) acc[i][j] = 0.f; }
    const float* stb  = ST + (size_t)(b*8 + (rb >> 1))*16640;
    const bf16* phiq = PHIQ + ((size_t)b*2048 + (size_t)rb*128)*256;
    for (int db = 0; db < 8; ++db) {
        __syncthreads();
#pragma unroll
        for (int i = 0; i < 16; ++i) {
            const int lin = t + i*256;            // 128 rows x 32 d
            const int r = lin >> 5, dd = lin & 31;
            Qst[dd][r] = __bfloat162float(phiq[(size_t)r*256 + db*32 + dd]);
        }
#pragma unroll
        for (int i = 0; i < 8; ++i) {
            const int lin = t + i*256;            // 32 d x 64 h
            const int dd = lin >> 6, hh = lin & 63;
            Ssb[dd][hh] = stb[(size_t)(db*32 + dd)*64 + hh];
        }
        if (t < 32) zb[t] = stb[16384 + db*32 + t];
        __syncthreads();
#pragma unroll
        for (int d = 0; d < 32; ++d) {
            float q[8];
            *reinterpret_cast<float4*>(&q[0]) = *reinterpret_cast<const float4*>(&Qst[d][ty*8]);
            *reinterpret_cast<float4*>(&q[4]) = *reinterpret_cast<const float4*>(&Qst[d][ty*8+4]);
            const float4 s4 = *reinterpret_cast<const float4*>(&Ssb[d][tx*4]);
#pragma unroll
            for (int i = 0; i < 8; ++i) {
                acc[i][0] += q[i]*s4.x; acc[i][1] += q[i]*s4.y;
                acc[i][2] += q[i]*s4.z; acc[i][3] += q[i]*s4.w;
            }
            if (tx == 0) {
                const float z = zb[d];
#pragma unroll
                for (int i = 0; i < 8; ++i) dacc[i] += q[i]*z;
            }
        }
    }
#pragma unroll
    for (int i = 0; i < 8; ++i) {
        const int row = rb*128 + ty*8 + i;
        float4 o; o.x = acc[i][0]; o.y = acc[i][1]; o.z = acc[i][2]; o.w = acc[i][3];
        *reinterpret_cast<float4*>(&ANUM[((size_t)b*2048 + row)*64 + tx*4]) = o;
        if (tx == 0) DEN[(size_t)b*2048 + row] = dacc[i];
    }
}

__global__ __launch_bounds__(256) void intra_chunk(
    const bf16* __restrict__ PHIQ, const bf16* __restrict__ PHIK,
    const float* __restrict__ VP, float* __restrict__ ANUM, float* __restrict__ DEN)
{
    // 256x256 causal tile as 10 sub-blocks of 64x64: s -> (ri, rj), rj <= ri
    __shared__ float sm[8768];
    float* Qst  = sm;                             // [32][68]
    float* Kst  = sm + 2176;                      // [32][68]
    float* Ps   = sm + 4352;                      // [64][68]
    float* Vs   = sm;                             // [64][64] (reuses Qst/Kst)
    float* denl = sm + 8704;                      // [64]
    const int b = blockIdx.x, c = blockIdx.y, s = blockIdx.z;
    const int ri = (s >= 6) ? 3 : ((s >= 3) ? 2 : ((s >= 1) ? 1 : 0));
    const int rj = s - (ri*(ri+1))/2;
    const bool diag = (ri == rj);
    const int rbase = ri*64, jbase = rj*64;
    const int t = threadIdx.x;
    const int tx = t & 15, ty = t >> 4;
    float p[4][4];
#pragma unroll
    for (int i = 0; i < 4; ++i)
#pragma unroll
        for (int j = 0; j < 4; ++j) p[i][j] = 0.f;
    const bf16* phiq = PHIQ + ((size_t)b*2048 + (size_t)c*256 + rbase)*256;
    const bf16* phik = PHIK + ((size_t)b*2048 + (size_t)c*256 + jbase)*256;
    for (int db = 0; db < 8; ++db) {
        __syncthreads();
#pragma unroll
        for (int i = 0; i < 8; ++i) {
            const int lin = t + i*256;            // 64 rows x 32 d
            const int r = lin >> 5, dd = lin & 31;
            Qst[dd*68 + r] = __bfloat162float(phiq[(size_t)r*256 + db*32 + dd]);
            Kst[dd*68 + r] = __bfloat162float(phik[(size_t)r*256 + db*32 + dd]);
        }
        __syncthreads();
#pragma unroll
        for (int d = 0; d < 32; ++d) {
            const float4 q4 = *reinterpret_cast<const float4*>(&Qst[d*68 + ty*4]);
            const float4 k4 = *reinterpret_cast<const float4*>(&Kst[d*68 + tx*4]);
            p[0][0] += q4.x*k4.x; p[0][1] += q4.x*k4.y; p[0][2] += q4.x*k4.z; p[0][3] += q4.x*k4.w;
            p[1][0] += q4.y*k4.x; p[1][1] += q4.y*k4.y; p[1][2] += q4.y*k4.z; p[1][3] += q4.y*k4.w;
            p[2][0] += q4.z*k4.x; p[2][1] += q4.z*k4.y; p[2][2] += q4.z*k4.z; p[2][3] += q4.z*k4.w;
            p[3][0] += q4.w*k4.x; p[3][1] += q4.w*k4.y; p[3][2] += q4.w*k4.z; p[3][3] += q4.w*k4.w;
        }
    }
    if (t < 64) denl[t] = 0.f;
    __syncthreads();
    float rs[4] = {0.f, 0.f, 0.f, 0.f};
#pragma unroll
    for (int i = 0; i < 4; ++i) {
#pragma unroll
        for (int j = 0; j < 4; ++j) {
            if (diag && (tx*4 + j) > (ty*4 + i)) p[i][j] = 0.f;
            rs[i] += p[i][j];
        }
    }
#pragma unroll
    for (int i = 0; i < 4; ++i) atomicAdd(&denl[ty*4 + i], rs[i]);
#pragma unroll
    for (int i = 0; i < 4; ++i) {
        float4 o; o.x = p[i][0]; o.y = p[i][1]; o.z = p[i][2]; o.w = p[i][3];
        *reinterpret_cast<float4*>(&Ps[(ty*4+i)*68 + tx*4]) = o;
    }
#pragma unroll
    for (int i = 0; i < 16; ++i) {
        const int lin = t + i*256;                // 64 x 64
        const int r = lin >> 6, hd = lin & 63;
        Vs[r*64 + hd] = VP[(size_t)(c*256 + jbase + r)*4096 + b*64 + hd];
    }
    __syncthreads();
    float o4[4][4];
#pragma unroll
    for (int i = 0; i < 4; ++i)
#pragma unroll
        for (int j = 0; j < 4; ++j) o4[i][j] = 0.f;
    for (int jb = 0; jb < 64; jb += 4) {
        float4 v4[4];
#pragma unroll
        for (int jj = 0; jj < 4; ++jj) v4[jj] = *reinterpret_cast<const float4*>(&Vs[(jb+jj)*64 + tx*4]);
#pragma unroll
        for (int i = 0; i < 4; ++i) {
            const float4 p4 = *reinterpret_cast<const float4*>(&Ps[(ty*4+i)*68 + jb]);
            o4[i][0] += p4.x*v4[0].x + p4.y*v4[1].x + p4.z*v4[2].x + p4.w*v4[3].x;
            o4[i][1] += p4.x*v4[0].y + p4.y*v4[1].y + p4.z*v4[2].y + p4.w*v4[3].y;
            o4[i][2] += p4.x*v4[0].z + p4.y*v4[1].z + p4.z*v4[2].z + p4.w*v4[3].z;
            o4[i][3] += p4.x*v4[0].w + p4.y*v4[1].w + p4.z*v4[2].w + p4.w*v4[3].w;
        }
    }
#pragma unroll
    for (int i = 0; i < 4; ++i) {
        const int row = c*256 + rbase + ty*4 + i;
#pragma unroll
        for (int j = 0; j < 4; ++j)
            atomicAdd(&ANUM[((size_t)b*2048 + row)*64 + tx*4 + j], o4[i][j]);
    }
    if (t < 64) atomicAdd(&DEN[(size_t)b*2048 + c*256 + rbase + t], denl[t]);
}

__global__ void finalize_attn(const float* __restrict__ ANUM,
        const float* __restrict__ DEN, float* __restrict__ ATT)
{
    // ANUM[b][i][hd]/(DEN[b][i]+eps) -> ATT[i*4096 + b*64 + hd]
    const size_t idx = ((size_t)blockIdx.x * 256 + threadIdx.x) * 4;
    const int hd = (int)(idx & 63);
    const size_t bi = idx >> 6;                   // b*2048 + i
    const int i = (int)(bi & 2047);
    const int b = (int)(bi >> 11);
    const float4 nm = *reinterpret_cast<const float4*>(&ANUM[idx]);
    const float inv = 1.f / (DEN[bi] + 1e-6f);
    float4 o; o.x = nm.x*inv; o.y = nm.y*inv; o.z = nm.z*inv; o.w = nm.w*inv;
    *reinterpret_cast<float4*>(&ATT[(size_t)i*4096 + b*64 + hd]) = o;
}

extern "C" void kernel_launch(void* const* d_in, const int* in_sizes, int n_in,
                              void* d_out, int out_size, void* d_ws, size_t ws_size,
                              hipStream_t stream)
{
    const float* query = (const float*)d_in[0];
    const float* key   = (const float*)d_in[1];
    const float* value = (const float*)d_in[2];
    const float* wq    = (const float*)d_in[3];
    const float* bq    = (const float*)d_in[4];
    const float* wk    = (const float*)d_in[5];
    const float* bk    = (const float*)d_in[6];
    const float* wv    = (const float*)d_in[7];
    const float* bv    = (const float*)d_in[8];
    const float* wo    = (const float*)d_in[9];
    const float* bo    = (const float*)d_in[10];
    const float* rm    = (const float*)d_in[11];
    float* out = (float*)d_out;

    // Workspace layout (225 MiB total):
    char* base = (char*)d_ws;
    float* vp   = (float*)(base);                 //  33,554,432 B
    bf16*  phiq = (bf16*)(base +  33554432);      //  67,108,864 B
    bf16*  phik = (bf16*)(base + 100663296);      //  67,108,864 B
    float* st   = (float*)(base + 167772160);     //  34,078,720 B
    float* den  = (float*)(base + 201850880);     //     524,288 B
    float* tmp  = (float*)(base + 202375168);     //  33,554,432 B  (end 235,929,600)
    float* anum = tmp;
    float* attn = st;   // st dead after inter_chunk; overlay

    const dim3 blk(256);
    gemm_nt_f32<<<dim3(64, 8), blk, 0, stream>>>(query, wq, bq, tmp);
    rand_project<<<dim3(16, 128), blk, 0, stream>>>(tmp, rm, phiq);
    gemm_nt_f32<<<dim3(64, 8), blk, 0, stream>>>(key,   wk, bk, tmp);
    rand_project<<<dim3(16, 128), blk, 0, stream>>>(tmp, rm, phik);
    gemm_nt_f32<<<dim3(64, 8), blk, 0, stream>>>(value, wv, bv, vp);
    chunk_state<<<dim3(64, 8), blk, 0, stream>>>(phik, vp, st);
    prefix_scan<<<dim3(64), blk, 0, stream>>>(st);
    inter_chunk<<<dim3(64, 16), blk, 0, stream>>>(phiq, st, anum, den);
    intra_chunk<<<dim3(64, 8, 10), blk, 0, stream>>>(phiq, phik, vp, anum, den);
    finalize_attn<<<dim3(8192), blk, 0, stream>>>(anum, den, attn);
    gemm_nt_f32<<<dim3(64, 8), blk, 0, stream>>>(attn, wo, bo, out);
}

// Round 3
// 1234.904 us; speedup vs baseline: 1.5133x; 1.5133x over previous
//
#include <hip/hip_runtime.h>
#include <math.h>

// Dims: L=2048 N=4 E=1024 H=16 D=128 HD=64; 2D=256; M=L*N=8192; B=64
// phi natural (l,n,h,d) flat order == reference's scrambled (b,l',d) view.
// V/attn row mapping: flat l*4096 + b*64 + hd == (l*4+n)*1024 + h*64 + hd for b=n*16+h.
// Chunked causal: CHK=256, NC=8. All heavy matmuls on MFMA bf16.

typedef unsigned short u16;
typedef unsigned int u32;
using f32x4v = __attribute__((ext_vector_type(4))) float;
using s16x8  = __attribute__((ext_vector_type(8))) short;

__device__ __forceinline__ float bf2f(u16 u) { return __uint_as_float(((u32)u) << 16); }
__device__ __forceinline__ u16 f2bf(float x) {
    u32 b = __float_as_uint(x);
    b += 0x7fff + ((b >> 16) & 1);          // RNE
    return (u16)(b >> 16);
}

// ---------------------------------------------------------------------------
// NT GEMM: C[m][n] = sum_k A[m][k]*B[n][k] + bias[n]; M=8192, N=1024, K=1024
// 128x128 tile, 4 waves (2x2), 16 frags of 16x16x32 bf16 per wave.
// LDS [row][32k] bf16, 16B-slot XOR swizzle slot^=((row>>1)&3) -> 2-way (free).
template<bool ABF16, bool OBF16>
__global__ __launch_bounds__(256) void gemm_mfma(
    const void* __restrict__ Ap, const float* __restrict__ Bw,
    const float* __restrict__ bias, void* __restrict__ Cp)
{
    __shared__ __align__(16) u16 As[4096];
    __shared__ __align__(16) u16 Bs[4096];
    const int t = threadIdx.x;
    const int m0 = blockIdx.x * 128, n0 = blockIdx.y * 128;
    const int wid = t >> 6, lane = t & 63;
    const int wr = wid >> 1, wc = wid & 1;

    f32x4v acc[4][4];
#pragma unroll
    for (int i = 0; i < 4; ++i)
#pragma unroll
        for (int j = 0; j < 4; ++j)
#pragma unroll
            for (int e = 0; e < 4; ++e) acc[i][j][e] = 0.f;

    const int srow = t >> 1;
    const int scol = (t & 1) * 16;
    const int sx   = (srow >> 1) & 3;
    const int sl0  = (t & 1) * 2;
    u16* wa0 = &As[srow * 32 + (((sl0    ) ^ sx)) * 8];
    u16* wa1 = &As[srow * 32 + (((sl0 + 1) ^ sx)) * 8];
    u16* wb0 = &Bs[srow * 32 + (((sl0    ) ^ sx)) * 8];
    u16* wb1 = &Bs[srow * 32 + (((sl0 + 1) ^ sx)) * 8];

    for (int k0 = 0; k0 < 1024; k0 += 32) {
        __syncthreads();
        {
            u16 ta[16];
            if (ABF16) {
                const u16* src = (const u16*)Ap + (size_t)(m0 + srow) * 1024 + k0 + scol;
                *(uint4*)&ta[0] = *(const uint4*)src;
                *(uint4*)&ta[8] = *(const uint4*)(src + 8);
            } else {
                const float* src = (const float*)Ap + (size_t)(m0 + srow) * 1024 + k0 + scol;
#pragma unroll
                for (int q = 0; q < 4; ++q) {
                    const float4 v = *(const float4*)(src + q * 4);
                    ta[q*4+0] = f2bf(v.x); ta[q*4+1] = f2bf(v.y);
                    ta[q*4+2] = f2bf(v.z); ta[q*4+3] = f2bf(v.w);
                }
            }
            *(uint4*)wa0 = *(const uint4*)&ta[0];
            *(uint4*)wa1 = *(const uint4*)&ta[8];
        }
        {
            const float* src = Bw + (size_t)(n0 + srow) * 1024 + k0 + scol;
            u16 tb[16];
#pragma unroll
            for (int q = 0; q < 4; ++q) {
                const float4 v = *(const float4*)(src + q * 4);
                tb[q*4+0] = f2bf(v.x); tb[q*4+1] = f2bf(v.y);
                tb[q*4+2] = f2bf(v.z); tb[q*4+3] = f2bf(v.w);
            }
            *(uint4*)wb0 = *(const uint4*)&tb[0];
            *(uint4*)wb1 = *(const uint4*)&tb[8];
        }
        __syncthreads();
        s16x8 af[4], bfr[4];
#pragma unroll
        for (int fi = 0; fi < 4; ++fi) {
            const int r  = wr * 64 + fi * 16 + (lane & 15);
            const int sl = (lane >> 4) ^ ((r >> 1) & 3);
            af[fi] = *(const s16x8*)&As[r * 32 + sl * 8];
        }
#pragma unroll
        for (int fj = 0; fj < 4; ++fj) {
            const int r  = wc * 64 + fj * 16 + (lane & 15);
            const int sl = (lane >> 4) ^ ((r >> 1) & 3);
            bfr[fj] = *(const s16x8*)&Bs[r * 32 + sl * 8];
        }
#pragma unroll
        for (int fi = 0; fi < 4; ++fi)
#pragma unroll
            for (int fj = 0; fj < 4; ++fj)
                acc[fi][fj] = __builtin_amdgcn_mfma_f32_16x16x32_bf16(af[fi], bfr[fj], acc[fi][fj], 0, 0, 0);
    }

    const int rl = (lane >> 4) * 4, cl = lane & 15;
    float bvals[4];
#pragma unroll
    for (int fj = 0; fj < 4; ++fj) bvals[fj] = bias[n0 + wc * 64 + fj * 16 + cl];
#pragma unroll
    for (int fi = 0; fi < 4; ++fi)
#pragma unroll
        for (int j = 0; j < 4; ++j) {
            const size_t m = m0 + wr * 64 + fi * 16 + rl + j;
#pragma unroll
            for (int fj = 0; fj < 4; ++fj) {
                const int n = n0 + wc * 64 + fj * 16 + cl;
                const float v = acc[fi][fj][j] + bvals[fj];
                if (OBF16) ((u16*)Cp)[m * 1024 + n] = f2bf(v);
                else       ((float*)Cp)[m * 1024 + n] = v;
            }
        }
}

// ---------------------------------------------------------------------------
__global__ __launch_bounds__(256) void rand_project(
    const float* __restrict__ X, const float* __restrict__ RM, u16* __restrict__ PHI)
{
    __shared__ float Xs[64][68];
    __shared__ float RMs[128][68];
    __shared__ float rsc[64];
    const int h  = blockIdx.x;
    const int r0 = blockIdx.y * 64;
    const int t  = threadIdx.x;
#pragma unroll
    for (int i = 0; i < 16; ++i) {
        const int lin = t + i * 256;
        const int r = lin >> 6, c = lin & 63;
        Xs[r][c] = X[(size_t)(r0 + r) * 1024 + h * 64 + c];
    }
#pragma unroll
    for (int i = 0; i < 32; ++i) {
        const int lin = t + i * 256;
        const int d = lin >> 6, c = lin & 63;
        RMs[d][c] = RM[((size_t)h * 128 + d) * 64 + c];
    }
    __syncthreads();
    if (t < 64) {
        float s = 0.f;
#pragma unroll
        for (int c = 0; c < 64; ++c) { const float v = Xs[t][c]; s += v * v; }
        rsc[t] = 1.f / fmaxf(sqrtf(s), 1e-12f);
    }
    __syncthreads();
    const int rr = (t >> 4) * 4;
    const int dc = t & 15;
    float acc[4][8];
#pragma unroll
    for (int i = 0; i < 4; ++i)
#pragma unroll
        for (int j = 0; j < 8; ++j) acc[i][j] = 0.f;
    for (int c = 0; c < 64; c += 4) {
        float4 xv[4], rv[8];
#pragma unroll
        for (int i = 0; i < 4; ++i) xv[i] = *(const float4*)&Xs[rr + i][c];
#pragma unroll
        for (int j = 0; j < 8; ++j) rv[j] = *(const float4*)&RMs[dc + 16 * j][c];
#pragma unroll
        for (int i = 0; i < 4; ++i)
#pragma unroll
            for (int j = 0; j < 8; ++j)
                acc[i][j] += xv[i].x*rv[j].x + xv[i].y*rv[j].y + xv[i].z*rv[j].z + xv[i].w*rv[j].w;
    }
#pragma unroll
    for (int i = 0; i < 4; ++i) {
        const float sc = rsc[rr + i];
        const size_t base = ((size_t)(r0 + rr + i) * 16 + h) * 256;
#pragma unroll
        for (int j = 0; j < 8; ++j) {
            const float xt = acc[i][j] * sc;
            const int d = dc + 16 * j;
            PHI[base + d]       = f2bf(0.0625f * expf(xt));
            PHI[base + 128 + d] = f2bf(0.0625f * expf(-xt));
        }
    }
}

// ---------------------------------------------------------------------------
// ST layout (h-major): per (b,c): st[h*256 + d] (h<64), z at st[16384 + d]
__global__ __launch_bounds__(256) void chunk_state(
    const u16* __restrict__ PHIK, const u16* __restrict__ VP, float* __restrict__ ST)
{
    __shared__ float Vs[128][64];
    const int b = blockIdx.x, c = blockIdx.y;
    const int t = threadIdx.x;                    // t = d
    float acc[64];
#pragma unroll
    for (int hh = 0; hh < 64; ++hh) acc[hh] = 0.f;
    float zacc = 0.f;
    for (int half = 0; half < 2; ++half) {
        __syncthreads();
#pragma unroll
        for (int i = 0; i < 32; ++i) {
            const int lin = t + i * 256;
            const int r = lin >> 6, hd = lin & 63;
            Vs[r][hd] = bf2f(VP[(size_t)(c * 256 + half * 128 + r) * 4096 + b * 64 + hd]);
        }
        __syncthreads();
        const u16* pk = PHIK + ((size_t)b * 2048 + c * 256 + half * 128) * 256 + t;
        for (int r = 0; r < 128; ++r) {
            const float kk = bf2f(pk[(size_t)r * 256]);
            zacc += kk;
#pragma unroll
            for (int hh = 0; hh < 64; hh += 4) {
                const float4 v4 = *(const float4*)&Vs[r][hh];
                acc[hh+0] += kk * v4.x; acc[hh+1] += kk * v4.y;
                acc[hh+2] += kk * v4.z; acc[hh+3] += kk * v4.w;
            }
        }
    }
    float* st = ST + (size_t)(b * 8 + c) * 16640;
#pragma unroll
    for (int hh = 0; hh < 64; ++hh) st[(size_t)hh * 256 + t] = acc[hh];
    st[16384 + t] = zacc;
}

// ---------------------------------------------------------------------------
__global__ void prefix_scan(float* __restrict__ ST, u16* __restrict__ STBF)
{
    const int b = blockIdx.x;
    const int t = threadIdx.x;
    for (int e = t; e < 16640; e += 256) {
        const size_t base = (size_t)b * 8 * 16640 + e;
        float run = 0.f;
#pragma unroll
        for (int c = 0; c < 8; ++c) {
            const float v = ST[base + (size_t)c * 16640];
            ST[base + (size_t)c * 16640] = run;
            if (e < 16384) STBF[(size_t)(b * 8 + c) * 16384 + e] = f2bf(run);
            run += v;
        }
    }
}

// ---------------------------------------------------------------------------
// ANUM[b][r][h] = PhiQ[r][:] . S_start[:][h] (MFMA); DEN[b][r] = PhiQ[r][:] . z
__global__ __launch_bounds__(256) void inter_mfma(
    const u16* __restrict__ PHIQ, const u16* __restrict__ STBF,
    const float* __restrict__ ST, float* __restrict__ ANUM, float* __restrict__ DEN)
{
    __shared__ __align__(16) u16 Qs[4096];
    __shared__ __align__(16) u16 Ss[2048];
    __shared__ float Zs[32];
    __shared__ float dred[128];
    const int b = blockIdx.x, rb = blockIdx.y;
    const int c = rb >> 1;
    const int t = threadIdx.x;
    const int wid = t >> 6, lane = t & 63;
    const int wr = wid >> 1, wc = wid & 1;

    f32x4v acc[4][2];
#pragma unroll
    for (int i = 0; i < 4; ++i)
#pragma unroll
        for (int j = 0; j < 2; ++j)
#pragma unroll
            for (int e = 0; e < 4; ++e) acc[i][j][e] = 0.f;
    float dacc = 0.f;

    const u16* phiq = PHIQ + ((size_t)b * 2048 + (size_t)rb * 128) * 256;
    const u16* stb  = STBF + (size_t)(b * 8 + c) * 16384;
    const float* zb = ST + (size_t)(b * 8 + c) * 16640 + 16384;
    const int drow = t & 127, dhalf = t >> 7;
    const int srow = t >> 1;
    const int sx   = (srow >> 1) & 3;
    const int sl0  = (t & 1) * 2;

    for (int d0 = 0; d0 < 256; d0 += 32) {
        __syncthreads();
        {
            const u16* src = phiq + (size_t)srow * 256 + d0 + (t & 1) * 16;
            const uint4 v0 = *(const uint4*)src;
            const uint4 v1 = *(const uint4*)(src + 8);
            *(uint4*)&Qs[srow * 32 + ((sl0     ^ sx)) * 8] = v0;
            *(uint4*)&Qs[srow * 32 + (((sl0+1) ^ sx)) * 8] = v1;
        }
        if (t < 128) {
            const u16* src = stb + (size_t)srow * 256 + d0 + (t & 1) * 16;
            const uint4 v0 = *(const uint4*)src;
            const uint4 v1 = *(const uint4*)(src + 8);
            *(uint4*)&Ss[srow * 32 + ((sl0     ^ sx)) * 8] = v0;
            *(uint4*)&Ss[srow * 32 + (((sl0+1) ^ sx)) * 8] = v1;
        }
        if (t < 32) Zs[t] = zb[d0 + t];
        __syncthreads();
        s16x8 af[4], bfr[2];
#pragma unroll
        for (int fi = 0; fi < 4; ++fi) {
            const int r  = wr * 64 + fi * 16 + (lane & 15);
            const int sl = (lane >> 4) ^ ((r >> 1) & 3);
            af[fi] = *(const s16x8*)&Qs[r * 32 + sl * 8];
        }
#pragma unroll
        for (int fj = 0; fj < 2; ++fj) {
            const int r  = wc * 32 + fj * 16 + (lane & 15);
            const int sl = (lane >> 4) ^ ((r >> 1) & 3);
            bfr[fj] = *(const s16x8*)&Ss[r * 32 + sl * 8];
        }
#pragma unroll
        for (int fi = 0; fi < 4; ++fi)
#pragma unroll
            for (int fj = 0; fj < 2; ++fj)
                acc[fi][fj] = __builtin_amdgcn_mfma_f32_16x16x32_bf16(af[fi], bfr[fj], acc[fi][fj], 0, 0, 0);
        // den partial: row drow, d-halves
#pragma unroll
        for (int s2 = 0; s2 < 2; ++s2) {
            const int sl  = dhalf * 2 + s2;
            const int adr = drow * 32 + ((sl ^ ((drow >> 1) & 3))) * 8;
#pragma unroll
            for (int e = 0; e < 8; ++e)
                dacc += bf2f(Qs[adr + e]) * Zs[sl * 8 + e];
        }
    }
    __syncthreads();
    if (t >= 128) dred[t - 128] = dacc;
    __syncthreads();
    if (t < 128) DEN[(size_t)b * 2048 + rb * 128 + t] = dacc + dred[t];

    const int rl = (lane >> 4) * 4, cl = lane & 15;
#pragma unroll
    for (int fi = 0; fi < 4; ++fi)
#pragma unroll
        for (int j = 0; j < 4; ++j) {
            const int row = rb * 128 + wr * 64 + fi * 16 + rl + j;
#pragma unroll
            for (int fj = 0; fj < 2; ++fj) {
                const int col = wc * 32 + fj * 16 + cl;
                ANUM[((size_t)b * 2048 + row) * 64 + col] = acc[fi][fj][j];
            }
        }
}

// ---------------------------------------------------------------------------
// Intra-chunk causal part. Block (b, c, zi): zi=0 -> ri {0,3}, zi=1 -> ri {1,2}.
// Accumulates PV in registers across rj (no global ANUM atomics), writes ANUM2.
__global__ __launch_bounds__(256) void intra_chunk(
    const u16* __restrict__ PHIQ, const u16* __restrict__ PHIK,
    const u16* __restrict__ VP, float* __restrict__ ANUM2, float* __restrict__ DEN)
{
    __shared__ float sm[8704];
    float* Qst = sm;            // [32][68]
    float* Kst = sm + 2176;     // [32][68]
    float* Ps  = sm + 4352;     // [64][68]
    float* Vs  = sm;            // [64][64], overlaps Qst/Kst
    const int b = blockIdx.x, c = blockIdx.y;
    const int t = threadIdx.x;
    const int tx = t & 15, ty = t >> 4;

#pragma unroll
    for (int rii = 0; rii < 2; ++rii) {
        const int ri = (blockIdx.z == 0) ? (rii ? 3 : 0) : (rii ? 2 : 1);
        float o4[4][4];
        float denacc[4] = {0.f, 0.f, 0.f, 0.f};
#pragma unroll
        for (int i = 0; i < 4; ++i)
#pragma unroll
            for (int j = 0; j < 4; ++j) o4[i][j] = 0.f;

        for (int rj = 0; rj <= ri; ++rj) {
            const bool diag = (rj == ri);
            float p[4][4];
#pragma unroll
            for (int i = 0; i < 4; ++i)
#pragma unroll
                for (int j = 0; j < 4; ++j) p[i][j] = 0.f;
            const u16* phiq = PHIQ + ((size_t)b * 2048 + c * 256 + ri * 64) * 256;
            const u16* phik = PHIK + ((size_t)b * 2048 + c * 256 + rj * 64) * 256;
            for (int db = 0; db < 8; ++db) {
                __syncthreads();
#pragma unroll
                for (int i = 0; i < 8; ++i) {
                    const int lin = t + i * 256;
                    const int r = lin >> 5, dd = lin & 31;
                    Qst[dd * 68 + r] = bf2f(phiq[(size_t)r * 256 + db * 32 + dd]);
                    Kst[dd * 68 + r] = bf2f(phik[(size_t)r * 256 + db * 32 + dd]);
                }
                __syncthreads();
#pragma unroll
                for (int d = 0; d < 32; ++d) {
                    const float4 q4 = *(const float4*)&Qst[d * 68 + ty * 4];
                    const float4 k4 = *(const float4*)&Kst[d * 68 + tx * 4];
                    p[0][0] += q4.x*k4.x; p[0][1] += q4.x*k4.y; p[0][2] += q4.x*k4.z; p[0][3] += q4.x*k4.w;
                    p[1][0] += q4.y*k4.x; p[1][1] += q4.y*k4.y; p[1][2] += q4.y*k4.z; p[1][3] += q4.y*k4.w;
                    p[2][0] += q4.z*k4.x; p[2][1] += q4.z*k4.y; p[2][2] += q4.z*k4.z; p[2][3] += q4.z*k4.w;
                    p[3][0] += q4.w*k4.x; p[3][1] += q4.w*k4.y; p[3][2] += q4.w*k4.z; p[3][3] += q4.w*k4.w;
                }
            }
            // mask + row-sum, reduce over tx via shfl (lanes grouped by 16)
            float rs[4] = {0.f, 0.f, 0.f, 0.f};
#pragma unroll
            for (int i = 0; i < 4; ++i)
#pragma unroll
                for (int j = 0; j < 4; ++j) {
                    if (diag && (tx * 4 + j) > (ty * 4 + i)) p[i][j] = 0.f;
                    rs[i] += p[i][j];
                }
#pragma unroll
            for (int off = 1; off < 16; off <<= 1)
#pragma unroll
                for (int i = 0; i < 4; ++i) rs[i] += __shfl_xor(rs[i], off, 16);
#pragma unroll
            for (int i = 0; i < 4; ++i) denacc[i] += rs[i];
            // stage P
#pragma unroll
            for (int i = 0; i < 4; ++i) {
                float4 o; o.x = p[i][0]; o.y = p[i][1]; o.z = p[i][2]; o.w = p[i][3];
                *(float4*)&Ps[(ty * 4 + i) * 68 + tx * 4] = o;
            }
            __syncthreads();
            // stage V (overlaps Qst/Kst)
#pragma unroll
            for (int i = 0; i < 16; ++i) {
                const int lin = t + i * 256;
                const int r = lin >> 6, hd = lin & 63;
                Vs[r * 64 + hd] = bf2f(VP[(size_t)(c * 256 + rj * 64 + r) * 4096 + b * 64 + hd]);
            }
            __syncthreads();
            for (int jb = 0; jb < 64; jb += 4) {
                float4 v4[4];
#pragma unroll
                for (int jj = 0; jj < 4; ++jj) v4[jj] = *(const float4*)&Vs[(jb + jj) * 64 + tx * 4];
#pragma unroll
                for (int i = 0; i < 4; ++i) {
                    const float4 p4 = *(const float4*)&Ps[(ty * 4 + i) * 68 + jb];
                    o4[i][0] += p4.x*v4[0].x + p4.y*v4[1].x + p4.z*v4[2].x + p4.w*v4[3].x;
                    o4[i][1] += p4.x*v4[0].y + p4.y*v4[1].y + p4.z*v4[2].y + p4.w*v4[3].y;
                    o4[i][2] += p4.x*v4[0].z + p4.y*v4[1].z + p4.z*v4[2].z + p4.w*v4[3].z;
                    o4[i][3] += p4.x*v4[0].w + p4.y*v4[1].w + p4.z*v4[2].w + p4.w*v4[3].w;
                }
            }
            __syncthreads();
        }
        // write per-ri results
#pragma unroll
        for (int i = 0; i < 4; ++i) {
            const int row = c * 256 + ri * 64 + ty * 4 + i;
            float4 o; o.x = o4[i][0]; o.y = o4[i][1]; o.z = o4[i][2]; o.w = o4[i][3];
            *(float4*)&ANUM2[((size_t)b * 2048 + row) * 64 + tx * 4] = o;
        }
        if (tx == 0) {
#pragma unroll
            for (int i = 0; i < 4; ++i)
                atomicAdd(&DEN[(size_t)b * 2048 + c * 256 + ri * 64 + ty * 4 + i], denacc[i]);
        }
    }
}

// ---------------------------------------------------------------------------
__global__ void finalize_attn(const float* __restrict__ ANUM, const float* __restrict__ ANUM2,
        const float* __restrict__ DEN, u16* __restrict__ ATT)
{
    const size_t idx = ((size_t)blockIdx.x * 256 + threadIdx.x) * 4;
    const int hd = (int)(idx & 63);
    const size_t bi = idx >> 6;                   // b*2048 + i
    const int i = (int)(bi & 2047);
    const int b = (int)(bi >> 11);
    const float4 n1 = *(const float4*)&ANUM[idx];
    const float4 n2 = *(const float4*)&ANUM2[idx];
    const float inv = 1.f / (DEN[bi] + 1e-6f);
    const u32 p0 = (u32)f2bf((n1.x + n2.x) * inv) | ((u32)f2bf((n1.y + n2.y) * inv) << 16);
    const u32 p1 = (u32)f2bf((n1.z + n2.z) * inv) | ((u32)f2bf((n1.w + n2.w) * inv) << 16);
    uint2 o; o.x = p0; o.y = p1;
    *(uint2*)&ATT[(size_t)i * 4096 + b * 64 + hd] = o;
}

// ---------------------------------------------------------------------------
extern "C" void kernel_launch(void* const* d_in, const int* in_sizes, int n_in,
                              void* d_out, int out_size, void* d_ws, size_t ws_size,
                              hipStream_t stream)
{
    const float* query = (const float*)d_in[0];
    const float* key   = (const float*)d_in[1];
    const float* value = (const float*)d_in[2];
    const float* wq    = (const float*)d_in[3];
    const float* bq    = (const float*)d_in[4];
    const float* wk    = (const float*)d_in[5];
    const float* bk    = (const float*)d_in[6];
    const float* wv    = (const float*)d_in[7];
    const float* bv    = (const float*)d_in[8];
    const float* wo    = (const float*)d_in[9];
    const float* bo    = (const float*)d_in[10];
    const float* rm    = (const float*)d_in[11];
    float* out = (float*)d_out;

    // Workspace (total 235,929,600 B == round-2-proven size):
    char* base = (char*)d_ws;
    u16*   vp   = (u16*)(base);                   //  16,777,216 B  (V proj, bf16)
    u16*   phiq = (u16*)(base +  16777216);       //  67,108,864 B
    u16*   phik = (u16*)(base +  83886080);       //  67,108,864 B
    float* st   = (float*)(base + 150994944);     //  34,078,720 B  (-> anum2 overlay)
    u16*   stbf = (u16*)(base + 185073664);       //  16,777,216 B  (-> attn bf16 overlay)
    float* den  = (float*)(base + 201850880);     //     524,288 B
    float* tmp  = (float*)(base + 202375168);     //  33,554,432 B  (q/k proj; anum)
    float* anum  = tmp;
    float* anum2 = st;
    u16*   attn  = stbf;

    const dim3 blk(256);
    gemm_mfma<false, false><<<dim3(64, 8), blk, 0, stream>>>(query, wq, bq, tmp);
    rand_project<<<dim3(16, 128), blk, 0, stream>>>(tmp, rm, phiq);
    gemm_mfma<false, false><<<dim3(64, 8), blk, 0, stream>>>(key, wk, bk, tmp);
    rand_project<<<dim3(16, 128), blk, 0, stream>>>(tmp, rm, phik);
    gemm_mfma<false, true><<<dim3(64, 8), blk, 0, stream>>>(value, wv, bv, vp);
    chunk_state<<<dim3(64, 8), blk, 0, stream>>>(phik, vp, st);
    prefix_scan<<<dim3(64), blk, 0, stream>>>(st, stbf);
    inter_mfma<<<dim3(64, 16), blk, 0, stream>>>(phiq, stbf, st, anum, den);
    intra_chunk<<<dim3(64, 8, 2), blk, 0, stream>>>(phiq, phik, vp, anum2, den);
    finalize_attn<<<dim3(8192), blk, 0, stream>>>(anum, anum2, den, attn);
    gemm_mfma<true, false><<<dim3(64, 8), blk, 0, stream>>>(attn, wo, bo, out);
}

// Round 4
// 706.613 us; speedup vs baseline: 2.6448x; 1.7476x over previous
//
#include <hip/hip_runtime.h>
#include <math.h>

// Dims: L=2048 N=4 E=1024 H=16 D=128 HD=64; 2D=256; M=L*N=8192; B=64
// phi natural (l,n,h,d) flat order == reference's scrambled (b,l',d) view.
// V/attn row mapping: flat l*4096 + b*64 + hd == (l*4+n)*1024 + h*64 + hd for b=n*16+h.
// Chunked causal: CHK=256, NC=8. All heavy matmuls on MFMA bf16.

typedef unsigned short u16;
typedef unsigned int u32;
using f32x4v = __attribute__((ext_vector_type(4))) float;
using s16x8  = __attribute__((ext_vector_type(8))) short;

__device__ __forceinline__ float bf2f(u16 u) { return __uint_as_float(((u32)u) << 16); }
__device__ __forceinline__ u16 f2bf(float x) {
    u32 b = __float_as_uint(x);
    b += 0x7fff + ((b >> 16) & 1);          // RNE
    return (u16)(b >> 16);
}

// ---------------------------------------------------------------------------
// NT GEMM: C[m][n] = sum_k A[m][k]*B[n][k] + bias[n]; M=8192, N=1024, K=1024
template<bool ABF16, bool OBF16>
__global__ __launch_bounds__(256) void gemm_mfma(
    const void* __restrict__ Ap, const float* __restrict__ Bw,
    const float* __restrict__ bias, void* __restrict__ Cp)
{
    __shared__ __align__(16) u16 As[4096];
    __shared__ __align__(16) u16 Bs[4096];
    const int t = threadIdx.x;
    const int m0 = blockIdx.x * 128, n0 = blockIdx.y * 128;
    const int wid = t >> 6, lane = t & 63;
    const int wr = wid >> 1, wc = wid & 1;

    f32x4v acc[4][4];
#pragma unroll
    for (int i = 0; i < 4; ++i)
#pragma unroll
        for (int j = 0; j < 4; ++j)
#pragma unroll
            for (int e = 0; e < 4; ++e) acc[i][j][e] = 0.f;

    const int srow = t >> 1;
    const int scol = (t & 1) * 16;
    const int sx   = (srow >> 1) & 3;
    const int sl0  = (t & 1) * 2;
    u16* wa0 = &As[srow * 32 + (((sl0    ) ^ sx)) * 8];
    u16* wa1 = &As[srow * 32 + (((sl0 + 1) ^ sx)) * 8];
    u16* wb0 = &Bs[srow * 32 + (((sl0    ) ^ sx)) * 8];
    u16* wb1 = &Bs[srow * 32 + (((sl0 + 1) ^ sx)) * 8];

    for (int k0 = 0; k0 < 1024; k0 += 32) {
        __syncthreads();
        {
            u16 ta[16];
            if (ABF16) {
                const u16* src = (const u16*)Ap + (size_t)(m0 + srow) * 1024 + k0 + scol;
                *(uint4*)&ta[0] = *(const uint4*)src;
                *(uint4*)&ta[8] = *(const uint4*)(src + 8);
            } else {
                const float* src = (const float*)Ap + (size_t)(m0 + srow) * 1024 + k0 + scol;
#pragma unroll
                for (int q = 0; q < 4; ++q) {
                    const float4 v = *(const float4*)(src + q * 4);
                    ta[q*4+0] = f2bf(v.x); ta[q*4+1] = f2bf(v.y);
                    ta[q*4+2] = f2bf(v.z); ta[q*4+3] = f2bf(v.w);
                }
            }
            *(uint4*)wa0 = *(const uint4*)&ta[0];
            *(uint4*)wa1 = *(const uint4*)&ta[8];
        }
        {
            const float* src = Bw + (size_t)(n0 + srow) * 1024 + k0 + scol;
            u16 tb[16];
#pragma unroll
            for (int q = 0; q < 4; ++q) {
                const float4 v = *(const float4*)(src + q * 4);
                tb[q*4+0] = f2bf(v.x); tb[q*4+1] = f2bf(v.y);
                tb[q*4+2] = f2bf(v.z); tb[q*4+3] = f2bf(v.w);
            }
            *(uint4*)wb0 = *(const uint4*)&tb[0];
            *(uint4*)wb1 = *(const uint4*)&tb[8];
        }
        __syncthreads();
        s16x8 af[4], bfr[4];
#pragma unroll
        for (int fi = 0; fi < 4; ++fi) {
            const int r  = wr * 64 + fi * 16 + (lane & 15);
            const int sl = (lane >> 4) ^ ((r >> 1) & 3);
            af[fi] = *(const s16x8*)&As[r * 32 + sl * 8];
        }
#pragma unroll
        for (int fj = 0; fj < 4; ++fj) {
            const int r  = wc * 64 + fj * 16 + (lane & 15);
            const int sl = (lane >> 4) ^ ((r >> 1) & 3);
            bfr[fj] = *(const s16x8*)&Bs[r * 32 + sl * 8];
        }
#pragma unroll
        for (int fi = 0; fi < 4; ++fi)
#pragma unroll
            for (int fj = 0; fj < 4; ++fj)
                acc[fi][fj] = __builtin_amdgcn_mfma_f32_16x16x32_bf16(af[fi], bfr[fj], acc[fi][fj], 0, 0, 0);
    }

    const int rl = (lane >> 4) * 4, cl = lane & 15;
    float bvals[4];
#pragma unroll
    for (int fj = 0; fj < 4; ++fj) bvals[fj] = bias[n0 + wc * 64 + fj * 16 + cl];
#pragma unroll
    for (int fi = 0; fi < 4; ++fi)
#pragma unroll
        for (int j = 0; j < 4; ++j) {
            const size_t m = m0 + wr * 64 + fi * 16 + rl + j;
#pragma unroll
            for (int fj = 0; fj < 4; ++fj) {
                const int n = n0 + wc * 64 + fj * 16 + cl;
                const float v = acc[fi][fj][j] + bvals[fj];
                if (OBF16) ((u16*)Cp)[m * 1024 + n] = f2bf(v);
                else       ((float*)Cp)[m * 1024 + n] = v;
            }
        }
}

// ---------------------------------------------------------------------------
__global__ __launch_bounds__(256) void rand_project(
    const float* __restrict__ X, const float* __restrict__ RM, u16* __restrict__ PHI)
{
    __shared__ float Xs[64][68];
    __shared__ float RMs[128][68];
    __shared__ float rsc[64];
    const int h  = blockIdx.x;
    const int r0 = blockIdx.y * 64;
    const int t  = threadIdx.x;
#pragma unroll
    for (int i = 0; i < 16; ++i) {
        const int lin = t + i * 256;
        const int r = lin >> 6, c = lin & 63;
        Xs[r][c] = X[(size_t)(r0 + r) * 1024 + h * 64 + c];
    }
#pragma unroll
    for (int i = 0; i < 32; ++i) {
        const int lin = t + i * 256;
        const int d = lin >> 6, c = lin & 63;
        RMs[d][c] = RM[((size_t)h * 128 + d) * 64 + c];
    }
    __syncthreads();
    if (t < 64) {
        float s = 0.f;
#pragma unroll
        for (int c = 0; c < 64; ++c) { const float v = Xs[t][c]; s += v * v; }
        rsc[t] = 1.f / fmaxf(sqrtf(s), 1e-12f);
    }
    __syncthreads();
    const int rr = (t >> 4) * 4;
    const int dc = t & 15;
    float acc[4][8];
#pragma unroll
    for (int i = 0; i < 4; ++i)
#pragma unroll
        for (int j = 0; j < 8; ++j) acc[i][j] = 0.f;
    for (int c = 0; c < 64; c += 4) {
        float4 xv[4], rv[8];
#pragma unroll
        for (int i = 0; i < 4; ++i) xv[i] = *(const float4*)&Xs[rr + i][c];
#pragma unroll
        for (int j = 0; j < 8; ++j) rv[j] = *(const float4*)&RMs[dc + 16 * j][c];
#pragma unroll
        for (int i = 0; i < 4; ++i)
#pragma unroll
            for (int j = 0; j < 8; ++j)
                acc[i][j] += xv[i].x*rv[j].x + xv[i].y*rv[j].y + xv[i].z*rv[j].z + xv[i].w*rv[j].w;
    }
#pragma unroll
    for (int i = 0; i < 4; ++i) {
        const float sc = rsc[rr + i];
        const size_t base = ((size_t)(r0 + rr + i) * 16 + h) * 256;
#pragma unroll
        for (int j = 0; j < 8; ++j) {
            const float xt = acc[i][j] * sc;
            const int d = dc + 16 * j;
            PHI[base + d]       = f2bf(0.0625f * expf(xt));
            PHI[base + 128 + d] = f2bf(0.0625f * expf(-xt));
        }
    }
}

// ---------------------------------------------------------------------------
// ST layout (h-major): per (b,c): st[h*256 + d] (h<64), z at st[16384 + d]
__global__ __launch_bounds__(256) void chunk_state(
    const u16* __restrict__ PHIK, const u16* __restrict__ VP, float* __restrict__ ST)
{
    __shared__ float Vs[128][64];
    const int b = blockIdx.x, c = blockIdx.y;
    const int t = threadIdx.x;                    // t = d
    float acc[64];
#pragma unroll
    for (int hh = 0; hh < 64; ++hh) acc[hh] = 0.f;
    float zacc = 0.f;
    for (int half = 0; half < 2; ++half) {
        __syncthreads();
#pragma unroll
        for (int i = 0; i < 32; ++i) {
            const int lin = t + i * 256;
            const int r = lin >> 6, hd = lin & 63;
            Vs[r][hd] = bf2f(VP[(size_t)(c * 256 + half * 128 + r) * 4096 + b * 64 + hd]);
        }
        __syncthreads();
        const u16* pk = PHIK + ((size_t)b * 2048 + c * 256 + half * 128) * 256 + t;
        for (int r = 0; r < 128; ++r) {
            const float kk = bf2f(pk[(size_t)r * 256]);
            zacc += kk;
#pragma unroll
            for (int hh = 0; hh < 64; hh += 4) {
                const float4 v4 = *(const float4*)&Vs[r][hh];
                acc[hh+0] += kk * v4.x; acc[hh+1] += kk * v4.y;
                acc[hh+2] += kk * v4.z; acc[hh+3] += kk * v4.w;
            }
        }
    }
    float* st = ST + (size_t)(b * 8 + c) * 16640;
#pragma unroll
    for (int hh = 0; hh < 64; ++hh) st[(size_t)hh * 256 + t] = acc[hh];
    st[16384 + t] = zacc;
}

// ---------------------------------------------------------------------------
__global__ void prefix_scan(float* __restrict__ ST, u16* __restrict__ STBF)
{
    const int b = blockIdx.x;
    const int t = threadIdx.x;
    for (int e = t; e < 16640; e += 256) {
        const size_t base = (size_t)b * 8 * 16640 + e;
        float run = 0.f;
#pragma unroll
        for (int c = 0; c < 8; ++c) {
            const float v = ST[base + (size_t)c * 16640];
            ST[base + (size_t)c * 16640] = run;
            if (e < 16384) STBF[(size_t)(b * 8 + c) * 16384 + e] = f2bf(run);
            run += v;
        }
    }
}

// ---------------------------------------------------------------------------
// ANUM[b][r][h] = PhiQ[r][:] . S_start[:][h] (MFMA); DEN[b][r] = PhiQ[r][:] . z
__global__ __launch_bounds__(256) void inter_mfma(
    const u16* __restrict__ PHIQ, const u16* __restrict__ STBF,
    const float* __restrict__ ST, float* __restrict__ ANUM, float* __restrict__ DEN)
{
    __shared__ __align__(16) u16 Qs[4096];
    __shared__ __align__(16) u16 Ss[2048];
    __shared__ float Zs[32];
    __shared__ float dred[128];
    const int b = blockIdx.x, rb = blockIdx.y;
    const int c = rb >> 1;
    const int t = threadIdx.x;
    const int wid = t >> 6, lane = t & 63;
    const int wr = wid >> 1, wc = wid & 1;

    f32x4v acc[4][2];
#pragma unroll
    for (int i = 0; i < 4; ++i)
#pragma unroll
        for (int j = 0; j < 2; ++j)
#pragma unroll
            for (int e = 0; e < 4; ++e) acc[i][j][e] = 0.f;
    float dacc = 0.f;

    const u16* phiq = PHIQ + ((size_t)b * 2048 + (size_t)rb * 128) * 256;
    const u16* stb  = STBF + (size_t)(b * 8 + c) * 16384;
    const float* zb = ST + (size_t)(b * 8 + c) * 16640 + 16384;
    const int drow = t & 127, dhalf = t >> 7;
    const int srow = t >> 1;
    const int sx   = (srow >> 1) & 3;
    const int sl0  = (t & 1) * 2;

    for (int d0 = 0; d0 < 256; d0 += 32) {
        __syncthreads();
        {
            const u16* src = phiq + (size_t)srow * 256 + d0 + (t & 1) * 16;
            const uint4 v0 = *(const uint4*)src;
            const uint4 v1 = *(const uint4*)(src + 8);
            *(uint4*)&Qs[srow * 32 + ((sl0     ^ sx)) * 8] = v0;
            *(uint4*)&Qs[srow * 32 + (((sl0+1) ^ sx)) * 8] = v1;
        }
        if (t < 128) {
            const u16* src = stb + (size_t)srow * 256 + d0 + (t & 1) * 16;
            const uint4 v0 = *(const uint4*)src;
            const uint4 v1 = *(const uint4*)(src + 8);
            *(uint4*)&Ss[srow * 32 + ((sl0     ^ sx)) * 8] = v0;
            *(uint4*)&Ss[srow * 32 + (((sl0+1) ^ sx)) * 8] = v1;
        }
        if (t < 32) Zs[t] = zb[d0 + t];
        __syncthreads();
        s16x8 af[4], bfr[2];
#pragma unroll
        for (int fi = 0; fi < 4; ++fi) {
            const int r  = wr * 64 + fi * 16 + (lane & 15);
            const int sl = (lane >> 4) ^ ((r >> 1) & 3);
            af[fi] = *(const s16x8*)&Qs[r * 32 + sl * 8];
        }
#pragma unroll
        for (int fj = 0; fj < 2; ++fj) {
            const int r  = wc * 32 + fj * 16 + (lane & 15);
            const int sl = (lane >> 4) ^ ((r >> 1) & 3);
            bfr[fj] = *(const s16x8*)&Ss[r * 32 + sl * 8];
        }
#pragma unroll
        for (int fi = 0; fi < 4; ++fi)
#pragma unroll
            for (int fj = 0; fj < 2; ++fj)
                acc[fi][fj] = __builtin_amdgcn_mfma_f32_16x16x32_bf16(af[fi], bfr[fj], acc[fi][fj], 0, 0, 0);
#pragma unroll
        for (int s2 = 0; s2 < 2; ++s2) {
            const int sl  = dhalf * 2 + s2;
            const int adr = drow * 32 + ((sl ^ ((drow >> 1) & 3))) * 8;
#pragma unroll
            for (int e = 0; e < 8; ++e)
                dacc += bf2f(Qs[adr + e]) * Zs[sl * 8 + e];
        }
    }
    __syncthreads();
    if (t >= 128) dred[t - 128] = dacc;
    __syncthreads();
    if (t < 128) DEN[(size_t)b * 2048 + rb * 128 + t] = dacc + dred[t];

    const int rl = (lane >> 4) * 4, cl = lane & 15;
#pragma unroll
    for (int fi = 0; fi < 4; ++fi)
#pragma unroll
        for (int j = 0; j < 4; ++j) {
            const int row = rb * 128 + wr * 64 + fi * 16 + rl + j;
#pragma unroll
            for (int fj = 0; fj < 2; ++fj) {
                const int col = wc * 32 + fj * 16 + cl;
                ANUM[((size_t)b * 2048 + row) * 64 + col] = acc[fi][fj][j];
            }
        }
}

// ---------------------------------------------------------------------------
// Intra-chunk causal, MFMA flash-style. Block=(b,c); wave ri owns rows ri*64..+64.
// For rj<=ri: P=Phiq*Phik^T (MFMA), mask, rowsum->den (shfl), P->bf16->P_lds,
// O += P*V (MFMA, V transposed+swizzled in LDS). Epilogue fuses finalize:
// attn = (ANUM_inter + O) / (DEN_inter + den_intra + eps), bf16.
__global__ __launch_bounds__(256) void intra_mfma(
    const u16* __restrict__ PHIQ, const u16* __restrict__ PHIK,
    const u16* __restrict__ VP, const float* __restrict__ ANUM,
    const float* __restrict__ DEN, u16* __restrict__ ATT)
{
    __shared__ __align__(16) u16 Qst[10240];      // [256][40] padded
    __shared__ __align__(16) u16 Kst[2560];       // [64][40]  padded
    __shared__ __align__(16) u16 Plds[4][4096];   // per-wave [64][64] XOR-swz
    __shared__ __align__(16) u16 Vt[4096];        // [64 h][64 j] XOR-swz
    const int b = blockIdx.x, c = blockIdx.y;
    const int t = threadIdx.x;
    const int wid = t >> 6, lane = t & 63;
    const int ri = wid;
    const int l15 = lane & 15, l4 = lane >> 4;

    f32x4v o[4][4];
    float denacc[4][4];
#pragma unroll
    for (int i = 0; i < 4; ++i)
#pragma unroll
        for (int j = 0; j < 4; ++j) {
            denacc[i][j] = 0.f;
#pragma unroll
            for (int e = 0; e < 4; ++e) o[i][j][e] = 0.f;
        }

    const size_t chunk_row0 = (size_t)b * 2048 + (size_t)c * 256;
    const u16* phiqB = PHIQ + chunk_row0 * 256;

    for (int rj = 0; rj < 4; ++rj) {
        __syncthreads();
        // stage Vt[h][j] (transposed, swizzled): thread t covers j=(t>>4)+16i, h0=(t&15)*4
        {
            const int hq = (t & 15) * 4;
#pragma unroll
            for (int i = 0; i < 4; ++i) {
                const int j = (t >> 4) + i * 16;
                const uint2 v = *(const uint2*)(VP + (size_t)(c * 256 + rj * 64 + j) * 4096 + b * 64 + hq);
                const int js = j & 7, jh = j >> 3;
                Vt[(hq+0) * 64 + ((jh ^ ((hq+0) & 7)) << 3) + js] = (u16)(v.x & 0xffff);
                Vt[(hq+1) * 64 + ((jh ^ ((hq+1) & 7)) << 3) + js] = (u16)(v.x >> 16);
                Vt[(hq+2) * 64 + ((jh ^ ((hq+2) & 7)) << 3) + js] = (u16)(v.y & 0xffff);
                Vt[(hq+3) * 64 + ((jh ^ ((hq+3) & 7)) << 3) + js] = (u16)(v.y >> 16);
            }
        }
        const bool active = (ri >= rj);
        const u16* phikB = PHIK + (chunk_row0 + rj * 64) * 256;
        f32x4v p[4][4];
#pragma unroll
        for (int i = 0; i < 4; ++i)
#pragma unroll
            for (int j = 0; j < 4; ++j)
#pragma unroll
                for (int e = 0; e < 4; ++e) p[i][j][e] = 0.f;

        for (int d0 = 0; d0 < 256; d0 += 32) {
            __syncthreads();
#pragma unroll
            for (int i = 0; i < 4; ++i) {
                const int idx = t + i * 256;
                const int r = idx >> 2, q = idx & 3;
                *(uint4*)&Qst[r * 40 + q * 8] = *(const uint4*)(phiqB + (size_t)r * 256 + d0 + q * 8);
            }
            {
                const int r = t >> 2, q = t & 3;
                *(uint4*)&Kst[r * 40 + q * 8] = *(const uint4*)(phikB + (size_t)r * 256 + d0 + q * 8);
            }
            __syncthreads();
            if (active) {
                s16x8 af[4], bv[4];
#pragma unroll
                for (int fi = 0; fi < 4; ++fi)
                    af[fi] = *(const s16x8*)&Qst[(ri * 64 + fi * 16 + l15) * 40 + l4 * 8];
#pragma unroll
                for (int fj = 0; fj < 4; ++fj)
                    bv[fj] = *(const s16x8*)&Kst[(fj * 16 + l15) * 40 + l4 * 8];
#pragma unroll
                for (int fi = 0; fi < 4; ++fi)
#pragma unroll
                    for (int fj = 0; fj < 4; ++fj)
                        p[fi][fj] = __builtin_amdgcn_mfma_f32_16x16x32_bf16(af[fi], bv[fj], p[fi][fj], 0, 0, 0);
            }
        }
        if (active) {
            const bool diag = (ri == rj);
#pragma unroll
            for (int fi = 0; fi < 4; ++fi) {
#pragma unroll
                for (int reg = 0; reg < 4; ++reg) {
                    const int lr = fi * 16 + l4 * 4 + reg;
                    float rsum = 0.f;
#pragma unroll
                    for (int fj = 0; fj < 4; ++fj) {
                        const int lc = fj * 16 + l15;
                        float v = p[fi][fj][reg];
                        if (diag && lc > lr) v = 0.f;
                        p[fi][fj][reg] = v;
                        rsum += v;
                    }
                    rsum += __shfl_xor(rsum, 1);
                    rsum += __shfl_xor(rsum, 2);
                    rsum += __shfl_xor(rsum, 4);
                    rsum += __shfl_xor(rsum, 8);
                    denacc[fi][reg] += rsum;
#pragma unroll
                    for (int fj = 0; fj < 4; ++fj) {
                        const int lc = fj * 16 + l15;
                        Plds[wid][lr * 64 + (((lc >> 3) ^ (lr & 7)) << 3) + (lc & 7)] = f2bf(p[fi][fj][reg]);
                    }
                }
            }
            // PV: O += P * V  (K = 64, two 32-steps)
#pragma unroll
            for (int ks = 0; ks < 2; ++ks) {
                s16x8 pa[4], vb[4];
#pragma unroll
                for (int fi = 0; fi < 4; ++fi) {
                    const int lr = fi * 16 + l15;
                    pa[fi] = *(const s16x8*)&Plds[wid][lr * 64 + (((ks * 4 + l4) ^ (lr & 7)) << 3)];
                }
#pragma unroll
                for (int fh = 0; fh < 4; ++fh) {
                    const int h = fh * 16 + l15;
                    vb[fh] = *(const s16x8*)&Vt[h * 64 + (((ks * 4 + l4) ^ (h & 7)) << 3)];
                }
#pragma unroll
                for (int fi = 0; fi < 4; ++fi)
#pragma unroll
                    for (int fh = 0; fh < 4; ++fh)
                        o[fi][fh] = __builtin_amdgcn_mfma_f32_16x16x32_bf16(pa[fi], vb[fh], o[fi][fh], 0, 0, 0);
            }
        }
    }
    // epilogue: fuse inter's num/den, divide, write bf16 attn
#pragma unroll
    for (int fi = 0; fi < 4; ++fi)
#pragma unroll
        for (int reg = 0; reg < 4; ++reg) {
            const int lrow = c * 256 + ri * 64 + fi * 16 + l4 * 4 + reg;   // b-local seq
            const size_t grow = (size_t)b * 2048 + lrow;
            const float inv = 1.f / (DEN[grow] + denacc[fi][reg] + 1e-6f);
#pragma unroll
            for (int fh = 0; fh < 4; ++fh) {
                const int h = fh * 16 + l15;
                const float val = (ANUM[grow * 64 + h] + o[fi][fh][reg]) * inv;
                ATT[(size_t)lrow * 4096 + b * 64 + h] = f2bf(val);
            }
        }
}

// ---------------------------------------------------------------------------
extern "C" void kernel_launch(void* const* d_in, const int* in_sizes, int n_in,
                              void* d_out, int out_size, void* d_ws, size_t ws_size,
                              hipStream_t stream)
{
    const float* query = (const float*)d_in[0];
    const float* key   = (const float*)d_in[1];
    const float* value = (const float*)d_in[2];
    const float* wq    = (const float*)d_in[3];
    const float* bq    = (const float*)d_in[4];
    const float* wk    = (const float*)d_in[5];
    const float* bk    = (const float*)d_in[6];
    const float* wv    = (const float*)d_in[7];
    const float* bv    = (const float*)d_in[8];
    const float* wo    = (const float*)d_in[9];
    const float* bo    = (const float*)d_in[10];
    const float* rm    = (const float*)d_in[11];
    float* out = (float*)d_out;

    // Workspace (total 235,929,600 B == proven size):
    char* base = (char*)d_ws;
    u16*   vp   = (u16*)(base);                   //  16,777,216 B  (V proj, bf16)
    u16*   phiq = (u16*)(base +  16777216);       //  67,108,864 B
    u16*   phik = (u16*)(base +  83886080);       //  67,108,864 B
    float* st   = (float*)(base + 150994944);     //  34,078,720 B
    u16*   stbf = (u16*)(base + 185073664);       //  16,777,216 B  (-> attn bf16 overlay)
    float* den  = (float*)(base + 201850880);     //     524,288 B
    float* tmp  = (float*)(base + 202375168);     //  33,554,432 B  (q/k proj; anum)
    float* anum = tmp;
    u16*   attn = stbf;

    const dim3 blk(256);
    gemm_mfma<false, false><<<dim3(64, 8), blk, 0, stream>>>(query, wq, bq, tmp);
    rand_project<<<dim3(16, 128), blk, 0, stream>>>(tmp, rm, phiq);
    gemm_mfma<false, false><<<dim3(64, 8), blk, 0, stream>>>(key, wk, bk, tmp);
    rand_project<<<dim3(16, 128), blk, 0, stream>>>(tmp, rm, phik);
    gemm_mfma<false, true><<<dim3(64, 8), blk, 0, stream>>>(value, wv, bv, vp);
    chunk_state<<<dim3(64, 8), blk, 0, stream>>>(phik, vp, st);
    prefix_scan<<<dim3(64), blk, 0, stream>>>(st, stbf);
    inter_mfma<<<dim3(64, 16), blk, 0, stream>>>(phiq, stbf, st, anum, den);
    intra_mfma<<<dim3(64, 8), blk, 0, stream>>>(phiq, phik, vp, anum, den, attn);
    gemm_mfma<true, false><<<dim3(64, 8), blk, 0, stream>>>(attn, wo, bo, out);
}

// Round 5
// 462.755 us; speedup vs baseline: 4.0385x; 1.5270x over previous
//
#include <hip/hip_runtime.h>
#include <math.h>

// Dims: L=2048 N=4 E=1024 H=16 D=128 HD=64; 2D=256; M=L*N=8192; B=64
// phi natural (l,n,h,d) flat order == reference's scrambled (b,l',d) view.
// V/attn row mapping: flat l*4096 + b*64 + hd == (l*4+n)*1024 + h*64 + hd for b=n*16+h.
// Chunked causal: CHK=256, NC=8. All heavy matmuls on MFMA bf16.

typedef unsigned short u16;
typedef unsigned int u32;
using f32x4v = __attribute__((ext_vector_type(4))) float;
using s16x8  = __attribute__((ext_vector_type(8))) short;

__device__ __forceinline__ float bf2f(u16 u) { return __uint_as_float(((u32)u) << 16); }
__device__ __forceinline__ u16 f2bf(float x) {
    u32 b = __float_as_uint(x);
    b += 0x7fff + ((b >> 16) & 1);          // RNE
    return (u16)(b >> 16);
}

// ---------------------------------------------------------------------------
// NT GEMM: C[m][n] = sum_k A[m][k]*B[n][k] + bias[n]; M=8192, N=1024, K=1024
template<bool ABF16, bool OBF16>
__global__ __launch_bounds__(256) void gemm_mfma(
    const void* __restrict__ Ap, const float* __restrict__ Bw,
    const float* __restrict__ bias, void* __restrict__ Cp)
{
    __shared__ __align__(16) u16 As[4096];
    __shared__ __align__(16) u16 Bs[4096];
    const int t = threadIdx.x;
    const int m0 = blockIdx.x * 128, n0 = blockIdx.y * 128;
    const int wid = t >> 6, lane = t & 63;
    const int wr = wid >> 1, wc = wid & 1;

    f32x4v acc[4][4];
#pragma unroll
    for (int i = 0; i < 4; ++i)
#pragma unroll
        for (int j = 0; j < 4; ++j)
#pragma unroll
            for (int e = 0; e < 4; ++e) acc[i][j][e] = 0.f;

    const int srow = t >> 1;
    const int scol = (t & 1) * 16;
    const int sx   = (srow >> 1) & 3;
    const int sl0  = (t & 1) * 2;
    u16* wa0 = &As[srow * 32 + (((sl0    ) ^ sx)) * 8];
    u16* wa1 = &As[srow * 32 + (((sl0 + 1) ^ sx)) * 8];
    u16* wb0 = &Bs[srow * 32 + (((sl0    ) ^ sx)) * 8];
    u16* wb1 = &Bs[srow * 32 + (((sl0 + 1) ^ sx)) * 8];

    for (int k0 = 0; k0 < 1024; k0 += 32) {
        __syncthreads();
        {
            u16 ta[16];
            if (ABF16) {
                const u16* src = (const u16*)Ap + (size_t)(m0 + srow) * 1024 + k0 + scol;
                *(uint4*)&ta[0] = *(const uint4*)src;
                *(uint4*)&ta[8] = *(const uint4*)(src + 8);
            } else {
                const float* src = (const float*)Ap + (size_t)(m0 + srow) * 1024 + k0 + scol;
#pragma unroll
                for (int q = 0; q < 4; ++q) {
                    const float4 v = *(const float4*)(src + q * 4);
                    ta[q*4+0] = f2bf(v.x); ta[q*4+1] = f2bf(v.y);
                    ta[q*4+2] = f2bf(v.z); ta[q*4+3] = f2bf(v.w);
                }
            }
            *(uint4*)wa0 = *(const uint4*)&ta[0];
            *(uint4*)wa1 = *(const uint4*)&ta[8];
        }
        {
            const float* src = Bw + (size_t)(n0 + srow) * 1024 + k0 + scol;
            u16 tb[16];
#pragma unroll
            for (int q = 0; q < 4; ++q) {
                const float4 v = *(const float4*)(src + q * 4);
                tb[q*4+0] = f2bf(v.x); tb[q*4+1] = f2bf(v.y);
                tb[q*4+2] = f2bf(v.z); tb[q*4+3] = f2bf(v.w);
            }
            *(uint4*)wb0 = *(const uint4*)&tb[0];
            *(uint4*)wb1 = *(const uint4*)&tb[8];
        }
        __syncthreads();
        s16x8 af[4], bfr[4];
#pragma unroll
        for (int fi = 0; fi < 4; ++fi) {
            const int r  = wr * 64 + fi * 16 + (lane & 15);
            const int sl = (lane >> 4) ^ ((r >> 1) & 3);
            af[fi] = *(const s16x8*)&As[r * 32 + sl * 8];
        }
#pragma unroll
        for (int fj = 0; fj < 4; ++fj) {
            const int r  = wc * 64 + fj * 16 + (lane & 15);
            const int sl = (lane >> 4) ^ ((r >> 1) & 3);
            bfr[fj] = *(const s16x8*)&Bs[r * 32 + sl * 8];
        }
#pragma unroll
        for (int fi = 0; fi < 4; ++fi)
#pragma unroll
            for (int fj = 0; fj < 4; ++fj)
                acc[fi][fj] = __builtin_amdgcn_mfma_f32_16x16x32_bf16(af[fi], bfr[fj], acc[fi][fj], 0, 0, 0);
    }

    const int rl = (lane >> 4) * 4, cl = lane & 15;
    float bvals[4];
#pragma unroll
    for (int fj = 0; fj < 4; ++fj) bvals[fj] = bias[n0 + wc * 64 + fj * 16 + cl];
#pragma unroll
    for (int fi = 0; fi < 4; ++fi)
#pragma unroll
        for (int j = 0; j < 4; ++j) {
            const size_t m = m0 + wr * 64 + fi * 16 + rl + j;
#pragma unroll
            for (int fj = 0; fj < 4; ++fj) {
                const int n = n0 + wc * 64 + fj * 16 + cl;
                const float v = acc[fi][fj][j] + bvals[fj];
                if (OBF16) ((u16*)Cp)[m * 1024 + n] = f2bf(v);
                else       ((float*)Cp)[m * 1024 + n] = v;
            }
        }
}

// ---------------------------------------------------------------------------
__global__ __launch_bounds__(256) void rand_project(
    const float* __restrict__ X, const float* __restrict__ RM, u16* __restrict__ PHI)
{
    __shared__ float Xs[64][68];
    __shared__ float RMs[128][68];
    __shared__ float rsc[64];
    const int h  = blockIdx.x;
    const int r0 = blockIdx.y * 64;
    const int t  = threadIdx.x;
#pragma unroll
    for (int i = 0; i < 16; ++i) {
        const int lin = t + i * 256;
        const int r = lin >> 6, c = lin & 63;
        Xs[r][c] = X[(size_t)(r0 + r) * 1024 + h * 64 + c];
    }
#pragma unroll
    for (int i = 0; i < 32; ++i) {
        const int lin = t + i * 256;
        const int d = lin >> 6, c = lin & 63;
        RMs[d][c] = RM[((size_t)h * 128 + d) * 64 + c];
    }
    __syncthreads();
    if (t < 64) {
        float s = 0.f;
#pragma unroll
        for (int c = 0; c < 64; ++c) { const float v = Xs[t][c]; s += v * v; }
        rsc[t] = 1.f / fmaxf(sqrtf(s), 1e-12f);
    }
    __syncthreads();
    const int rr = (t >> 4) * 4;
    const int dc = t & 15;
    float acc[4][8];
#pragma unroll
    for (int i = 0; i < 4; ++i)
#pragma unroll
        for (int j = 0; j < 8; ++j) acc[i][j] = 0.f;
    for (int c = 0; c < 64; c += 4) {
        float4 xv[4], rv[8];
#pragma unroll
        for (int i = 0; i < 4; ++i) xv[i] = *(const float4*)&Xs[rr + i][c];
#pragma unroll
        for (int j = 0; j < 8; ++j) rv[j] = *(const float4*)&RMs[dc + 16 * j][c];
#pragma unroll
        for (int i = 0; i < 4; ++i)
#pragma unroll
            for (int j = 0; j < 8; ++j)
                acc[i][j] += xv[i].x*rv[j].x + xv[i].y*rv[j].y + xv[i].z*rv[j].z + xv[i].w*rv[j].w;
    }
#pragma unroll
    for (int i = 0; i < 4; ++i) {
        const float sc = rsc[rr + i];
        const size_t base = ((size_t)(r0 + rr + i) * 16 + h) * 256;
#pragma unroll
        for (int j = 0; j < 8; ++j) {
            const float xt = acc[i][j] * sc;
            const int d = dc + 16 * j;
            PHI[base + d]       = f2bf(0.0625f * expf(xt));
            PHI[base + 128 + d] = f2bf(0.0625f * expf(-xt));
        }
    }
}

// ---------------------------------------------------------------------------
// Chunk state via MFMA. Block (b, c, dh): OUT[m=h 0..63][n=d 0..127 of half dh]
// = sum_{r<256} V[r][h]*K[r][d]; plus z[d] = sum_r K[r][d].
// LDS tiles stored as-read (row-major) with 16B-block XOR swizzle keyed on
// r bits 3-4 so strided per-lane b16 fragment reads are 2-way (free).
__global__ __launch_bounds__(256) void chunk_state_mfma(
    const u16* __restrict__ PHIK, const u16* __restrict__ VP, float* __restrict__ ST)
{
    __shared__ __align__(16) u16 Ks[64 * 136];    // [r][128 d + pad], swizzled 16B blocks
    __shared__ __align__(16) u16 Vs[64 * 72];     // [r][64 h + pad], swizzled
    __shared__ float zlds[16][132];
    const int b = blockIdx.x;
    const int c = blockIdx.y >> 1;
    const int dh = blockIdx.y & 1;
    const int t = threadIdx.x;
    const int wid = t >> 6, lane = t & 63;
    const int l15 = lane & 15, l4 = lane >> 4;
    const int wr = wid >> 1, wc = wid & 1;        // wave: h-range wr*32, d-range wc*64

    const size_t R0 = (size_t)b * 2048 + (size_t)c * 256;
    const int rgrp = t >> 4, d08 = (t & 15) * 8;  // K staging map
    const int vr = t >> 2, vh0 = (t & 3) * 16;    // V staging map

    float zpart[8];
#pragma unroll
    for (int i = 0; i < 8; ++i) zpart[i] = 0.f;

    f32x4v acc[2][4];
#pragma unroll
    for (int i = 0; i < 2; ++i)
#pragma unroll
        for (int j = 0; j < 4; ++j)
#pragma unroll
            for (int e = 0; e < 4; ++e) acc[i][j][e] = 0.f;

    for (int stage = 0; stage < 4; ++stage) {
        __syncthreads();
        // stage K: thread covers rows rgrp+16j, 8 d-cols
#pragma unroll
        for (int j = 0; j < 4; ++j) {
            const int r = rgrp + 16 * j;
            const uint4 v = *(const uint4*)(PHIK + (R0 + stage * 64 + r) * 256 + dh * 128 + d08);
            const int x = ((r >> 3) & 3) << 1;
            *(uint4*)&Ks[r * 136 + (((d08 >> 3) ^ x) << 3)] = v;
            const u16* pv = (const u16*)&v;
#pragma unroll
            for (int i = 0; i < 8; ++i) zpart[i] += bf2f(pv[i]);
        }
        // stage V: thread covers row vr, 16 h
        {
            const int x = ((vr >> 3) & 3) << 1;
            const u16* src = VP + (size_t)(c * 256 + stage * 64 + vr) * 4096 + b * 64 + vh0;
            const uint4 v0 = *(const uint4*)(src);
            const uint4 v1 = *(const uint4*)(src + 8);
            *(uint4*)&Vs[vr * 72 + ((((vh0 >> 3) + 0) ^ x) << 3)] = v0;
            *(uint4*)&Vs[vr * 72 + ((((vh0 >> 3) + 1) ^ x) << 3)] = v1;
        }
        __syncthreads();
#pragma unroll
        for (int ks = 0; ks < 2; ++ks) {
            const int xk = ((ks * 4 + l4) & 3) << 1;   // == ((r>>3)&3)<<1 for rows below
            const int r0 = ks * 32 + l4 * 8;
            s16x8 af[2], bk[4];
#pragma unroll
            for (int fi = 0; fi < 2; ++fi) {
                const int h = wr * 32 + fi * 16 + l15;
                const int colv = (((h >> 3) ^ xk) << 3) + (h & 7);
#pragma unroll
                for (int e = 0; e < 8; ++e)
                    af[fi][e] = (short)Vs[(r0 + e) * 72 + colv];
            }
#pragma unroll
            for (int fj = 0; fj < 4; ++fj) {
                const int d = wc * 64 + fj * 16 + l15;
                const int colk = (((d >> 3) ^ xk) << 3) + (d & 7);
#pragma unroll
                for (int e = 0; e < 8; ++e)
                    bk[fj][e] = (short)Ks[(r0 + e) * 136 + colk];
            }
#pragma unroll
            for (int fi = 0; fi < 2; ++fi)
#pragma unroll
                for (int fj = 0; fj < 4; ++fj)
                    acc[fi][fj] = __builtin_amdgcn_mfma_f32_16x16x32_bf16(af[fi], bk[fj], acc[fi][fj], 0, 0, 0);
        }
    }
    // z reduction across the 16 r-groups
    __syncthreads();
    *(float4*)&zlds[rgrp][d08]     = *(float4*)&zpart[0];
    *(float4*)&zlds[rgrp][d08 + 4] = *(float4*)&zpart[4];
    __syncthreads();
    float* st = ST + (size_t)(b * 8 + c) * 16640;
    if (t < 128) {
        float z = 0.f;
#pragma unroll
        for (int g = 0; g < 16; ++g) z += zlds[g][t];
        st[16384 + dh * 128 + t] = z;
    }
    // store KV: st[h*256 + d]; lanes l15 -> consecutive d (coalesced)
#pragma unroll
    for (int fi = 0; fi < 2; ++fi)
#pragma unroll
        for (int reg = 0; reg < 4; ++reg) {
            const int h = wr * 32 + fi * 16 + l4 * 4 + reg;
#pragma unroll
            for (int fj = 0; fj < 4; ++fj) {
                const int d = dh * 128 + wc * 64 + fj * 16 + l15;
                st[(size_t)h * 256 + d] = acc[fi][fj][reg];
            }
        }
}

// ---------------------------------------------------------------------------
__global__ void prefix_scan(float* __restrict__ ST, u16* __restrict__ STBF)
{
    // one thread per (b, element); serial exclusive scan over the 8 chunks
    const int b = blockIdx.x;
    const int e = blockIdx.y * 256 + threadIdx.x;
    if (e >= 16640) return;
    const size_t base = (size_t)b * 8 * 16640 + e;
    float run = 0.f;
#pragma unroll
    for (int c = 0; c < 8; ++c) {
        const float v = ST[base + (size_t)c * 16640];
        ST[base + (size_t)c * 16640] = run;
        if (e < 16384) STBF[(size_t)(b * 8 + c) * 16384 + e] = f2bf(run);
        run += v;
    }
}

// ---------------------------------------------------------------------------
// ANUM[b][r][h] = PhiQ[r][:] . S_start[:][h] (MFMA); DEN[b][r] = PhiQ[r][:] . z
__global__ __launch_bounds__(256) void inter_mfma(
    const u16* __restrict__ PHIQ, const u16* __restrict__ STBF,
    const float* __restrict__ ST, float* __restrict__ ANUM, float* __restrict__ DEN)
{
    __shared__ __align__(16) u16 Qs[4096];
    __shared__ __align__(16) u16 Ss[2048];
    __shared__ float Zs[32];
    __shared__ float dred[128];
    const int b = blockIdx.x, rb = blockIdx.y;
    const int c = rb >> 1;
    const int t = threadIdx.x;
    const int wid = t >> 6, lane = t & 63;
    const int wr = wid >> 1, wc = wid & 1;

    f32x4v acc[4][2];
#pragma unroll
    for (int i = 0; i < 4; ++i)
#pragma unroll
        for (int j = 0; j < 2; ++j)
#pragma unroll
            for (int e = 0; e < 4; ++e) acc[i][j][e] = 0.f;
    float dacc = 0.f;

    const u16* phiq = PHIQ + ((size_t)b * 2048 + (size_t)rb * 128) * 256;
    const u16* stb  = STBF + (size_t)(b * 8 + c) * 16384;
    const float* zb = ST + (size_t)(b * 8 + c) * 16640 + 16384;
    const int drow = t & 127, dhalf = t >> 7;
    const int srow = t >> 1;
    const int sx   = (srow >> 1) & 3;
    const int sl0  = (t & 1) * 2;

    for (int d0 = 0; d0 < 256; d0 += 32) {
        __syncthreads();
        {
            const u16* src = phiq + (size_t)srow * 256 + d0 + (t & 1) * 16;
            const uint4 v0 = *(const uint4*)src;
            const uint4 v1 = *(const uint4*)(src + 8);
            *(uint4*)&Qs[srow * 32 + ((sl0     ^ sx)) * 8] = v0;
            *(uint4*)&Qs[srow * 32 + (((sl0+1) ^ sx)) * 8] = v1;
        }
        if (t < 128) {
            const u16* src = stb + (size_t)srow * 256 + d0 + (t & 1) * 16;
            const uint4 v0 = *(const uint4*)src;
            const uint4 v1 = *(const uint4*)(src + 8);
            *(uint4*)&Ss[srow * 32 + ((sl0     ^ sx)) * 8] = v0;
            *(uint4*)&Ss[srow * 32 + (((sl0+1) ^ sx)) * 8] = v1;
        }
        if (t < 32) Zs[t] = zb[d0 + t];
        __syncthreads();
        s16x8 af[4], bfr[2];
#pragma unroll
        for (int fi = 0; fi < 4; ++fi) {
            const int r  = wr * 64 + fi * 16 + (lane & 15);
            const int sl = (lane >> 4) ^ ((r >> 1) & 3);
            af[fi] = *(const s16x8*)&Qs[r * 32 + sl * 8];
        }
#pragma unroll
        for (int fj = 0; fj < 2; ++fj) {
            const int r  = wc * 32 + fj * 16 + (lane & 15);
            const int sl = (lane >> 4) ^ ((r >> 1) & 3);
            bfr[fj] = *(const s16x8*)&Ss[r * 32 + sl * 8];
        }
#pragma unroll
        for (int fi = 0; fi < 4; ++fi)
#pragma unroll
            for (int fj = 0; fj < 2; ++fj)
                acc[fi][fj] = __builtin_amdgcn_mfma_f32_16x16x32_bf16(af[fi], bfr[fj], acc[fi][fj], 0, 0, 0);
#pragma unroll
        for (int s2 = 0; s2 < 2; ++s2) {
            const int sl  = dhalf * 2 + s2;
            const int adr = drow * 32 + ((sl ^ ((drow >> 1) & 3))) * 8;
#pragma unroll
            for (int e = 0; e < 8; ++e)
                dacc += bf2f(Qs[adr + e]) * Zs[sl * 8 + e];
        }
    }
    __syncthreads();
    if (t >= 128) dred[t - 128] = dacc;
    __syncthreads();
    if (t < 128) DEN[(size_t)b * 2048 + rb * 128 + t] = dacc + dred[t];

    const int rl = (lane >> 4) * 4, cl = lane & 15;
#pragma unroll
    for (int fi = 0; fi < 4; ++fi)
#pragma unroll
        for (int j = 0; j < 4; ++j) {
            const int row = rb * 128 + wr * 64 + fi * 16 + rl + j;
#pragma unroll
            for (int fj = 0; fj < 2; ++fj) {
                const int col = wc * 32 + fj * 16 + cl;
                ANUM[((size_t)b * 2048 + row) * 64 + col] = acc[fi][fj][j];
            }
        }
}

// ---------------------------------------------------------------------------
// Intra-chunk causal, MFMA flash-style. Block=(b,c); wave ri owns rows ri*64..+64.
// Epilogue fuses finalize: attn = (ANUM + O) / (DEN + den_intra + eps), bf16.
__global__ __launch_bounds__(256) void intra_mfma(
    const u16* __restrict__ PHIQ, const u16* __restrict__ PHIK,
    const u16* __restrict__ VP, const float* __restrict__ ANUM,
    const float* __restrict__ DEN, u16* __restrict__ ATT)
{
    __shared__ __align__(16) u16 Qst[10240];      // [256][40] padded
    __shared__ __align__(16) u16 Kst[2560];       // [64][40]  padded
    __shared__ __align__(16) u16 Plds[4][4096];   // per-wave [64][64] XOR-swz
    __shared__ __align__(16) u16 Vt[4096];        // [64 h][64 j] XOR-swz
    const int b = blockIdx.x, c = blockIdx.y;
    const int t = threadIdx.x;
    const int wid = t >> 6, lane = t & 63;
    const int ri = wid;
    const int l15 = lane & 15, l4 = lane >> 4;

    f32x4v o[4][4];
    float denacc[4][4];
#pragma unroll
    for (int i = 0; i < 4; ++i)
#pragma unroll
        for (int j = 0; j < 4; ++j) {
            denacc[i][j] = 0.f;
#pragma unroll
            for (int e = 0; e < 4; ++e) o[i][j][e] = 0.f;
        }

    const size_t chunk_row0 = (size_t)b * 2048 + (size_t)c * 256;
    const u16* phiqB = PHIQ + chunk_row0 * 256;

    for (int rj = 0; rj < 4; ++rj) {
        __syncthreads();
        {
            const int hq = (t & 15) * 4;
#pragma unroll
            for (int i = 0; i < 4; ++i) {
                const int j = (t >> 4) + i * 16;
                const uint2 v = *(const uint2*)(VP + (size_t)(c * 256 + rj * 64 + j) * 4096 + b * 64 + hq);
                const int js = j & 7, jh = j >> 3;
                Vt[(hq+0) * 64 + ((jh ^ ((hq+0) & 7)) << 3) + js] = (u16)(v.x & 0xffff);
                Vt[(hq+1) * 64 + ((jh ^ ((hq+1) & 7)) << 3) + js] = (u16)(v.x >> 16);
                Vt[(hq+2) * 64 + ((jh ^ ((hq+2) & 7)) << 3) + js] = (u16)(v.y & 0xffff);
                Vt[(hq+3) * 64 + ((jh ^ ((hq+3) & 7)) << 3) + js] = (u16)(v.y >> 16);
            }
        }
        const bool active = (ri >= rj);
        const u16* phikB = PHIK + (chunk_row0 + rj * 64) * 256;
        f32x4v p[4][4];
#pragma unroll
        for (int i = 0; i < 4; ++i)
#pragma unroll
            for (int j = 0; j < 4; ++j)
#pragma unroll
                for (int e = 0; e < 4; ++e) p[i][j][e] = 0.f;

        for (int d0 = 0; d0 < 256; d0 += 32) {
            __syncthreads();
#pragma unroll
            for (int i = 0; i < 4; ++i) {
                const int idx = t + i * 256;
                const int r = idx >> 2, q = idx & 3;
                *(uint4*)&Qst[r * 40 + q * 8] = *(const uint4*)(phiqB + (size_t)r * 256 + d0 + q * 8);
            }
            {
                const int r = t >> 2, q = t & 3;
                *(uint4*)&Kst[r * 40 + q * 8] = *(const uint4*)(phikB + (size_t)r * 256 + d0 + q * 8);
            }
            __syncthreads();
            if (active) {
                s16x8 af[4], bv[4];
#pragma unroll
                for (int fi = 0; fi < 4; ++fi)
                    af[fi] = *(const s16x8*)&Qst[(ri * 64 + fi * 16 + l15) * 40 + l4 * 8];
#pragma unroll
                for (int fj = 0; fj < 4; ++fj)
                    bv[fj] = *(const s16x8*)&Kst[(fj * 16 + l15) * 40 + l4 * 8];
#pragma unroll
                for (int fi = 0; fi < 4; ++fi)
#pragma unroll
                    for (int fj = 0; fj < 4; ++fj)
                        p[fi][fj] = __builtin_amdgcn_mfma_f32_16x16x32_bf16(af[fi], bv[fj], p[fi][fj], 0, 0, 0);
            }
        }
        if (active) {
            const bool diag = (ri == rj);
#pragma unroll
            for (int fi = 0; fi < 4; ++fi) {
#pragma unroll
                for (int reg = 0; reg < 4; ++reg) {
                    const int lr = fi * 16 + l4 * 4 + reg;
                    float rsum = 0.f;
#pragma unroll
                    for (int fj = 0; fj < 4; ++fj) {
                        const int lc = fj * 16 + l15;
                        float v = p[fi][fj][reg];
                        if (diag && lc > lr) v = 0.f;
                        p[fi][fj][reg] = v;
                        rsum += v;
                    }
                    rsum += __shfl_xor(rsum, 1);
                    rsum += __shfl_xor(rsum, 2);
                    rsum += __shfl_xor(rsum, 4);
                    rsum += __shfl_xor(rsum, 8);
                    denacc[fi][reg] += rsum;
#pragma unroll
                    for (int fj = 0; fj < 4; ++fj) {
                        const int lc = fj * 16 + l15;
                        Plds[wid][lr * 64 + (((lc >> 3) ^ (lr & 7)) << 3) + (lc & 7)] = f2bf(p[fi][fj][reg]);
                    }
                }
            }
#pragma unroll
            for (int ks = 0; ks < 2; ++ks) {
                s16x8 pa[4], vb[4];
#pragma unroll
                for (int fi = 0; fi < 4; ++fi) {
                    const int lr = fi * 16 + l15;
                    pa[fi] = *(const s16x8*)&Plds[wid][lr * 64 + (((ks * 4 + l4) ^ (lr & 7)) << 3)];
                }
#pragma unroll
                for (int fh = 0; fh < 4; ++fh) {
                    const int h = fh * 16 + l15;
                    vb[fh] = *(const s16x8*)&Vt[h * 64 + (((ks * 4 + l4) ^ (h & 7)) << 3)];
                }
#pragma unroll
                for (int fi = 0; fi < 4; ++fi)
#pragma unroll
                    for (int fh = 0; fh < 4; ++fh)
                        o[fi][fh] = __builtin_amdgcn_mfma_f32_16x16x32_bf16(pa[fi], vb[fh], o[fi][fh], 0, 0, 0);
            }
        }
    }
#pragma unroll
    for (int fi = 0; fi < 4; ++fi)
#pragma unroll
        for (int reg = 0; reg < 4; ++reg) {
            const int lrow = c * 256 + ri * 64 + fi * 16 + l4 * 4 + reg;
            const size_t grow = (size_t)b * 2048 + lrow;
            const float inv = 1.f / (DEN[grow] + denacc[fi][reg] + 1e-6f);
#pragma unroll
            for (int fh = 0; fh < 4; ++fh) {
                const int h = fh * 16 + l15;
                const float val = (ANUM[grow * 64 + h] + o[fi][fh][reg]) * inv;
                ATT[(size_t)lrow * 4096 + b * 64 + h] = f2bf(val);
            }
        }
}

// ---------------------------------------------------------------------------
extern "C" void kernel_launch(void* const* d_in, const int* in_sizes, int n_in,
                              void* d_out, int out_size, void* d_ws, size_t ws_size,
                              hipStream_t stream)
{
    const float* query = (const float*)d_in[0];
    const float* key   = (const float*)d_in[1];
    const float* value = (const float*)d_in[2];
    const float* wq    = (const float*)d_in[3];
    const float* bq    = (const float*)d_in[4];
    const float* wk    = (const float*)d_in[5];
    const float* bk    = (const float*)d_in[6];
    const float* wv    = (const float*)d_in[7];
    const float* bv    = (const float*)d_in[8];
    const float* wo    = (const float*)d_in[9];
    const float* bo    = (const float*)d_in[10];
    const float* rm    = (const float*)d_in[11];
    float* out = (float*)d_out;

    // Workspace (total 235,929,600 B == proven size):
    char* base = (char*)d_ws;
    u16*   vp   = (u16*)(base);                   //  16,777,216 B  (V proj, bf16)
    u16*   phiq = (u16*)(base +  16777216);       //  67,108,864 B
    u16*   phik = (u16*)(base +  83886080);       //  67,108,864 B
    float* st   = (float*)(base + 150994944);     //  34,078,720 B
    u16*   stbf = (u16*)(base + 185073664);       //  16,777,216 B  (-> attn bf16 overlay)
    float* den  = (float*)(base + 201850880);     //     524,288 B
    float* tmp  = (float*)(base + 202375168);     //  33,554,432 B  (q/k proj; anum)
    float* anum = tmp;
    u16*   attn = stbf;

    const dim3 blk(256);
    gemm_mfma<false, false><<<dim3(64, 8), blk, 0, stream>>>(query, wq, bq, tmp);
    rand_project<<<dim3(16, 128), blk, 0, stream>>>(tmp, rm, phiq);
    gemm_mfma<false, false><<<dim3(64, 8), blk, 0, stream>>>(key, wk, bk, tmp);
    rand_project<<<dim3(16, 128), blk, 0, stream>>>(tmp, rm, phik);
    gemm_mfma<false, true><<<dim3(64, 8), blk, 0, stream>>>(value, wv, bv, vp);
    chunk_state_mfma<<<dim3(64, 16), blk, 0, stream>>>(phik, vp, st);
    prefix_scan<<<dim3(64, 65), blk, 0, stream>>>(st, stbf);
    inter_mfma<<<dim3(64, 16), blk, 0, stream>>>(phiq, stbf, st, anum, den);
    intra_mfma<<<dim3(64, 8), blk, 0, stream>>>(phiq, phik, vp, anum, den, attn);
    gemm_mfma<true, false><<<dim3(64, 8), blk, 0, stream>>>(attn, wo, bo, out);
}

// Round 6
// 437.706 us; speedup vs baseline: 4.2696x; 1.0572x over previous
//
#include <hip/hip_runtime.h>
#include <math.h>

// Dims: L=2048 N=4 E=1024 H=16 D=128 HD=64; 2D=256; M=L*N=8192; B=64
// phi natural (l,n,h,d) flat order == reference's scrambled (b,l',d) view.
// attn row mapping: flat l*4096 + b*64 + hd == (l*4+nb)*1024 + (h16*64+hd), b=nb*16+h16.
// Chunked causal: CHK=256, NC=8. Causal core: single LDS-free fused kernel.

typedef unsigned short u16;
typedef unsigned int u32;
using f32x4v  = __attribute__((ext_vector_type(4))) float;
using f32x16v = __attribute__((ext_vector_type(16))) float;
using s16x8   = __attribute__((ext_vector_type(8))) short;

__device__ __forceinline__ float bf2f(u16 u) { return __uint_as_float(((u32)u) << 16); }
__device__ __forceinline__ u16 f2bf(float x) {
    u32 b = __float_as_uint(x);
    b += 0x7fff + ((b >> 16) & 1);          // RNE
    return (u16)(b >> 16);
}
__device__ __forceinline__ u32 cvtpk(float lo, float hi) {
    u32 r;
    asm("v_cvt_pk_bf16_f32 %0, %1, %2" : "=v"(r) : "v"(lo), "v"(hi));
    return r;
}

// ---------------------------------------------------------------------------
// NT GEMM: C[m][n] = sum_k A[m][k]*B[n][k] + bias[n]; M=8192, N=1024, K=1024
// OMODE: 0 = f32 row-major, 1 = bf16 row-major, 2 = bf16 vpt[(b*64+hd)*2048 + k]
template<bool ABF16, int OMODE>
__global__ __launch_bounds__(256) void gemm_mfma(
    const void* __restrict__ Ap, const float* __restrict__ Bw,
    const float* __restrict__ bias, void* __restrict__ Cp)
{
    __shared__ __align__(16) u16 As[4096];
    __shared__ __align__(16) u16 Bs[4096];
    const int t = threadIdx.x;
    const int m0 = blockIdx.x * 128, n0 = blockIdx.y * 128;
    const int wid = t >> 6, lane = t & 63;
    const int wr = wid >> 1, wc = wid & 1;

    f32x4v acc[4][4];
#pragma unroll
    for (int i = 0; i < 4; ++i)
#pragma unroll
        for (int j = 0; j < 4; ++j)
#pragma unroll
            for (int e = 0; e < 4; ++e) acc[i][j][e] = 0.f;

    const int srow = t >> 1;
    const int scol = (t & 1) * 16;
    const int sx   = (srow >> 1) & 3;
    const int sl0  = (t & 1) * 2;
    u16* wa0 = &As[srow * 32 + (((sl0    ) ^ sx)) * 8];
    u16* wa1 = &As[srow * 32 + (((sl0 + 1) ^ sx)) * 8];
    u16* wb0 = &Bs[srow * 32 + (((sl0    ) ^ sx)) * 8];
    u16* wb1 = &Bs[srow * 32 + (((sl0 + 1) ^ sx)) * 8];

    for (int k0 = 0; k0 < 1024; k0 += 32) {
        __syncthreads();
        {
            u16 ta[16];
            if (ABF16) {
                const u16* src = (const u16*)Ap + (size_t)(m0 + srow) * 1024 + k0 + scol;
                *(uint4*)&ta[0] = *(const uint4*)src;
                *(uint4*)&ta[8] = *(const uint4*)(src + 8);
            } else {
                const float* src = (const float*)Ap + (size_t)(m0 + srow) * 1024 + k0 + scol;
#pragma unroll
                for (int q = 0; q < 4; ++q) {
                    const float4 v = *(const float4*)(src + q * 4);
                    ta[q*4+0] = f2bf(v.x); ta[q*4+1] = f2bf(v.y);
                    ta[q*4+2] = f2bf(v.z); ta[q*4+3] = f2bf(v.w);
                }
            }
            *(uint4*)wa0 = *(const uint4*)&ta[0];
            *(uint4*)wa1 = *(const uint4*)&ta[8];
        }
        {
            const float* src = Bw + (size_t)(n0 + srow) * 1024 + k0 + scol;
            u16 tb[16];
#pragma unroll
            for (int q = 0; q < 4; ++q) {
                const float4 v = *(const float4*)(src + q * 4);
                tb[q*4+0] = f2bf(v.x); tb[q*4+1] = f2bf(v.y);
                tb[q*4+2] = f2bf(v.z); tb[q*4+3] = f2bf(v.w);
            }
            *(uint4*)wb0 = *(const uint4*)&tb[0];
            *(uint4*)wb1 = *(const uint4*)&tb[8];
        }
        __syncthreads();
        s16x8 af[4], bfr[4];
#pragma unroll
        for (int fi = 0; fi < 4; ++fi) {
            const int r  = wr * 64 + fi * 16 + (lane & 15);
            const int sl = (lane >> 4) ^ ((r >> 1) & 3);
            af[fi] = *(const s16x8*)&As[r * 32 + sl * 8];
        }
#pragma unroll
        for (int fj = 0; fj < 4; ++fj) {
            const int r  = wc * 64 + fj * 16 + (lane & 15);
            const int sl = (lane >> 4) ^ ((r >> 1) & 3);
            bfr[fj] = *(const s16x8*)&Bs[r * 32 + sl * 8];
        }
#pragma unroll
        for (int fi = 0; fi < 4; ++fi)
#pragma unroll
            for (int fj = 0; fj < 4; ++fj)
                acc[fi][fj] = __builtin_amdgcn_mfma_f32_16x16x32_bf16(af[fi], bfr[fj], acc[fi][fj], 0, 0, 0);
    }

    const int rl = (lane >> 4) * 4, cl = lane & 15;
    float bvals[4];
#pragma unroll
    for (int fj = 0; fj < 4; ++fj) bvals[fj] = bias[n0 + wc * 64 + fj * 16 + cl];
#pragma unroll
    for (int fi = 0; fi < 4; ++fi)
#pragma unroll
        for (int j = 0; j < 4; ++j) {
            const size_t m = m0 + wr * 64 + fi * 16 + rl + j;
#pragma unroll
            for (int fj = 0; fj < 4; ++fj) {
                const int n = n0 + wc * 64 + fj * 16 + cl;
                const float v = acc[fi][fj][j] + bvals[fj];
                if (OMODE == 0)      ((float*)Cp)[m * 1024 + n] = v;
                else if (OMODE == 1) ((u16*)Cp)[m * 1024 + n] = f2bf(v);
                else {
                    // vpt[(b*64+hd)*2048 + k]; b=(m&3)*16+(n>>6), hd=n&63, k=m>>2
                    ((u16*)Cp)[((size_t)((m & 3) * 16 + (n >> 6)) * 64 + (n & 63)) * 2048 + (m >> 2)] = f2bf(v);
                }
            }
        }
}

// ---------------------------------------------------------------------------
__global__ __launch_bounds__(256) void rand_project(
    const float* __restrict__ X, const float* __restrict__ RM, u16* __restrict__ PHI)
{
    __shared__ float Xs[64][68];
    __shared__ float RMs[128][68];
    __shared__ float rsc[64];
    const int h  = blockIdx.x;
    const int r0 = blockIdx.y * 64;
    const int t  = threadIdx.x;
#pragma unroll
    for (int i = 0; i < 16; ++i) {
        const int lin = t + i * 256;
        const int r = lin >> 6, c = lin & 63;
        Xs[r][c] = X[(size_t)(r0 + r) * 1024 + h * 64 + c];
    }
#pragma unroll
    for (int i = 0; i < 32; ++i) {
        const int lin = t + i * 256;
        const int d = lin >> 6, c = lin & 63;
        RMs[d][c] = RM[((size_t)h * 128 + d) * 64 + c];
    }
    __syncthreads();
    if (t < 64) {
        float s = 0.f;
#pragma unroll
        for (int c = 0; c < 64; ++c) { const float v = Xs[t][c]; s += v * v; }
        rsc[t] = 1.f / fmaxf(sqrtf(s), 1e-12f);
    }
    __syncthreads();
    const int rr = (t >> 4) * 4;
    const int dc = t & 15;
    float acc[4][8];
#pragma unroll
    for (int i = 0; i < 4; ++i)
#pragma unroll
        for (int j = 0; j < 8; ++j) acc[i][j] = 0.f;
    for (int c = 0; c < 64; c += 4) {
        float4 xv[4], rv[8];
#pragma unroll
        for (int i = 0; i < 4; ++i) xv[i] = *(const float4*)&Xs[rr + i][c];
#pragma unroll
        for (int j = 0; j < 8; ++j) rv[j] = *(const float4*)&RMs[dc + 16 * j][c];
#pragma unroll
        for (int i = 0; i < 4; ++i)
#pragma unroll
            for (int j = 0; j < 8; ++j)
                acc[i][j] += xv[i].x*rv[j].x + xv[i].y*rv[j].y + xv[i].z*rv[j].z + xv[i].w*rv[j].w;
    }
#pragma unroll
    for (int i = 0; i < 4; ++i) {
        const float sc = rsc[rr + i];
        const size_t base = ((size_t)(r0 + rr + i) * 16 + h) * 256;
#pragma unroll
        for (int j = 0; j < 8; ++j) {
            const float xt = acc[i][j] * sc;
            const int d = dc + 16 * j;
            PHI[base + d]       = f2bf(0.0625f * expf(xt));
            PHI[base + 128 + d] = f2bf(0.0625f * expf(-xt));
        }
    }
}

// ---------------------------------------------------------------------------
// Chunk state via MFMA. Block (b, c, dh): OUT[m=h 0..63][n=d 0..127 of half dh]
// = sum_{r<256} V[r][h]*K[r][d]; plus z[d] = sum_r K[r][d]. V frags direct from vpt.
__global__ __launch_bounds__(256) void chunk_state_mfma(
    const u16* __restrict__ PHIK, const u16* __restrict__ VPT, float* __restrict__ ST)
{
    __shared__ __align__(16) u16 Ks[64 * 136];    // [r][128 d + pad], swizzled 16B blocks
    __shared__ float zlds[16][132];
    const int b = blockIdx.x;
    const int c = blockIdx.y >> 1;
    const int dh = blockIdx.y & 1;
    const int t = threadIdx.x;
    const int wid = t >> 6, lane = t & 63;
    const int l15 = lane & 15, l4 = lane >> 4;
    const int wr = wid >> 1, wc = wid & 1;        // wave: h-range wr*32, d-range wc*64

    const size_t R0 = (size_t)b * 2048 + (size_t)c * 256;
    const int rgrp = t >> 4, d08 = (t & 15) * 8;  // K staging map

    float zpart[8];
#pragma unroll
    for (int i = 0; i < 8; ++i) zpart[i] = 0.f;

    f32x4v acc[2][4];
#pragma unroll
    for (int i = 0; i < 2; ++i)
#pragma unroll
        for (int j = 0; j < 4; ++j)
#pragma unroll
            for (int e = 0; e < 4; ++e) acc[i][j][e] = 0.f;

    for (int stage = 0; stage < 4; ++stage) {
        __syncthreads();
#pragma unroll
        for (int j = 0; j < 4; ++j) {
            const int r = rgrp + 16 * j;
            const uint4 v = *(const uint4*)(PHIK + (R0 + stage * 64 + r) * 256 + dh * 128 + d08);
            const int x = ((r >> 3) & 3) << 1;
            *(uint4*)&Ks[r * 136 + (((d08 >> 3) ^ x) << 3)] = v;
            const u16* pv = (const u16*)&v;
#pragma unroll
            for (int i = 0; i < 8; ++i) zpart[i] += bf2f(pv[i]);
        }
        __syncthreads();
#pragma unroll
        for (int ks = 0; ks < 2; ++ks) {
            const int xk = ((ks * 4 + l4) & 3) << 1;
            const int r0 = ks * 32 + l4 * 8;
            s16x8 af[2], bk[4];
#pragma unroll
            for (int fi = 0; fi < 2; ++fi) {
                const int h = wr * 32 + fi * 16 + l15;
                af[fi] = *(const s16x8*)(VPT + ((size_t)b * 64 + h) * 2048 + c * 256 + stage * 64 + ks * 32 + l4 * 8);
            }
#pragma unroll
            for (int fj = 0; fj < 4; ++fj) {
                const int d = wc * 64 + fj * 16 + l15;
                const int colk = (((d >> 3) ^ xk) << 3) + (d & 7);
#pragma unroll
                for (int e = 0; e < 8; ++e)
                    bk[fj][e] = (short)Ks[(r0 + e) * 136 + colk];
            }
#pragma unroll
            for (int fi = 0; fi < 2; ++fi)
#pragma unroll
                for (int fj = 0; fj < 4; ++fj)
                    acc[fi][fj] = __builtin_amdgcn_mfma_f32_16x16x32_bf16(af[fi], bk[fj], acc[fi][fj], 0, 0, 0);
        }
    }
    __syncthreads();
    *(float4*)&zlds[rgrp][d08]     = *(float4*)&zpart[0];
    *(float4*)&zlds[rgrp][d08 + 4] = *(float4*)&zpart[4];
    __syncthreads();
    float* st = ST + (size_t)(b * 8 + c) * 16640;
    if (t < 128) {
        float z = 0.f;
#pragma unroll
        for (int g = 0; g < 16; ++g) z += zlds[g][t];
        st[16384 + dh * 128 + t] = z;
    }
#pragma unroll
    for (int fi = 0; fi < 2; ++fi)
#pragma unroll
        for (int reg = 0; reg < 4; ++reg) {
            const int h = wr * 32 + fi * 16 + l4 * 4 + reg;
#pragma unroll
            for (int fj = 0; fj < 4; ++fj) {
                const int d = dh * 128 + wc * 64 + fj * 16 + l15;
                st[(size_t)h * 256 + d] = acc[fi][fj][reg];
            }
        }
}

// ---------------------------------------------------------------------------
// Exclusive prefix over 8 chunks -> bf16 stbf[(b*8+c)*16640 + e]
// e<16384: S^T h-major (h*256+d); e>=16384: z.
__global__ void prefix_scan(const float* __restrict__ ST, u16* __restrict__ STBF)
{
    const int b = blockIdx.x;
    const int e = blockIdx.y * 256 + threadIdx.x;
    if (e >= 16640) return;
    const size_t base = (size_t)b * 8 * 16640 + e;
    float run = 0.f;
#pragma unroll
    for (int c = 0; c < 8; ++c) {
        const float v = ST[base + (size_t)c * 16640];
        STBF[(size_t)(b * 8 + c) * 16640 + e] = f2bf(run);
        run += v;
    }
}

// ---------------------------------------------------------------------------
// Fused causal kernel (LDS-free, barrier-free). Grid (b, c, ri), 64-thread blocks.
// Wave owns q-rows [ri*64, ri*64+64) of chunk c; fi in {0,1} halves of 32.
// o[q][h] = sum_d Q[q][d]*Sprefix^T[h][d]  (inter, via stbf)
//         + sum_{k<=q in chunk} P[q][k]*V[k][h]  (intra, swapped-QK + reg-packed PV)
// den[q] = Q.zprefix + rowsum(masked P);  attn = o/(den+eps) -> bf16.
__global__ __launch_bounds__(64) void causal_fused(
    const u16* __restrict__ PHIQ, const u16* __restrict__ PHIK,
    const u16* __restrict__ VPT, const u16* __restrict__ STBF,
    u16* __restrict__ ATT)
{
    const int b = blockIdx.x, c = blockIdx.y, ri = blockIdx.z;
    const int lane = threadIdx.x;
    const int l31 = lane & 31, s = lane >> 5;
    const size_t chunk0 = (size_t)b * 2048 + (size_t)c * 256;
    const u16* stb = STBF + (size_t)(b * 8 + c) * 16640;

#pragma unroll
    for (int fi = 0; fi < 2; ++fi) {
        const int qc = ri * 64 + fi * 32 + l31;   // chunk-local q row
        // ---- Q fragments (reused by inter A-role and QK B-role; same layout)
        s16x8 qf[16];
        const u16* qp = PHIQ + (chunk0 + qc) * 256 + s * 8;
#pragma unroll
        for (int ds = 0; ds < 16; ++ds)
            qf[ds] = *(const s16x8*)(qp + ds * 16);

        f32x16v o[2];
#pragma unroll
        for (int e = 0; e < 16; ++e) { o[0][e] = 0.f; o[1][e] = 0.f; }
        float den = 0.f;

        // ---- inter: o += Q . S^T ; den += Q . z
#pragma unroll
        for (int ds = 0; ds < 16; ++ds) {
            const s16x8 zf = *(const s16x8*)(stb + 16384 + ds * 16 + s * 8);
#pragma unroll
            for (int e = 0; e < 8; ++e)
                den += bf2f((u16)qf[ds][e]) * bf2f((u16)zf[e]);
#pragma unroll
            for (int fh = 0; fh < 2; ++fh) {
                const s16x8 sx = *(const s16x8*)(stb + (fh * 32 + l31) * 256 + ds * 16 + s * 8);
                o[fh] = __builtin_amdgcn_mfma_f32_32x32x16_bf16(qf[ds], sx, o[fh], 0, 0, 0);
            }
        }

        // ---- intra: swapped QK^T over 32-row k-blocks
        const int kbmax = ri * 2 + fi;
        for (int kb = 0; kb <= kbmax; ++kb) {
            // V fragments (global, from vpt): vf[kh][fh]
            s16x8 vf[2][2];
#pragma unroll
            for (int kh = 0; kh < 2; ++kh)
#pragma unroll
                for (int fh = 0; fh < 2; ++fh)
                    vf[kh][fh] = *(const s16x8*)(VPT + ((size_t)b * 64 + fh * 32 + l31) * 2048
                                                 + c * 256 + kb * 32 + kh * 16 + s * 8);
            // P^T = K . Q^T : D (q=l31, k=(reg&3)+8*(reg>>2)+4*s)
            f32x16v p;
#pragma unroll
            for (int e = 0; e < 16; ++e) p[e] = 0.f;
            const u16* kp = PHIK + (chunk0 + kb * 32 + l31) * 256 + s * 8;
#pragma unroll
            for (int ds = 0; ds < 16; ++ds) {
                const s16x8 kf = *(const s16x8*)(kp + ds * 16);
                p = __builtin_amdgcn_mfma_f32_32x32x16_bf16(kf, qf[ds], p, 0, 0, 0);
            }
            // mask (diag block only) + rowsum
            const bool diag = (kb == kbmax);
            float rsum = 0.f;
#pragma unroll
            for (int reg = 0; reg < 16; ++reg) {
                if (diag) {
                    const int kc = kb * 32 + (reg & 3) + 8 * (reg >> 2) + 4 * s;
                    if (kc > qc) p[reg] = 0.f;
                }
                rsum += p[reg];
            }
            den += rsum;
            // pack to PV A-fragments: frag[kh] needs group g=2kh+s from both lane halves
#pragma unroll
            for (int kh = 0; kh < 2; ++kh) {
                const u32 pA_lo = cvtpk(p[8*kh + 0], p[8*kh + 1]);   // group 2kh   (k&3 = 0,1)
                const u32 pA_hi = cvtpk(p[8*kh + 2], p[8*kh + 3]);   //             (k&3 = 2,3)
                const u32 pB_lo = cvtpk(p[8*kh + 4], p[8*kh + 5]);   // group 2kh+1
                const u32 pB_hi = cvtpk(p[8*kh + 6], p[8*kh + 7]);
                const u32 X_lo = s ? pB_lo : pA_lo;   // own-half, group 2kh+s
                const u32 X_hi = s ? pB_hi : pA_hi;
                const u32 Y_lo = s ? pA_lo : pB_lo;   // what the OTHER half needs from me
                const u32 Y_hi = s ? pA_hi : pB_hi;
                const u32 sY_lo = __shfl_xor((int)Y_lo, 32);
                const u32 sY_hi = __shfl_xor((int)Y_hi, 32);
                u32 w[4];
                w[0] = s ? sY_lo : X_lo;   // k-slot e=0,1 (s'=0 part)
                w[1] = s ? sY_hi : X_hi;   // e=2,3
                w[2] = s ? X_lo : sY_lo;   // e=4,5 (s'=1 part)
                w[3] = s ? X_hi : sY_hi;   // e=6,7
                s16x8 pa;
#pragma unroll
                for (int i = 0; i < 4; ++i) {
                    pa[2*i]   = (short)(w[i] & 0xffff);
                    pa[2*i+1] = (short)(w[i] >> 16);
                }
                o[0] = __builtin_amdgcn_mfma_f32_32x32x16_bf16(pa, vf[kh][0], o[0], 0, 0, 0);
                o[1] = __builtin_amdgcn_mfma_f32_32x32x16_bf16(pa, vf[kh][1], o[1], 0, 0, 0);
            }
        }

        // ---- epilogue: complete den, divide, write bf16 attn
        const float denT = den + __shfl_xor(den, 32);   // den[q=l31], all lanes
#pragma unroll
        for (int reg = 0; reg < 16; ++reg) {
            const int q32 = (reg & 3) + 8 * (reg >> 2) + 4 * s;   // q-within-32 for this D row
            const float dv = __shfl(denT, q32);                   // den for that q (src holds l31=q32)
            const float inv = 1.f / (dv + 1e-6f);
            const int qrow = c * 256 + ri * 64 + fi * 32 + q32;   // b-local sequence row
            const size_t abase = (size_t)qrow * 4096 + b * 64;
            ATT[abase + l31]      = f2bf(o[0][reg] * inv);
            ATT[abase + 32 + l31] = f2bf(o[1][reg] * inv);
        }
    }
}

// ---------------------------------------------------------------------------
extern "C" void kernel_launch(void* const* d_in, const int* in_sizes, int n_in,
                              void* d_out, int out_size, void* d_ws, size_t ws_size,
                              hipStream_t stream)
{
    const float* query = (const float*)d_in[0];
    const float* key   = (const float*)d_in[1];
    const float* value = (const float*)d_in[2];
    const float* wq    = (const float*)d_in[3];
    const float* bq    = (const float*)d_in[4];
    const float* wk    = (const float*)d_in[5];
    const float* bk    = (const float*)d_in[6];
    const float* wv    = (const float*)d_in[7];
    const float* bv    = (const float*)d_in[8];
    const float* wo    = (const float*)d_in[9];
    const float* bo    = (const float*)d_in[10];
    const float* rm    = (const float*)d_in[11];
    float* out = (float*)d_out;

    // Workspace (202,113,024 B total, well under proven 235.9 MB):
    char* base = (char*)d_ws;
    u16*   phiq = (u16*)(base);                   //  67,108,864 B
    u16*   phik = (u16*)(base +  67108864);       //  67,108,864 B
    u16*   vpt  = (u16*)(base + 134217728);       //  16,777,216 B  (V^T: [(b*64+hd)][2048 k])
    u16*   stbf = (u16*)(base + 150994944);       //  17,039,360 B  (bf16 prefix states + z)
    char*  shared = base + 168034304;             //  34,078,720 B  (tmp f32 / st f32 / attn bf16)
    float* tmp  = (float*)shared;
    float* st   = (float*)shared;
    u16*   attn = (u16*)shared;

    const dim3 blk(256);
    gemm_mfma<false, 0><<<dim3(64, 8), blk, 0, stream>>>(query, wq, bq, tmp);
    rand_project<<<dim3(16, 128), blk, 0, stream>>>(tmp, rm, phiq);
    gemm_mfma<false, 0><<<dim3(64, 8), blk, 0, stream>>>(key, wk, bk, tmp);
    rand_project<<<dim3(16, 128), blk, 0, stream>>>(tmp, rm, phik);
    gemm_mfma<false, 2><<<dim3(64, 8), blk, 0, stream>>>(value, wv, bv, vpt);
    chunk_state_mfma<<<dim3(64, 16), blk, 0, stream>>>(phik, vpt, st);
    prefix_scan<<<dim3(64, 65), blk, 0, stream>>>(st, stbf);
    causal_fused<<<dim3(64, 8, 4), dim3(64), 0, stream>>>(phiq, phik, vpt, stbf, attn);
    gemm_mfma<true, 0><<<dim3(64, 8), blk, 0, stream>>>(attn, wo, bo, out);
}

// Round 7
// 414.243 us; speedup vs baseline: 4.5115x; 1.0566x over previous
//
#include <hip/hip_runtime.h>
#include <math.h>

// Dims: L=2048 N=4 E=1024 H=16 D=128 HD=64; 2D=256; M=L*N=8192; B=64
// phi natural (l,n,h,d) flat order == reference's scrambled (b,l',d) view.
// attn row mapping: flat l*4096 + b*64 + hd == (l*4+nb)*1024 + (h16*64+hd), b=nb*16+h16.
// Chunked causal: CHK=256, NC=8. Causal core: single LDS-free fused kernel.

typedef unsigned short u16;
typedef unsigned int u32;
using f32x4v  = __attribute__((ext_vector_type(4))) float;
using f32x16v = __attribute__((ext_vector_type(16))) float;
using s16x8   = __attribute__((ext_vector_type(8))) short;

__device__ __forceinline__ float bf2f(u16 u) { return __uint_as_float(((u32)u) << 16); }
__device__ __forceinline__ u16 f2bf(float x) {
    u32 b = __float_as_uint(x);
    b += 0x7fff + ((b >> 16) & 1);          // RNE
    return (u16)(b >> 16);
}
__device__ __forceinline__ u32 cvtpk(float lo, float hi) {
    u32 r;
    asm("v_cvt_pk_bf16_f32 %0, %1, %2" : "=v"(r) : "v"(lo), "v"(hi));
    return r;
}
// async global->LDS, 16B per lane; LDS dest is wave-uniform base + lane*16
__device__ __forceinline__ void gload_lds16(const void* g, void* l) {
    __builtin_amdgcn_global_load_lds(
        (const __attribute__((address_space(1))) void*)g,
        (__attribute__((address_space(3))) void*)l, 16, 0, 0);
}

// ---------------------------------------------------------------------------
// f32 -> bf16 converters (8 elems/thread, exact grids)
__global__ __launch_bounds__(256) void cvt_x_bf16(
    const float* __restrict__ q, const float* __restrict__ k,
    const float* __restrict__ v, u16* __restrict__ dst)
{
    const float* src = (blockIdx.y == 0) ? q : (blockIdx.y == 1) ? k : v;
    u16* d = dst + (size_t)blockIdx.y * 8388608;
    const size_t i = ((size_t)blockIdx.x * 256 + threadIdx.x) * 8;
    const float4 a = *(const float4*)(src + i);
    const float4 b = *(const float4*)(src + i + 4);
    u16 o[8] = {f2bf(a.x), f2bf(a.y), f2bf(a.z), f2bf(a.w),
                f2bf(b.x), f2bf(b.y), f2bf(b.z), f2bf(b.w)};
    *(uint4*)(d + i) = *(uint4*)o;
}

__global__ __launch_bounds__(256) void cvt_w_bf16(
    const float* __restrict__ w0, const float* __restrict__ w1,
    const float* __restrict__ w2, const float* __restrict__ w3,
    u16* __restrict__ dst)
{
    const float* src = (blockIdx.y == 0) ? w0 : (blockIdx.y == 1) ? w1
                     : (blockIdx.y == 2) ? w2 : w3;
    u16* d = dst + (size_t)blockIdx.y * 1048576;
    const size_t i = ((size_t)blockIdx.x * 256 + threadIdx.x) * 8;
    const float4 a = *(const float4*)(src + i);
    const float4 b = *(const float4*)(src + i + 4);
    u16 o[8] = {f2bf(a.x), f2bf(a.y), f2bf(a.z), f2bf(a.w),
                f2bf(b.x), f2bf(b.y), f2bf(b.z), f2bf(b.w)};
    *(uint4*)(d + i) = *(uint4*)o;
}

// ---------------------------------------------------------------------------
// bf16 NT GEMM with global_load_lds staging (m97 structure).
// C[m][n] = sum_k A[m][k]*B[n][k] + bias[n]; M=8192, N=1024, K=1024.
// OMODE: 0 = f32 row-major, 2 = bf16 vpt[(b*64+hd)*2048 + k]
template<int OMODE>
__global__ __launch_bounds__(256) void gemm_bf16(
    const u16* __restrict__ A, const u16* __restrict__ Bw,
    const float* __restrict__ bias, void* __restrict__ Cp)
{
    __shared__ __align__(16) u16 As[4096];   // [128][32] linear
    __shared__ __align__(16) u16 Bs[4096];
    const int t = threadIdx.x;
    const int m0 = blockIdx.x * 128, n0 = blockIdx.y * 128;
    const int wid = t >> 6, lane = t & 63;
    const int wr = wid >> 1, wc = wid & 1;
    const int l15 = lane & 15, l4 = lane >> 4;

    f32x4v acc[4][4];
#pragma unroll
    for (int i = 0; i < 4; ++i)
#pragma unroll
        for (int j = 0; j < 4; ++j)
#pragma unroll
            for (int e = 0; e < 4; ++e) acc[i][j][e] = 0.f;

    // staging: wave wid covers rows [wid*32, wid*32+32) in two 16-row instrs.
    // lane l -> row wid*32 + i*16 + (l>>2), u16 col (l&3)*8; LDS linear = base + l*16B.
    const int srow = wid * 32 + (lane >> 2);
    const int scol = (lane & 3) * 8;
    const u16* ga0 = A  + (size_t)(m0 + srow) * 1024 + scol;
    const u16* ga1 = ga0 + 16 * 1024;
    const u16* gb0 = Bw + (size_t)(n0 + srow) * 1024 + scol;
    const u16* gb1 = gb0 + 16 * 1024;
    u16* la0 = &As[wid * 1024];
    u16* la1 = la0 + 512;
    u16* lb0 = &Bs[wid * 1024];
    u16* lb1 = lb0 + 512;

    for (int k0 = 0; k0 < 1024; k0 += 32) {
        __syncthreads();
        gload_lds16(ga0 + k0, la0);
        gload_lds16(ga1 + k0, la1);
        gload_lds16(gb0 + k0, lb0);
        gload_lds16(gb1 + k0, lb1);
        __syncthreads();
        s16x8 af[4], bfr[4];
#pragma unroll
        for (int fi = 0; fi < 4; ++fi)
            af[fi] = *(const s16x8*)&As[(wr * 64 + fi * 16 + l15) * 32 + l4 * 8];
#pragma unroll
        for (int fj = 0; fj < 4; ++fj)
            bfr[fj] = *(const s16x8*)&Bs[(wc * 64 + fj * 16 + l15) * 32 + l4 * 8];
#pragma unroll
        for (int fi = 0; fi < 4; ++fi)
#pragma unroll
            for (int fj = 0; fj < 4; ++fj)
                acc[fi][fj] = __builtin_amdgcn_mfma_f32_16x16x32_bf16(af[fi], bfr[fj], acc[fi][fj], 0, 0, 0);
    }

    const int rl = l4 * 4, cl = l15;
    float bvals[4];
#pragma unroll
    for (int fj = 0; fj < 4; ++fj) bvals[fj] = bias[n0 + wc * 64 + fj * 16 + cl];
#pragma unroll
    for (int fi = 0; fi < 4; ++fi)
#pragma unroll
        for (int j = 0; j < 4; ++j) {
            const size_t m = m0 + wr * 64 + fi * 16 + rl + j;
#pragma unroll
            for (int fj = 0; fj < 4; ++fj) {
                const int n = n0 + wc * 64 + fj * 16 + cl;
                const float v = acc[fi][fj][j] + bvals[fj];
                if (OMODE == 0) ((float*)Cp)[m * 1024 + n] = v;
                else {
                    // vpt[(b*64+hd)*2048 + k]; b=(m&3)*16+(n>>6), hd=n&63, k=m>>2
                    ((u16*)Cp)[((size_t)((m & 3) * 16 + (n >> 6)) * 64 + (n & 63)) * 2048 + (m >> 2)] = f2bf(v);
                }
            }
        }
}

// ---------------------------------------------------------------------------
__global__ __launch_bounds__(256) void rand_project(
    const float* __restrict__ X, const float* __restrict__ RM, u16* __restrict__ PHI)
{
    __shared__ float Xs[64][68];
    __shared__ float RMs[128][68];
    __shared__ float rsc[64];
    const int h  = blockIdx.x;
    const int r0 = blockIdx.y * 64;
    const int t  = threadIdx.x;
#pragma unroll
    for (int i = 0; i < 16; ++i) {
        const int lin = t + i * 256;
        const int r = lin >> 6, c = lin & 63;
        Xs[r][c] = X[(size_t)(r0 + r) * 1024 + h * 64 + c];
    }
#pragma unroll
    for (int i = 0; i < 32; ++i) {
        const int lin = t + i * 256;
        const int d = lin >> 6, c = lin & 63;
        RMs[d][c] = RM[((size_t)h * 128 + d) * 64 + c];
    }
    __syncthreads();
    if (t < 64) {
        float s = 0.f;
#pragma unroll
        for (int c = 0; c < 64; ++c) { const float v = Xs[t][c]; s += v * v; }
        rsc[t] = 1.f / fmaxf(sqrtf(s), 1e-12f);
    }
    __syncthreads();
    const int rr = (t >> 4) * 4;
    const int dc = t & 15;
    float acc[4][8];
#pragma unroll
    for (int i = 0; i < 4; ++i)
#pragma unroll
        for (int j = 0; j < 8; ++j) acc[i][j] = 0.f;
    for (int c = 0; c < 64; c += 4) {
        float4 xv[4], rv[8];
#pragma unroll
        for (int i = 0; i < 4; ++i) xv[i] = *(const float4*)&Xs[rr + i][c];
#pragma unroll
        for (int j = 0; j < 8; ++j) rv[j] = *(const float4*)&RMs[dc + 16 * j][c];
#pragma unroll
        for (int i = 0; i < 4; ++i)
#pragma unroll
            for (int j = 0; j < 8; ++j)
                acc[i][j] += xv[i].x*rv[j].x + xv[i].y*rv[j].y + xv[i].z*rv[j].z + xv[i].w*rv[j].w;
    }
#pragma unroll
    for (int i = 0; i < 4; ++i) {
        const float sc = rsc[rr + i];
        const size_t base = ((size_t)(r0 + rr + i) * 16 + h) * 256;
#pragma unroll
        for (int j = 0; j < 8; ++j) {
            const float xt = acc[i][j] * sc;
            const int d = dc + 16 * j;
            PHI[base + d]       = f2bf(0.0625f * expf(xt));
            PHI[base + 128 + d] = f2bf(0.0625f * expf(-xt));
        }
    }
}

// ---------------------------------------------------------------------------
// Chunk state via MFMA. Block (b, c, dh): OUT[m=h 0..63][n=d 0..127 of half dh]
// = sum_{r<256} V[r][h]*K[r][d]; plus z[d] = sum_r K[r][d]. V frags direct from vpt.
__global__ __launch_bounds__(256) void chunk_state_mfma(
    const u16* __restrict__ PHIK, const u16* __restrict__ VPT, float* __restrict__ ST)
{
    __shared__ __align__(16) u16 Ks[64 * 136];    // [r][128 d + pad], swizzled 16B blocks
    __shared__ float zlds[16][132];
    const int b = blockIdx.x;
    const int c = blockIdx.y >> 1;
    const int dh = blockIdx.y & 1;
    const int t = threadIdx.x;
    const int wid = t >> 6, lane = t & 63;
    const int l15 = lane & 15, l4 = lane >> 4;
    const int wr = wid >> 1, wc = wid & 1;

    const size_t R0 = (size_t)b * 2048 + (size_t)c * 256;
    const int rgrp = t >> 4, d08 = (t & 15) * 8;

    float zpart[8];
#pragma unroll
    for (int i = 0; i < 8; ++i) zpart[i] = 0.f;

    f32x4v acc[2][4];
#pragma unroll
    for (int i = 0; i < 2; ++i)
#pragma unroll
        for (int j = 0; j < 4; ++j)
#pragma unroll
            for (int e = 0; e < 4; ++e) acc[i][j][e] = 0.f;

    for (int stage = 0; stage < 4; ++stage) {
        __syncthreads();
#pragma unroll
        for (int j = 0; j < 4; ++j) {
            const int r = rgrp + 16 * j;
            const uint4 v = *(const uint4*)(PHIK + (R0 + stage * 64 + r) * 256 + dh * 128 + d08);
            const int x = ((r >> 3) & 3) << 1;
            *(uint4*)&Ks[r * 136 + (((d08 >> 3) ^ x) << 3)] = v;
            const u16* pv = (const u16*)&v;
#pragma unroll
            for (int i = 0; i < 8; ++i) zpart[i] += bf2f(pv[i]);
        }
        __syncthreads();
#pragma unroll
        for (int ks = 0; ks < 2; ++ks) {
            const int xk = ((ks * 4 + l4) & 3) << 1;
            const int r0 = ks * 32 + l4 * 8;
            s16x8 af[2], bk[4];
#pragma unroll
            for (int fi = 0; fi < 2; ++fi) {
                const int h = wr * 32 + fi * 16 + l15;
                af[fi] = *(const s16x8*)(VPT + ((size_t)b * 64 + h) * 2048 + c * 256 + stage * 64 + ks * 32 + l4 * 8);
            }
#pragma unroll
            for (int fj = 0; fj < 4; ++fj) {
                const int d = wc * 64 + fj * 16 + l15;
                const int colk = (((d >> 3) ^ xk) << 3) + (d & 7);
#pragma unroll
                for (int e = 0; e < 8; ++e)
                    bk[fj][e] = (short)Ks[(r0 + e) * 136 + colk];
            }
#pragma unroll
            for (int fi = 0; fi < 2; ++fi)
#pragma unroll
                for (int fj = 0; fj < 4; ++fj)
                    acc[fi][fj] = __builtin_amdgcn_mfma_f32_16x16x32_bf16(af[fi], bk[fj], acc[fi][fj], 0, 0, 0);
        }
    }
    __syncthreads();
    *(float4*)&zlds[rgrp][d08]     = *(float4*)&zpart[0];
    *(float4*)&zlds[rgrp][d08 + 4] = *(float4*)&zpart[4];
    __syncthreads();
    float* st = ST + (size_t)(b * 8 + c) * 16640;
    if (t < 128) {
        float z = 0.f;
#pragma unroll
        for (int g = 0; g < 16; ++g) z += zlds[g][t];
        st[16384 + dh * 128 + t] = z;
    }
#pragma unroll
    for (int fi = 0; fi < 2; ++fi)
#pragma unroll
        for (int reg = 0; reg < 4; ++reg) {
            const int h = wr * 32 + fi * 16 + l4 * 4 + reg;
#pragma unroll
            for (int fj = 0; fj < 4; ++fj) {
                const int d = dh * 128 + wc * 64 + fj * 16 + l15;
                st[(size_t)h * 256 + d] = acc[fi][fj][reg];
            }
        }
}

// ---------------------------------------------------------------------------
// Exclusive prefix over 8 chunks -> bf16 stbf[(b*8+c)*16640 + e]
__global__ void prefix_scan(const float* __restrict__ ST, u16* __restrict__ STBF)
{
    const int b = blockIdx.x;
    const int e = blockIdx.y * 256 + threadIdx.x;
    if (e >= 16640) return;
    const size_t base = (size_t)b * 8 * 16640 + e;
    float run = 0.f;
#pragma unroll
    for (int c = 0; c < 8; ++c) {
        const float v = ST[base + (size_t)c * 16640];
        STBF[(size_t)(b * 8 + c) * 16640 + e] = f2bf(run);
        run += v;
    }
}

// ---------------------------------------------------------------------------
// Fused causal kernel (LDS-free, barrier-free). Grid (rf, b, c), 64-thr blocks.
// rf = ri*2+fi: wave owns q-rows [ri*64+fi*32, +32) of chunk c.
__global__ __launch_bounds__(64) void causal_fused(
    const u16* __restrict__ PHIQ, const u16* __restrict__ PHIK,
    const u16* __restrict__ VPT, const u16* __restrict__ STBF,
    u16* __restrict__ ATT)
{
    const int rf = blockIdx.x, b = blockIdx.y, c = blockIdx.z;
    const int ri = rf >> 1, fi = rf & 1;
    const int lane = threadIdx.x;
    const int l31 = lane & 31, s = lane >> 5;
    const size_t chunk0 = (size_t)b * 2048 + (size_t)c * 256;
    const u16* stb = STBF + (size_t)(b * 8 + c) * 16640;

    const int qc = ri * 64 + fi * 32 + l31;       // chunk-local q row
    s16x8 qf[16];
    const u16* qp = PHIQ + (chunk0 + qc) * 256 + s * 8;
#pragma unroll
    for (int ds = 0; ds < 16; ++ds)
        qf[ds] = *(const s16x8*)(qp + ds * 16);

    f32x16v o[2];
#pragma unroll
    for (int e = 0; e < 16; ++e) { o[0][e] = 0.f; o[1][e] = 0.f; }
    float den = 0.f;

    // ---- inter: o += Q . S^T ; den += Q . z
#pragma unroll
    for (int ds = 0; ds < 16; ++ds) {
        const s16x8 zf = *(const s16x8*)(stb + 16384 + ds * 16 + s * 8);
#pragma unroll
        for (int e = 0; e < 8; ++e)
            den += bf2f((u16)qf[ds][e]) * bf2f((u16)zf[e]);
#pragma unroll
        for (int fh = 0; fh < 2; ++fh) {
            const s16x8 sx = *(const s16x8*)(stb + (fh * 32 + l31) * 256 + ds * 16 + s * 8);
            o[fh] = __builtin_amdgcn_mfma_f32_32x32x16_bf16(qf[ds], sx, o[fh], 0, 0, 0);
        }
    }

    // ---- intra: swapped QK^T over 32-row k-blocks
    const int kbmax = ri * 2 + fi;
    for (int kb = 0; kb <= kbmax; ++kb) {
        s16x8 vf[2][2];
#pragma unroll
        for (int kh = 0; kh < 2; ++kh)
#pragma unroll
            for (int fh = 0; fh < 2; ++fh)
                vf[kh][fh] = *(const s16x8*)(VPT + ((size_t)b * 64 + fh * 32 + l31) * 2048
                                             + c * 256 + kb * 32 + kh * 16 + s * 8);
        // P^T = K . Q^T : D (q=l31, k=(reg&3)+8*(reg>>2)+4*s)
        f32x16v p;
#pragma unroll
        for (int e = 0; e < 16; ++e) p[e] = 0.f;
        const u16* kp = PHIK + (chunk0 + kb * 32 + l31) * 256 + s * 8;
#pragma unroll
        for (int ds = 0; ds < 16; ++ds) {
            const s16x8 kf = *(const s16x8*)(kp + ds * 16);
            p = __builtin_amdgcn_mfma_f32_32x32x16_bf16(kf, qf[ds], p, 0, 0, 0);
        }
        const bool diag = (kb == kbmax);
        float rsum = 0.f;
#pragma unroll
        for (int reg = 0; reg < 16; ++reg) {
            if (diag) {
                const int kc = kb * 32 + (reg & 3) + 8 * (reg >> 2) + 4 * s;
                if (kc > qc) p[reg] = 0.f;
            }
            rsum += p[reg];
        }
        den += rsum;
        // pack to PV A-fragments: frag[kh] needs group g=2kh+s from both lane halves
#pragma unroll
        for (int kh = 0; kh < 2; ++kh) {
            const u32 pA_lo = cvtpk(p[8*kh + 0], p[8*kh + 1]);
            const u32 pA_hi = cvtpk(p[8*kh + 2], p[8*kh + 3]);
            const u32 pB_lo = cvtpk(p[8*kh + 4], p[8*kh + 5]);
            const u32 pB_hi = cvtpk(p[8*kh + 6], p[8*kh + 7]);
            const u32 X_lo = s ? pB_lo : pA_lo;
            const u32 X_hi = s ? pB_hi : pA_hi;
            const u32 Y_lo = s ? pA_lo : pB_lo;
            const u32 Y_hi = s ? pA_hi : pB_hi;
            const u32 sY_lo = __shfl_xor((int)Y_lo, 32);
            const u32 sY_hi = __shfl_xor((int)Y_hi, 32);
            u32 w[4];
            w[0] = s ? sY_lo : X_lo;
            w[1] = s ? sY_hi : X_hi;
            w[2] = s ? X_lo : sY_lo;
            w[3] = s ? X_hi : sY_hi;
            s16x8 pa;
#pragma unroll
            for (int i = 0; i < 4; ++i) {
                pa[2*i]   = (short)(w[i] & 0xffff);
                pa[2*i+1] = (short)(w[i] >> 16);
            }
            o[0] = __builtin_amdgcn_mfma_f32_32x32x16_bf16(pa, vf[kh][0], o[0], 0, 0, 0);
            o[1] = __builtin_amdgcn_mfma_f32_32x32x16_bf16(pa, vf[kh][1], o[1], 0, 0, 0);
        }
    }

    // ---- epilogue
    const float denT = den + __shfl_xor(den, 32);
#pragma unroll
    for (int reg = 0; reg < 16; ++reg) {
        const int q32 = (reg & 3) + 8 * (reg >> 2) + 4 * s;
        const float dv = __shfl(denT, q32);
        const float inv = 1.f / (dv + 1e-6f);
        const int qrow = c * 256 + ri * 64 + fi * 32 + q32;
        const size_t abase = (size_t)qrow * 4096 + b * 64;
        ATT[abase + l31]      = f2bf(o[0][reg] * inv);
        ATT[abase + 32 + l31] = f2bf(o[1][reg] * inv);
    }
}

// ---------------------------------------------------------------------------
extern "C" void kernel_launch(void* const* d_in, const int* in_sizes, int n_in,
                              void* d_out, int out_size, void* d_ws, size_t ws_size,
                              hipStream_t stream)
{
    const float* query = (const float*)d_in[0];
    const float* key   = (const float*)d_in[1];
    const float* value = (const float*)d_in[2];
    const float* wq    = (const float*)d_in[3];
    const float* bq    = (const float*)d_in[4];
    const float* wk    = (const float*)d_in[5];
    const float* bk    = (const float*)d_in[6];
    const float* wv    = (const float*)d_in[7];
    const float* bv    = (const float*)d_in[8];
    const float* wo    = (const float*)d_in[9];
    const float* bo    = (const float*)d_in[10];
    const float* rm    = (const float*)d_in[11];
    float* out = (float*)d_out;

    // Workspace (226,754,560 B total <= proven 235,929,600 B), with overlays:
    //   tmp (f32 q/k proj) overlays vpt+stbf (written later)
    //   st (f32 states) and attn overlay xbf3 (dead after GEMM-v)
    char* base = (char*)d_ws;
    u16*   phiq = (u16*)(base);                   //  67,108,864
    u16*   phik = (u16*)(base +  67108864);       //  67,108,864
    u16*   vpt  = (u16*)(base + 134217728);       //  16,777,216
    u16*   stbf = (u16*)(base + 150994944);       //  17,039,360
    float* tmp  = (float*)(base + 134217728);     //  33,554,432 (overlay, dead early)
    u16*   xbf  = (u16*)(base + 168034304);       //  50,331,648 (q,k,v bf16)
    float* st   = (float*)(base + 168034304);     //  34,078,720 (overlay)
    u16*   attn = (u16*)(base + 168034304);       //  16,777,216 (overlay)
    u16*   wbf  = (u16*)(base + 218365952);       //   8,388,608 (4 weights bf16)

    u16* xq = xbf;
    u16* xk = xbf +  8388608;
    u16* xv = xbf + 16777216;
    u16* wqb = wbf;
    u16* wkb = wbf + 1048576;
    u16* wvb = wbf + 2097152;
    u16* wob = wbf + 3145728;

    const dim3 blk(256);
    cvt_x_bf16<<<dim3(4096, 3), blk, 0, stream>>>(query, key, value, xbf);
    cvt_w_bf16<<<dim3(512, 4), blk, 0, stream>>>(wq, wk, wv, wo, wbf);
    gemm_bf16<0><<<dim3(64, 8), blk, 0, stream>>>(xq, wqb, bq, tmp);
    rand_project<<<dim3(16, 128), blk, 0, stream>>>(tmp, rm, phiq);
    gemm_bf16<0><<<dim3(64, 8), blk, 0, stream>>>(xk, wkb, bk, tmp);
    rand_project<<<dim3(16, 128), blk, 0, stream>>>(tmp, rm, phik);
    gemm_bf16<2><<<dim3(64, 8), blk, 0, stream>>>(xv, wvb, bv, vpt);
    chunk_state_mfma<<<dim3(64, 16), blk, 0, stream>>>(phik, vpt, st);
    prefix_scan<<<dim3(64, 65), blk, 0, stream>>>(st, stbf);
    causal_fused<<<dim3(8, 64, 8), dim3(64), 0, stream>>>(phiq, phik, vpt, stbf, attn);
    gemm_bf16<0><<<dim3(64, 8), blk, 0, stream>>>(attn, wob, bo, out);
}

// Round 8
// 379.309 us; speedup vs baseline: 4.9270x; 1.0921x over previous
//
#include <hip/hip_runtime.h>
#include <math.h>

// Dims: L=2048 N=4 E=1024 H=16 D=128 HD=64; 2D=256; M=L*N=8192; B=64
// phi natural (l,n,h,d) flat order == reference's scrambled (b,l',d) view.
// attn row mapping: flat l*4096 + b*64 + hd == (l*4+nb)*1024 + (h16*64+hd), b=nb*16+h16.
// Chunked causal: CHK=256, NC=8. Causal core: LDS-free fused kernel, XCD-grouped.

typedef unsigned short u16;
typedef unsigned int u32;
using f32x4v  = __attribute__((ext_vector_type(4))) float;
using f32x16v = __attribute__((ext_vector_type(16))) float;
using s16x8   = __attribute__((ext_vector_type(8))) short;

__device__ __forceinline__ float bf2f(u16 u) { return __uint_as_float(((u32)u) << 16); }
__device__ __forceinline__ u16 f2bf(float x) {
    u32 b = __float_as_uint(x);
    b += 0x7fff + ((b >> 16) & 1);          // RNE
    return (u16)(b >> 16);
}
__device__ __forceinline__ u32 cvtpk(float lo, float hi) {
    u32 r;
    asm("v_cvt_pk_bf16_f32 %0, %1, %2" : "=v"(r) : "v"(lo), "v"(hi));
    return r;
}
// async global->LDS, 16B per lane; LDS dest is wave-uniform base + lane*16
__device__ __forceinline__ void gload_lds16(const void* g, void* l) {
    __builtin_amdgcn_global_load_lds(
        (const __attribute__((address_space(1))) void*)g,
        (__attribute__((address_space(3))) void*)l, 16, 0, 0);
}

// ---------------------------------------------------------------------------
// f32 -> bf16 converters (8 elems/thread, exact grids)
__global__ __launch_bounds__(256) void cvt_x_bf16(
    const float* __restrict__ q, const float* __restrict__ k,
    const float* __restrict__ v, u16* __restrict__ dst)
{
    const float* src = (blockIdx.y == 0) ? q : (blockIdx.y == 1) ? k : v;
    u16* d = dst + (size_t)blockIdx.y * 8388608;
    const size_t i = ((size_t)blockIdx.x * 256 + threadIdx.x) * 8;
    const float4 a = *(const float4*)(src + i);
    const float4 b = *(const float4*)(src + i + 4);
    u16 o[8] = {f2bf(a.x), f2bf(a.y), f2bf(a.z), f2bf(a.w),
                f2bf(b.x), f2bf(b.y), f2bf(b.z), f2bf(b.w)};
    *(uint4*)(d + i) = *(uint4*)o;
}

__global__ __launch_bounds__(256) void cvt_w_bf16(
    const float* __restrict__ w0, const float* __restrict__ w1,
    const float* __restrict__ w2, const float* __restrict__ w3,
    u16* __restrict__ dst)
{
    const float* src = (blockIdx.y == 0) ? w0 : (blockIdx.y == 1) ? w1
                     : (blockIdx.y == 2) ? w2 : w3;
    u16* d = dst + (size_t)blockIdx.y * 1048576;
    const size_t i = ((size_t)blockIdx.x * 256 + threadIdx.x) * 8;
    const float4 a = *(const float4*)(src + i);
    const float4 b = *(const float4*)(src + i + 4);
    u16 o[8] = {f2bf(a.x), f2bf(a.y), f2bf(a.z), f2bf(a.w),
                f2bf(b.x), f2bf(b.y), f2bf(b.z), f2bf(b.w)};
    *(uint4*)(d + i) = *(uint4*)o;
}

// ---------------------------------------------------------------------------
// bf16 NT GEMM with global_load_lds staging (m97 structure).
// C[m][n] = sum_k A[m][k]*B[n][k] + bias[n]; M=8192, N=1024, K=1024.
// OMODE: 0 = f32 row-major, 1 = bf16 row-major, 2 = bf16 vpt[(b*64+hd)*2048 + k]
template<int OMODE>
__global__ __launch_bounds__(256) void gemm_bf16(
    const u16* __restrict__ A, const u16* __restrict__ Bw,
    const float* __restrict__ bias, void* __restrict__ Cp)
{
    __shared__ __align__(16) u16 As[4096];   // [128][32] linear
    __shared__ __align__(16) u16 Bs[4096];
    const int t = threadIdx.x;
    const int m0 = blockIdx.x * 128, n0 = blockIdx.y * 128;
    const int wid = t >> 6, lane = t & 63;
    const int wr = wid >> 1, wc = wid & 1;
    const int l15 = lane & 15, l4 = lane >> 4;

    f32x4v acc[4][4];
#pragma unroll
    for (int i = 0; i < 4; ++i)
#pragma unroll
        for (int j = 0; j < 4; ++j)
#pragma unroll
            for (int e = 0; e < 4; ++e) acc[i][j][e] = 0.f;

    const int srow = wid * 32 + (lane >> 2);
    const int scol = (lane & 3) * 8;
    const u16* ga0 = A  + (size_t)(m0 + srow) * 1024 + scol;
    const u16* ga1 = ga0 + 16 * 1024;
    const u16* gb0 = Bw + (size_t)(n0 + srow) * 1024 + scol;
    const u16* gb1 = gb0 + 16 * 1024;
    u16* la0 = &As[wid * 1024];
    u16* la1 = la0 + 512;
    u16* lb0 = &Bs[wid * 1024];
    u16* lb1 = lb0 + 512;

    for (int k0 = 0; k0 < 1024; k0 += 32) {
        __syncthreads();
        gload_lds16(ga0 + k0, la0);
        gload_lds16(ga1 + k0, la1);
        gload_lds16(gb0 + k0, lb0);
        gload_lds16(gb1 + k0, lb1);
        __syncthreads();
        s16x8 af[4], bfr[4];
#pragma unroll
        for (int fi = 0; fi < 4; ++fi)
            af[fi] = *(const s16x8*)&As[(wr * 64 + fi * 16 + l15) * 32 + l4 * 8];
#pragma unroll
        for (int fj = 0; fj < 4; ++fj)
            bfr[fj] = *(const s16x8*)&Bs[(wc * 64 + fj * 16 + l15) * 32 + l4 * 8];
#pragma unroll
        for (int fi = 0; fi < 4; ++fi)
#pragma unroll
            for (int fj = 0; fj < 4; ++fj)
                acc[fi][fj] = __builtin_amdgcn_mfma_f32_16x16x32_bf16(af[fi], bfr[fj], acc[fi][fj], 0, 0, 0);
    }

    const int rl = l4 * 4, cl = l15;
    float bvals[4];
#pragma unroll
    for (int fj = 0; fj < 4; ++fj) bvals[fj] = bias[n0 + wc * 64 + fj * 16 + cl];
#pragma unroll
    for (int fi = 0; fi < 4; ++fi)
#pragma unroll
        for (int j = 0; j < 4; ++j) {
            const size_t m = m0 + wr * 64 + fi * 16 + rl + j;
#pragma unroll
            for (int fj = 0; fj < 4; ++fj) {
                const int n = n0 + wc * 64 + fj * 16 + cl;
                const float v = acc[fi][fj][j] + bvals[fj];
                if (OMODE == 0)      ((float*)Cp)[m * 1024 + n] = v;
                else if (OMODE == 1) ((u16*)Cp)[m * 1024 + n] = f2bf(v);
                else {
                    // vpt[(b*64+hd)*2048 + k]; b=(m&3)*16+(n>>6), hd=n&63, k=m>>2
                    ((u16*)Cp)[((size_t)((m & 3) * 16 + (n >> 6)) * 64 + (n & 63)) * 2048 + (m >> 2)] = f2bf(v);
                }
            }
        }
}

// ---------------------------------------------------------------------------
// Random projection; X is bf16 (projected q/k), RM f32.
__global__ __launch_bounds__(256) void rand_project(
    const u16* __restrict__ X, const float* __restrict__ RM, u16* __restrict__ PHI)
{
    __shared__ float Xs[64][68];
    __shared__ float RMs[128][68];
    __shared__ float rsc[64];
    const int h  = blockIdx.x;
    const int r0 = blockIdx.y * 64;
    const int t  = threadIdx.x;
#pragma unroll
    for (int i = 0; i < 2; ++i) {
        const int lin = t + i * 256;              // 512 = 64 rows x 8 col-octets
        const int r = lin >> 3, c8 = (lin & 7) * 8;
        const uint4 v = *(const uint4*)(X + (size_t)(r0 + r) * 1024 + h * 64 + c8);
        const u16* pv = (const u16*)&v;
#pragma unroll
        for (int e = 0; e < 8; ++e) Xs[r][c8 + e] = bf2f(pv[e]);
    }
#pragma unroll
    for (int i = 0; i < 32; ++i) {
        const int lin = t + i * 256;
        const int d = lin >> 6, c = lin & 63;
        RMs[d][c] = RM[((size_t)h * 128 + d) * 64 + c];
    }
    __syncthreads();
    if (t < 64) {
        float s = 0.f;
#pragma unroll
        for (int c = 0; c < 64; ++c) { const float v = Xs[t][c]; s += v * v; }
        rsc[t] = 1.f / fmaxf(sqrtf(s), 1e-12f);
    }
    __syncthreads();
    const int rr = (t >> 4) * 4;
    const int dc = t & 15;
    float acc[4][8];
#pragma unroll
    for (int i = 0; i < 4; ++i)
#pragma unroll
        for (int j = 0; j < 8; ++j) acc[i][j] = 0.f;
    for (int c = 0; c < 64; c += 4) {
        float4 xv[4], rv[8];
#pragma unroll
        for (int i = 0; i < 4; ++i) xv[i] = *(const float4*)&Xs[rr + i][c];
#pragma unroll
        for (int j = 0; j < 8; ++j) rv[j] = *(const float4*)&RMs[dc + 16 * j][c];
#pragma unroll
        for (int i = 0; i < 4; ++i)
#pragma unroll
            for (int j = 0; j < 8; ++j)
                acc[i][j] += xv[i].x*rv[j].x + xv[i].y*rv[j].y + xv[i].z*rv[j].z + xv[i].w*rv[j].w;
    }
#pragma unroll
    for (int i = 0; i < 4; ++i) {
        const float sc = rsc[rr + i];
        const size_t base = ((size_t)(r0 + rr + i) * 16 + h) * 256;
#pragma unroll
        for (int j = 0; j < 8; ++j) {
            const float xt = acc[i][j] * sc;
            const int d = dc + 16 * j;
            PHI[base + d]       = f2bf(0.0625f * expf(xt));
            PHI[base + 128 + d] = f2bf(0.0625f * expf(-xt));
        }
    }
}

// ---------------------------------------------------------------------------
// Chunk state via MFMA. Block (b, c, dh): OUT[m=h 0..63][n=d 0..127 of half dh]
__global__ __launch_bounds__(256) void chunk_state_mfma(
    const u16* __restrict__ PHIK, const u16* __restrict__ VPT, float* __restrict__ ST)
{
    __shared__ __align__(16) u16 Ks[64 * 136];
    __shared__ float zlds[16][132];
    const int b = blockIdx.x;
    const int c = blockIdx.y >> 1;
    const int dh = blockIdx.y & 1;
    const int t = threadIdx.x;
    const int wid = t >> 6, lane = t & 63;
    const int l15 = lane & 15, l4 = lane >> 4;
    const int wr = wid >> 1, wc = wid & 1;

    const size_t R0 = (size_t)b * 2048 + (size_t)c * 256;
    const int rgrp = t >> 4, d08 = (t & 15) * 8;

    float zpart[8];
#pragma unroll
    for (int i = 0; i < 8; ++i) zpart[i] = 0.f;

    f32x4v acc[2][4];
#pragma unroll
    for (int i = 0; i < 2; ++i)
#pragma unroll
        for (int j = 0; j < 4; ++j)
#pragma unroll
            for (int e = 0; e < 4; ++e) acc[i][j][e] = 0.f;

    for (int stage = 0; stage < 4; ++stage) {
        __syncthreads();
#pragma unroll
        for (int j = 0; j < 4; ++j) {
            const int r = rgrp + 16 * j;
            const uint4 v = *(const uint4*)(PHIK + (R0 + stage * 64 + r) * 256 + dh * 128 + d08);
            const int x = ((r >> 3) & 3) << 1;
            *(uint4*)&Ks[r * 136 + (((d08 >> 3) ^ x) << 3)] = v;
            const u16* pv = (const u16*)&v;
#pragma unroll
            for (int i = 0; i < 8; ++i) zpart[i] += bf2f(pv[i]);
        }
        __syncthreads();
#pragma unroll
        for (int ks = 0; ks < 2; ++ks) {
            const int xk = ((ks * 4 + l4) & 3) << 1;
            const int r0 = ks * 32 + l4 * 8;
            s16x8 af[2], bk[4];
#pragma unroll
            for (int fi = 0; fi < 2; ++fi) {
                const int h = wr * 32 + fi * 16 + l15;
                af[fi] = *(const s16x8*)(VPT + ((size_t)b * 64 + h) * 2048 + c * 256 + stage * 64 + ks * 32 + l4 * 8);
            }
#pragma unroll
            for (int fj = 0; fj < 4; ++fj) {
                const int d = wc * 64 + fj * 16 + l15;
                const int colk = (((d >> 3) ^ xk) << 3) + (d & 7);
#pragma unroll
                for (int e = 0; e < 8; ++e)
                    bk[fj][e] = (short)Ks[(r0 + e) * 136 + colk];
            }
#pragma unroll
            for (int fi = 0; fi < 2; ++fi)
#pragma unroll
                for (int fj = 0; fj < 4; ++fj)
                    acc[fi][fj] = __builtin_amdgcn_mfma_f32_16x16x32_bf16(af[fi], bk[fj], acc[fi][fj], 0, 0, 0);
        }
    }
    __syncthreads();
    *(float4*)&zlds[rgrp][d08]     = *(float4*)&zpart[0];
    *(float4*)&zlds[rgrp][d08 + 4] = *(float4*)&zpart[4];
    __syncthreads();
    float* st = ST + (size_t)(b * 8 + c) * 16640;
    if (t < 128) {
        float z = 0.f;
#pragma unroll
        for (int g = 0; g < 16; ++g) z += zlds[g][t];
        st[16384 + dh * 128 + t] = z;
    }
#pragma unroll
    for (int fi = 0; fi < 2; ++fi)
#pragma unroll
        for (int reg = 0; reg < 4; ++reg) {
            const int h = wr * 32 + fi * 16 + l4 * 4 + reg;
#pragma unroll
            for (int fj = 0; fj < 4; ++fj) {
                const int d = dh * 128 + wc * 64 + fj * 16 + l15;
                st[(size_t)h * 256 + d] = acc[fi][fj][reg];
            }
        }
}

// ---------------------------------------------------------------------------
// Exclusive prefix over 8 chunks -> bf16 stbf[(b*8+c)*16640 + e]
__global__ void prefix_scan(const float* __restrict__ ST, u16* __restrict__ STBF)
{
    const int b = blockIdx.x;
    const int e = blockIdx.y * 256 + threadIdx.x;
    if (e >= 16640) return;
    const size_t base = (size_t)b * 8 * 16640 + e;
    float run = 0.f;
#pragma unroll
    for (int c = 0; c < 8; ++c) {
        const float v = ST[base + (size_t)c * 16640];
        STBF[(size_t)(b * 8 + c) * 16640 + e] = f2bf(run);
        run += v;
    }
}

// ---------------------------------------------------------------------------
// Fused causal kernel (LDS-free, barrier-free). 1D grid 4096, 64-thr blocks.
// XCD-grouped decode: bid = g_hi*64 + rf*8 + g_lo, G = g_hi*8+g_lo = c*64+b.
// All 8 rf-blocks of one (b,c) share bid%8 (same XCD) and a 64-bid window
// (co-resident) -> phik/vpt/stbf reads become L2 hits.
__global__ __launch_bounds__(64) void causal_fused(
    const u16* __restrict__ PHIQ, const u16* __restrict__ PHIK,
    const u16* __restrict__ VPT, const u16* __restrict__ STBF,
    u16* __restrict__ ATT)
{
    const u32 bid = blockIdx.x;
    const int rf = (int)((bid >> 3) & 7);
    const int G  = (int)((bid >> 6) * 8 + (bid & 7));
    const int b  = G & 63;
    const int c  = G >> 6;
    const int ri = rf >> 1, fi = rf & 1;
    const int lane = threadIdx.x;
    const int l31 = lane & 31, s = lane >> 5;
    const size_t chunk0 = (size_t)b * 2048 + (size_t)c * 256;
    const u16* stb = STBF + (size_t)(b * 8 + c) * 16640;

    const int qc = ri * 64 + fi * 32 + l31;       // chunk-local q row
    s16x8 qf[16];
    const u16* qp = PHIQ + (chunk0 + qc) * 256 + s * 8;
#pragma unroll
    for (int ds = 0; ds < 16; ++ds)
        qf[ds] = *(const s16x8*)(qp + ds * 16);

    f32x16v o[2];
#pragma unroll
    for (int e = 0; e < 16; ++e) { o[0][e] = 0.f; o[1][e] = 0.f; }
    float den = 0.f;

    // ---- inter: o += Q . S^T ; den += Q . z
#pragma unroll
    for (int ds = 0; ds < 16; ++ds) {
        const s16x8 zf = *(const s16x8*)(stb + 16384 + ds * 16 + s * 8);
#pragma unroll
        for (int e = 0; e < 8; ++e)
            den += bf2f((u16)qf[ds][e]) * bf2f((u16)zf[e]);
#pragma unroll
        for (int fh = 0; fh < 2; ++fh) {
            const s16x8 sx = *(const s16x8*)(stb + (fh * 32 + l31) * 256 + ds * 16 + s * 8);
            o[fh] = __builtin_amdgcn_mfma_f32_32x32x16_bf16(qf[ds], sx, o[fh], 0, 0, 0);
        }
    }

    // ---- intra: swapped QK^T over 32-row k-blocks
    const int kbmax = ri * 2 + fi;
    for (int kb = 0; kb <= kbmax; ++kb) {
        s16x8 vf[2][2];
#pragma unroll
        for (int kh = 0; kh < 2; ++kh)
#pragma unroll
            for (int fh = 0; fh < 2; ++fh)
                vf[kh][fh] = *(const s16x8*)(VPT + ((size_t)b * 64 + fh * 32 + l31) * 2048
                                             + c * 256 + kb * 32 + kh * 16 + s * 8);
        // P^T = K . Q^T : D (q=l31, k=(reg&3)+8*(reg>>2)+4*s)
        f32x16v p;
#pragma unroll
        for (int e = 0; e < 16; ++e) p[e] = 0.f;
        const u16* kp = PHIK + (chunk0 + kb * 32 + l31) * 256 + s * 8;
#pragma unroll
        for (int ds = 0; ds < 16; ++ds) {
            const s16x8 kf = *(const s16x8*)(kp + ds * 16);
            p = __builtin_amdgcn_mfma_f32_32x32x16_bf16(kf, qf[ds], p, 0, 0, 0);
        }
        const bool diag = (kb == kbmax);
        float rsum = 0.f;
#pragma unroll
        for (int reg = 0; reg < 16; ++reg) {
            if (diag) {
                const int kc = kb * 32 + (reg & 3) + 8 * (reg >> 2) + 4 * s;
                if (kc > qc) p[reg] = 0.f;
            }
            rsum += p[reg];
        }
        den += rsum;
        // pack to PV A-fragments: frag[kh] needs group g=2kh+s from both lane halves
#pragma unroll
        for (int kh = 0; kh < 2; ++kh) {
            const u32 pA_lo = cvtpk(p[8*kh + 0], p[8*kh + 1]);
            const u32 pA_hi = cvtpk(p[8*kh + 2], p[8*kh + 3]);
            const u32 pB_lo = cvtpk(p[8*kh + 4], p[8*kh + 5]);
            const u32 pB_hi = cvtpk(p[8*kh + 6], p[8*kh + 7]);
            const u32 X_lo = s ? pB_lo : pA_lo;
            const u32 X_hi = s ? pB_hi : pA_hi;
            const u32 Y_lo = s ? pA_lo : pB_lo;
            const u32 Y_hi = s ? pA_hi : pB_hi;
            const u32 sY_lo = __shfl_xor((int)Y_lo, 32);
            const u32 sY_hi = __shfl_xor((int)Y_hi, 32);
            u32 w[4];
            w[0] = s ? sY_lo : X_lo;
            w[1] = s ? sY_hi : X_hi;
            w[2] = s ? X_lo : sY_lo;
            w[3] = s ? X_hi : sY_hi;
            s16x8 pa;
#pragma unroll
            for (int i = 0; i < 4; ++i) {
                pa[2*i]   = (short)(w[i] & 0xffff);
                pa[2*i+1] = (short)(w[i] >> 16);
            }
            o[0] = __builtin_amdgcn_mfma_f32_32x32x16_bf16(pa, vf[kh][0], o[0], 0, 0, 0);
            o[1] = __builtin_amdgcn_mfma_f32_32x32x16_bf16(pa, vf[kh][1], o[1], 0, 0, 0);
        }
    }

    // ---- epilogue
    const float denT = den + __shfl_xor(den, 32);
#pragma unroll
    for (int reg = 0; reg < 16; ++reg) {
        const int q32 = (reg & 3) + 8 * (reg >> 2) + 4 * s;
        const float dv = __shfl(denT, q32);
        const float inv = 1.f / (dv + 1e-6f);
        const int qrow = c * 256 + ri * 64 + fi * 32 + q32;
        const size_t abase = (size_t)qrow * 4096 + b * 64;
        ATT[abase + l31]      = f2bf(o[0][reg] * inv);
        ATT[abase + 32 + l31] = f2bf(o[1][reg] * inv);
    }
}

// ---------------------------------------------------------------------------
extern "C" void kernel_launch(void* const* d_in, const int* in_sizes, int n_in,
                              void* d_out, int out_size, void* d_ws, size_t ws_size,
                              hipStream_t stream)
{
    const float* query = (const float*)d_in[0];
    const float* key   = (const float*)d_in[1];
    const float* value = (const float*)d_in[2];
    const float* wq    = (const float*)d_in[3];
    const float* bq    = (const float*)d_in[4];
    const float* wk    = (const float*)d_in[5];
    const float* bk    = (const float*)d_in[6];
    const float* wv    = (const float*)d_in[7];
    const float* bv    = (const float*)d_in[8];
    const float* wo    = (const float*)d_in[9];
    const float* bo    = (const float*)d_in[10];
    const float* rm    = (const float*)d_in[11];
    float* out = (float*)d_out;

    // Workspace (226,754,560 B total <= proven 235,929,600 B), overlays:
    //   tmpb (bf16 q/k proj, 16 MB) overlays vpt (written later)
    //   st (f32 states) and attn overlay xbf (dead after GEMM-v)
    char* base = (char*)d_ws;
    u16*   phiq = (u16*)(base);                   //  67,108,864
    u16*   phik = (u16*)(base +  67108864);       //  67,108,864
    u16*   vpt  = (u16*)(base + 134217728);       //  16,777,216
    u16*   tmpb = (u16*)(base + 134217728);       //  16,777,216 (overlay, dead early)
    u16*   stbf = (u16*)(base + 150994944);       //  17,039,360
    u16*   xbf  = (u16*)(base + 168034304);       //  50,331,648 (q,k,v bf16)
    float* st   = (float*)(base + 168034304);     //  34,078,720 (overlay)
    u16*   attn = (u16*)(base + 168034304);       //  16,777,216 (overlay)
    u16*   wbf  = (u16*)(base + 218365952);       //   8,388,608 (4 weights bf16)

    u16* xq = xbf;
    u16* xk = xbf +  8388608;
    u16* xv = xbf + 16777216;
    u16* wqb = wbf;
    u16* wkb = wbf + 1048576;
    u16* wvb = wbf + 2097152;
    u16* wob = wbf + 3145728;

    const dim3 blk(256);
    cvt_x_bf16<<<dim3(4096, 3), blk, 0, stream>>>(query, key, value, xbf);
    cvt_w_bf16<<<dim3(512, 4), blk, 0, stream>>>(wq, wk, wv, wo, wbf);
    gemm_bf16<1><<<dim3(64, 8), blk, 0, stream>>>(xq, wqb, bq, tmpb);
    rand_project<<<dim3(16, 128), blk, 0, stream>>>(tmpb, rm, phiq);
    gemm_bf16<1><<<dim3(64, 8), blk, 0, stream>>>(xk, wkb, bk, tmpb);
    rand_project<<<dim3(16, 128), blk, 0, stream>>>(tmpb, rm, phik);
    gemm_bf16<2><<<dim3(64, 8), blk, 0, stream>>>(xv, wvb, bv, vpt);
    chunk_state_mfma<<<dim3(64, 16), blk, 0, stream>>>(phik, vpt, st);
    prefix_scan<<<dim3(64, 65), blk, 0, stream>>>(st, stbf);
    causal_fused<<<dim3(4096), dim3(64), 0, stream>>>(phiq, phik, vpt, stbf, attn);
    gemm_bf16<0><<<dim3(64, 8), blk, 0, stream>>>(attn, wob, bo, out);
}

// Round 9
// 347.117 us; speedup vs baseline: 5.3839x; 1.0927x over previous
//
#include <hip/hip_runtime.h>
#include <math.h>

// Dims: L=2048 N=4 E=1024 H=16 D=128 HD=64; 2D=256; M=L*N=8192; B=64
// phi natural (l,n,h,d) flat order == reference's scrambled (b,l',d) view.
// attn row mapping: flat l*4096 + b*64 + hd == (l*4+nb)*1024 + (h16*64+hd), b=nb*16+h16.
// Chunked causal: CHK=256, NC=8. Causal core: LDS-free fused kernel, XCD-grouped,
// 2-wave balanced blocks, den-inter via MFMA, ILP-split QK chain.

typedef unsigned short u16;
typedef unsigned int u32;
using f32x4v  = __attribute__((ext_vector_type(4))) float;
using f32x16v = __attribute__((ext_vector_type(16))) float;
using s16x8   = __attribute__((ext_vector_type(8))) short;

__device__ __forceinline__ float bf2f(u16 u) { return __uint_as_float(((u32)u) << 16); }
__device__ __forceinline__ u16 f2bf(float x) {
    u32 b = __float_as_uint(x);
    b += 0x7fff + ((b >> 16) & 1);          // RNE
    return (u16)(b >> 16);
}
__device__ __forceinline__ u32 cvtpk(float lo, float hi) {
    u32 r;
    asm("v_cvt_pk_bf16_f32 %0, %1, %2" : "=v"(r) : "v"(lo), "v"(hi));
    return r;
}
// async global->LDS, 16B per lane; LDS dest is wave-uniform base + lane*16
__device__ __forceinline__ void gload_lds16(const void* g, void* l) {
    __builtin_amdgcn_global_load_lds(
        (const __attribute__((address_space(1))) void*)g,
        (__attribute__((address_space(3))) void*)l, 16, 0, 0);
}

// ---------------------------------------------------------------------------
// f32 -> bf16 converters
__global__ __launch_bounds__(256) void cvt_x_bf16(
    const float* __restrict__ q, const float* __restrict__ k,
    const float* __restrict__ v, u16* __restrict__ dst)
{
    const float* src = (blockIdx.y == 0) ? q : (blockIdx.y == 1) ? k : v;
    u16* d = dst + (size_t)blockIdx.y * 8388608;
    const size_t i = ((size_t)blockIdx.x * 256 + threadIdx.x) * 8;
    const float4 a = *(const float4*)(src + i);
    const float4 b = *(const float4*)(src + i + 4);
    u16 o[8] = {f2bf(a.x), f2bf(a.y), f2bf(a.z), f2bf(a.w),
                f2bf(b.x), f2bf(b.y), f2bf(b.z), f2bf(b.w)};
    *(uint4*)(d + i) = *(uint4*)o;
}

__global__ __launch_bounds__(256) void cvt_w_bf16(
    const float* __restrict__ w0, const float* __restrict__ w1,
    const float* __restrict__ w2, const float* __restrict__ w3,
    u16* __restrict__ dst)
{
    const float* src = (blockIdx.y == 0) ? w0 : (blockIdx.y == 1) ? w1
                     : (blockIdx.y == 2) ? w2 : w3;
    u16* d = dst + (size_t)blockIdx.y * 1048576;
    const size_t i = ((size_t)blockIdx.x * 256 + threadIdx.x) * 8;
    const float4 a = *(const float4*)(src + i);
    const float4 b = *(const float4*)(src + i + 4);
    u16 o[8] = {f2bf(a.x), f2bf(a.y), f2bf(a.z), f2bf(a.w),
                f2bf(b.x), f2bf(b.y), f2bf(b.z), f2bf(b.w)};
    *(uint4*)(d + i) = *(uint4*)o;
}

// ---------------------------------------------------------------------------
// bf16 NT GEMM body (m97 structure, global_load_lds staging).
// C[m][n] = sum_k A[m][k]*B[n][k] + bias[n]; K=1024, 128x128 tile.
// OMODE: 0 = f32 row-major, 1 = bf16 row-major, 2 = bf16 vpt[(b*64+hd)*2048 + k]
template<int OMODE>
__device__ __forceinline__ void gemm_body(
    const u16* __restrict__ A, const u16* __restrict__ Bw,
    const float* __restrict__ bias, void* __restrict__ Cp,
    int m0, int n0, u16* As, u16* Bs)
{
    const int t = threadIdx.x;
    const int wid = t >> 6, lane = t & 63;
    const int wr = wid >> 1, wc = wid & 1;
    const int l15 = lane & 15, l4 = lane >> 4;

    f32x4v acc[4][4];
#pragma unroll
    for (int i = 0; i < 4; ++i)
#pragma unroll
        for (int j = 0; j < 4; ++j)
#pragma unroll
            for (int e = 0; e < 4; ++e) acc[i][j][e] = 0.f;

    const int srow = wid * 32 + (lane >> 2);
    const int scol = (lane & 3) * 8;
    const u16* ga0 = A  + (size_t)(m0 + srow) * 1024 + scol;
    const u16* ga1 = ga0 + 16 * 1024;
    const u16* gb0 = Bw + (size_t)(n0 + srow) * 1024 + scol;
    const u16* gb1 = gb0 + 16 * 1024;
    u16* la0 = &As[wid * 1024];
    u16* la1 = la0 + 512;
    u16* lb0 = &Bs[wid * 1024];
    u16* lb1 = lb0 + 512;

    for (int k0 = 0; k0 < 1024; k0 += 32) {
        __syncthreads();
        gload_lds16(ga0 + k0, la0);
        gload_lds16(ga1 + k0, la1);
        gload_lds16(gb0 + k0, lb0);
        gload_lds16(gb1 + k0, lb1);
        __syncthreads();
        s16x8 af[4], bfr[4];
#pragma unroll
        for (int fi = 0; fi < 4; ++fi)
            af[fi] = *(const s16x8*)&As[(wr * 64 + fi * 16 + l15) * 32 + l4 * 8];
#pragma unroll
        for (int fj = 0; fj < 4; ++fj)
            bfr[fj] = *(const s16x8*)&Bs[(wc * 64 + fj * 16 + l15) * 32 + l4 * 8];
#pragma unroll
        for (int fi = 0; fi < 4; ++fi)
#pragma unroll
            for (int fj = 0; fj < 4; ++fj)
                acc[fi][fj] = __builtin_amdgcn_mfma_f32_16x16x32_bf16(af[fi], bfr[fj], acc[fi][fj], 0, 0, 0);
    }

    const int rl = l4 * 4, cl = l15;
    float bvals[4];
#pragma unroll
    for (int fj = 0; fj < 4; ++fj) bvals[fj] = bias[n0 + wc * 64 + fj * 16 + cl];
#pragma unroll
    for (int fi = 0; fi < 4; ++fi)
#pragma unroll
        for (int j = 0; j < 4; ++j) {
            const size_t m = m0 + wr * 64 + fi * 16 + rl + j;
#pragma unroll
            for (int fj = 0; fj < 4; ++fj) {
                const int n = n0 + wc * 64 + fj * 16 + cl;
                const float v = acc[fi][fj][j] + bvals[fj];
                if (OMODE == 0)      ((float*)Cp)[m * 1024 + n] = v;
                else if (OMODE == 1) ((u16*)Cp)[m * 1024 + n] = f2bf(v);
                else {
                    // vpt[(b*64+hd)*2048 + k]; b=(m&3)*16+(n>>6), hd=n&63, k=m>>2
                    ((u16*)Cp)[((size_t)((m & 3) * 16 + (n >> 6)) * 64 + (n & 63)) * 2048 + (m >> 2)] = f2bf(v);
                }
            }
        }
}

template<int OMODE>
__global__ __launch_bounds__(256) void gemm_bf16(
    const u16* __restrict__ A, const u16* __restrict__ Bw,
    const float* __restrict__ bias, void* __restrict__ Cp)
{
    __shared__ __align__(16) u16 As[4096];
    __shared__ __align__(16) u16 Bs[4096];
    gemm_body<OMODE>(A, Bw, bias, Cp, blockIdx.x * 128, blockIdx.y * 128, As, Bs);
}

// Q and K projections in one launch (z selects)
__global__ __launch_bounds__(256) void gemm_qk(
    const u16* __restrict__ xq, const u16* __restrict__ wq, const float* __restrict__ bq, u16* __restrict__ qp,
    const u16* __restrict__ xk, const u16* __restrict__ wk, const float* __restrict__ bk, u16* __restrict__ kp)
{
    __shared__ __align__(16) u16 As[4096];
    __shared__ __align__(16) u16 Bs[4096];
    const bool isq = (blockIdx.z == 0);
    gemm_body<1>(isq ? xq : xk, isq ? wq : wk, isq ? bq : bk, isq ? (void*)qp : (void*)kp,
                 blockIdx.x * 128, blockIdx.y * 128, As, Bs);
}

// ---------------------------------------------------------------------------
// Random projection; X is bf16 (projected q/k); z selects q or k.
__global__ __launch_bounds__(256) void rand_project2(
    const u16* __restrict__ QP, const u16* __restrict__ KP,
    const float* __restrict__ RM, u16* __restrict__ PHIQ, u16* __restrict__ PHIK)
{
    const u16* X  = (blockIdx.z == 0) ? QP : KP;
    u16* PHI      = (blockIdx.z == 0) ? PHIQ : PHIK;
    __shared__ float Xs[64][68];
    __shared__ float RMs[128][68];
    __shared__ float rsc[64];
    const int h  = blockIdx.x;
    const int r0 = blockIdx.y * 64;
    const int t  = threadIdx.x;
#pragma unroll
    for (int i = 0; i < 2; ++i) {
        const int lin = t + i * 256;              // 512 = 64 rows x 8 col-octets
        const int r = lin >> 3, c8 = (lin & 7) * 8;
        const uint4 v = *(const uint4*)(X + (size_t)(r0 + r) * 1024 + h * 64 + c8);
        const u16* pv = (const u16*)&v;
#pragma unroll
        for (int e = 0; e < 8; ++e) Xs[r][c8 + e] = bf2f(pv[e]);
    }
#pragma unroll
    for (int i = 0; i < 32; ++i) {
        const int lin = t + i * 256;
        const int d = lin >> 6, c = lin & 63;
        RMs[d][c] = RM[((size_t)h * 128 + d) * 64 + c];
    }
    __syncthreads();
    if (t < 64) {
        float s = 0.f;
#pragma unroll
        for (int c = 0; c < 64; ++c) { const float v = Xs[t][c]; s += v * v; }
        rsc[t] = 1.f / fmaxf(sqrtf(s), 1e-12f);
    }
    __syncthreads();
    const int rr = (t >> 4) * 4;
    const int dc = t & 15;
    float acc[4][8];
#pragma unroll
    for (int i = 0; i < 4; ++i)
#pragma unroll
        for (int j = 0; j < 8; ++j) acc[i][j] = 0.f;
    for (int c = 0; c < 64; c += 4) {
        float4 xv[4], rv[8];
#pragma unroll
        for (int i = 0; i < 4; ++i) xv[i] = *(const float4*)&Xs[rr + i][c];
#pragma unroll
        for (int j = 0; j < 8; ++j) rv[j] = *(const float4*)&RMs[dc + 16 * j][c];
#pragma unroll
        for (int i = 0; i < 4; ++i)
#pragma unroll
            for (int j = 0; j < 8; ++j)
                acc[i][j] += xv[i].x*rv[j].x + xv[i].y*rv[j].y + xv[i].z*rv[j].z + xv[i].w*rv[j].w;
    }
#pragma unroll
    for (int i = 0; i < 4; ++i) {
        const float sc = rsc[rr + i];
        const size_t base = ((size_t)(r0 + rr + i) * 16 + h) * 256;
#pragma unroll
        for (int j = 0; j < 8; ++j) {
            const float xt = acc[i][j] * sc;
            const int d = dc + 16 * j;
            PHI[base + d]       = f2bf(0.0625f * expf(xt));
            PHI[base + 128 + d] = f2bf(0.0625f * expf(-xt));
        }
    }
}

// ---------------------------------------------------------------------------
// Chunk state via MFMA. Block (b, c, dh): OUT[m=h 0..63][n=d 0..127 of half dh]
__global__ __launch_bounds__(256) void chunk_state_mfma(
    const u16* __restrict__ PHIK, const u16* __restrict__ VPT, float* __restrict__ ST)
{
    __shared__ __align__(16) u16 Ks[64 * 136];
    __shared__ float zlds[16][132];
    const int b = blockIdx.x;
    const int c = blockIdx.y >> 1;
    const int dh = blockIdx.y & 1;
    const int t = threadIdx.x;
    const int wid = t >> 6, lane = t & 63;
    const int l15 = lane & 15, l4 = lane >> 4;
    const int wr = wid >> 1, wc = wid & 1;

    const size_t R0 = (size_t)b * 2048 + (size_t)c * 256;
    const int rgrp = t >> 4, d08 = (t & 15) * 8;

    float zpart[8];
#pragma unroll
    for (int i = 0; i < 8; ++i) zpart[i] = 0.f;

    f32x4v acc[2][4];
#pragma unroll
    for (int i = 0; i < 2; ++i)
#pragma unroll
        for (int j = 0; j < 4; ++j)
#pragma unroll
            for (int e = 0; e < 4; ++e) acc[i][j][e] = 0.f;

    for (int stage = 0; stage < 4; ++stage) {
        __syncthreads();
#pragma unroll
        for (int j = 0; j < 4; ++j) {
            const int r = rgrp + 16 * j;
            const uint4 v = *(const uint4*)(PHIK + (R0 + stage * 64 + r) * 256 + dh * 128 + d08);
            const int x = ((r >> 3) & 3) << 1;
            *(uint4*)&Ks[r * 136 + (((d08 >> 3) ^ x) << 3)] = v;
            const u16* pv = (const u16*)&v;
#pragma unroll
            for (int i = 0; i < 8; ++i) zpart[i] += bf2f(pv[i]);
        }
        __syncthreads();
#pragma unroll
        for (int ks = 0; ks < 2; ++ks) {
            const int xk = ((ks * 4 + l4) & 3) << 1;
            const int r0 = ks * 32 + l4 * 8;
            s16x8 af[2], bk[4];
#pragma unroll
            for (int fi = 0; fi < 2; ++fi) {
                const int h = wr * 32 + fi * 16 + l15;
                af[fi] = *(const s16x8*)(VPT + ((size_t)b * 64 + h) * 2048 + c * 256 + stage * 64 + ks * 32 + l4 * 8);
            }
#pragma unroll
            for (int fj = 0; fj < 4; ++fj) {
                const int d = wc * 64 + fj * 16 + l15;
                const int colk = (((d >> 3) ^ xk) << 3) + (d & 7);
#pragma unroll
                for (int e = 0; e < 8; ++e)
                    bk[fj][e] = (short)Ks[(r0 + e) * 136 + colk];
            }
#pragma unroll
            for (int fi = 0; fi < 2; ++fi)
#pragma unroll
                for (int fj = 0; fj < 4; ++fj)
                    acc[fi][fj] = __builtin_amdgcn_mfma_f32_16x16x32_bf16(af[fi], bk[fj], acc[fi][fj], 0, 0, 0);
        }
    }
    __syncthreads();
    *(float4*)&zlds[rgrp][d08]     = *(float4*)&zpart[0];
    *(float4*)&zlds[rgrp][d08 + 4] = *(float4*)&zpart[4];
    __syncthreads();
    float* st = ST + (size_t)(b * 8 + c) * 16640;
    if (t < 128) {
        float z = 0.f;
#pragma unroll
        for (int g = 0; g < 16; ++g) z += zlds[g][t];
        st[16384 + dh * 128 + t] = z;
    }
#pragma unroll
    for (int fi = 0; fi < 2; ++fi)
#pragma unroll
        for (int reg = 0; reg < 4; ++reg) {
            const int h = wr * 32 + fi * 16 + l4 * 4 + reg;
#pragma unroll
            for (int fj = 0; fj < 4; ++fj) {
                const int d = dh * 128 + wc * 64 + fj * 16 + l15;
                st[(size_t)h * 256 + d] = acc[fi][fj][reg];
            }
        }
}

// ---------------------------------------------------------------------------
// Exclusive prefix over 8 chunks -> bf16 stbf[(b*8+c)*16640 + e]
__global__ void prefix_scan(const float* __restrict__ ST, u16* __restrict__ STBF)
{
    const int b = blockIdx.x;
    const int e = blockIdx.y * 256 + threadIdx.x;
    if (e >= 16640) return;
    const size_t base = (size_t)b * 8 * 16640 + e;
    float run = 0.f;
#pragma unroll
    for (int c = 0; c < 8; ++c) {
        const float v = ST[base + (size_t)c * 16640];
        STBF[(size_t)(b * 8 + c) * 16640 + e] = f2bf(run);
        run += v;
    }
}

// ---------------------------------------------------------------------------
// Fused causal kernel. 2-wave blocks; wave w handles rf = pair (w=0) or 7-pair
// (w=1) -> every block = 9 kb-units (balanced). XCD-grouped: bid%8 = b-group.
// den_inter via MFMA (o2, z broadcast in B); QK chain ILP-split (2 accums).
__global__ __launch_bounds__(128) void causal_fused(
    const u16* __restrict__ PHIQ, const u16* __restrict__ PHIK,
    const u16* __restrict__ VPT, const u16* __restrict__ STBF,
    u16* __restrict__ ATT)
{
    const u32 bid = blockIdx.x;
    const int pair = (int)((bid >> 3) & 3);
    const int G  = (int)((bid >> 5) * 8 + (bid & 7));   // = c*64 + b
    const int b  = G & 63;
    const int c  = G >> 6;
    const int w  = threadIdx.x >> 6;
    const int rf = w ? (7 - pair) : pair;
    const int ri = rf >> 1, fi = rf & 1;
    const int lane = threadIdx.x & 63;
    const int l31 = lane & 31, s = lane >> 5;
    const size_t chunk0 = (size_t)b * 2048 + (size_t)c * 256;
    const u16* stb = STBF + (size_t)(b * 8 + c) * 16640;

    const int qc = ri * 64 + fi * 32 + l31;       // chunk-local q row
    s16x8 qf[16];
    const u16* qp = PHIQ + (chunk0 + qc) * 256 + s * 8;
#pragma unroll
    for (int ds = 0; ds < 16; ++ds)
        qf[ds] = *(const s16x8*)(qp + ds * 16);

    f32x16v o[2], o2;
#pragma unroll
    for (int e = 0; e < 16; ++e) { o[0][e] = 0.f; o[1][e] = 0.f; o2[e] = 0.f; }
    float den = 0.f;                              // intra rowsum only

    // ---- inter: o += Q.S^T ; o2 += Q.z (z broadcast -> den per D-row)
#pragma unroll
    for (int ds = 0; ds < 16; ++ds) {
        const s16x8 zf = *(const s16x8*)(stb + 16384 + ds * 16 + s * 8);
        o2 = __builtin_amdgcn_mfma_f32_32x32x16_bf16(qf[ds], zf, o2, 0, 0, 0);
#pragma unroll
        for (int fh = 0; fh < 2; ++fh) {
            const s16x8 sx = *(const s16x8*)(stb + (fh * 32 + l31) * 256 + ds * 16 + s * 8);
            o[fh] = __builtin_amdgcn_mfma_f32_32x32x16_bf16(qf[ds], sx, o[fh], 0, 0, 0);
        }
    }

    // ---- intra: swapped QK^T over 32-row k-blocks
    const int kbmax = ri * 2 + fi;
    for (int kb = 0; kb <= kbmax; ++kb) {
        s16x8 vf[2][2];
#pragma unroll
        for (int kh = 0; kh < 2; ++kh)
#pragma unroll
            for (int fh = 0; fh < 2; ++fh)
                vf[kh][fh] = *(const s16x8*)(VPT + ((size_t)b * 64 + fh * 32 + l31) * 2048
                                             + c * 256 + kb * 32 + kh * 16 + s * 8);
        // P^T = K . Q^T, 2 independent chains (depth 8 each)
        f32x16v p0, p1;
#pragma unroll
        for (int e = 0; e < 16; ++e) { p0[e] = 0.f; p1[e] = 0.f; }
        const u16* kptr = PHIK + (chunk0 + kb * 32 + l31) * 256 + s * 8;
#pragma unroll
        for (int ds = 0; ds < 8; ++ds) {
            const s16x8 kf0 = *(const s16x8*)(kptr + (2 * ds) * 16);
            const s16x8 kf1 = *(const s16x8*)(kptr + (2 * ds + 1) * 16);
            p0 = __builtin_amdgcn_mfma_f32_32x32x16_bf16(kf0, qf[2 * ds],     p0, 0, 0, 0);
            p1 = __builtin_amdgcn_mfma_f32_32x32x16_bf16(kf1, qf[2 * ds + 1], p1, 0, 0, 0);
        }
        f32x16v p;
#pragma unroll
        for (int e = 0; e < 16; ++e) p[e] = p0[e] + p1[e];

        const bool diag = (kb == kbmax);
        float rsum = 0.f;
#pragma unroll
        for (int reg = 0; reg < 16; ++reg) {
            if (diag) {
                const int kc = kb * 32 + (reg & 3) + 8 * (reg >> 2) + 4 * s;
                if (kc > qc) p[reg] = 0.f;
            }
            rsum += p[reg];
        }
        den += rsum;
        // pack to PV A-fragments: frag[kh] needs group g=2kh+s from both lane halves
#pragma unroll
        for (int kh = 0; kh < 2; ++kh) {
            const u32 pA_lo = cvtpk(p[8*kh + 0], p[8*kh + 1]);
            const u32 pA_hi = cvtpk(p[8*kh + 2], p[8*kh + 3]);
            const u32 pB_lo = cvtpk(p[8*kh + 4], p[8*kh + 5]);
            const u32 pB_hi = cvtpk(p[8*kh + 6], p[8*kh + 7]);
            const u32 X_lo = s ? pB_lo : pA_lo;
            const u32 X_hi = s ? pB_hi : pA_hi;
            const u32 Y_lo = s ? pA_lo : pB_lo;
            const u32 Y_hi = s ? pA_hi : pB_hi;
            const u32 sY_lo = __shfl_xor((int)Y_lo, 32);
            const u32 sY_hi = __shfl_xor((int)Y_hi, 32);
            u32 wq[4];
            wq[0] = s ? sY_lo : X_lo;
            wq[1] = s ? sY_hi : X_hi;
            wq[2] = s ? X_lo : sY_lo;
            wq[3] = s ? X_hi : sY_hi;
            s16x8 pa;
#pragma unroll
            for (int i = 0; i < 4; ++i) {
                pa[2*i]   = (short)(wq[i] & 0xffff);
                pa[2*i+1] = (short)(wq[i] >> 16);
            }
            o[0] = __builtin_amdgcn_mfma_f32_32x32x16_bf16(pa, vf[kh][0], o[0], 0, 0, 0);
            o[1] = __builtin_amdgcn_mfma_f32_32x32x16_bf16(pa, vf[kh][1], o[1], 0, 0, 0);
        }
    }

    // ---- epilogue: dv = den_inter (o2, already per-D-row) + den_intra (shfl)
    const float denT = den + __shfl_xor(den, 32);
#pragma unroll
    for (int reg = 0; reg < 16; ++reg) {
        const int q32 = (reg & 3) + 8 * (reg >> 2) + 4 * s;
        const float dv = o2[reg] + __shfl(denT, q32);
        const float inv = 1.f / (dv + 1e-6f);
        const int qrow = c * 256 + ri * 64 + fi * 32 + q32;
        const size_t abase = (size_t)qrow * 4096 + b * 64;
        ATT[abase + l31]      = f2bf(o[0][reg] * inv);
        ATT[abase + 32 + l31] = f2bf(o[1][reg] * inv);
    }
}

// ---------------------------------------------------------------------------
extern "C" void kernel_launch(void* const* d_in, const int* in_sizes, int n_in,
                              void* d_out, int out_size, void* d_ws, size_t ws_size,
                              hipStream_t stream)
{
    const float* query = (const float*)d_in[0];
    const float* key   = (const float*)d_in[1];
    const float* value = (const float*)d_in[2];
    const float* wq    = (const float*)d_in[3];
    const float* bq    = (const float*)d_in[4];
    const float* wk    = (const float*)d_in[5];
    const float* bk    = (const float*)d_in[6];
    const float* wv    = (const float*)d_in[7];
    const float* bv    = (const float*)d_in[8];
    const float* wo    = (const float*)d_in[9];
    const float* bo    = (const float*)d_in[10];
    const float* rm    = (const float*)d_in[11];
    float* out = (float*)d_out;

    // Workspace (226,754,560 B <= proven 235,929,600 B), overlays:
    //   qp (16M) -> vpt slot; kp (16M) -> stbf slot; st/attn -> xbf slot
    char* base = (char*)d_ws;
    u16*   phiq = (u16*)(base);                   //  67,108,864
    u16*   phik = (u16*)(base +  67108864);       //  67,108,864
    u16*   qp   = (u16*)(base + 134217728);       //  16,777,216 (-> vpt)
    u16*   vpt  = (u16*)(base + 134217728);
    u16*   kp   = (u16*)(base + 150994944);       //  16,777,216 (-> stbf 17,039,360)
    u16*   stbf = (u16*)(base + 150994944);
    u16*   xbf  = (u16*)(base + 168034304);       //  50,331,648 (q,k,v bf16)
    float* st   = (float*)(base + 168034304);     //  34,078,720 (overlay, after GEMMs)
    u16*   attn = (u16*)(base + 168034304);       //  16,777,216 (overlay, after prefix)
    u16*   wbf  = (u16*)(base + 218365952);       //   8,388,608 (4 weights bf16)

    u16* xq = xbf;
    u16* xk = xbf +  8388608;
    u16* xv = xbf + 16777216;
    u16* wqb = wbf;
    u16* wkb = wbf + 1048576;
    u16* wvb = wbf + 2097152;
    u16* wob = wbf + 3145728;

    const dim3 blk(256);
    cvt_x_bf16<<<dim3(4096, 3), blk, 0, stream>>>(query, key, value, xbf);
    cvt_w_bf16<<<dim3(512, 4), blk, 0, stream>>>(wq, wk, wv, wo, wbf);
    gemm_qk<<<dim3(64, 8, 2), blk, 0, stream>>>(xq, wqb, bq, qp, xk, wkb, bk, kp);
    rand_project2<<<dim3(16, 128, 2), blk, 0, stream>>>(qp, kp, rm, phiq, phik);
    gemm_bf16<2><<<dim3(64, 8), blk, 0, stream>>>(xv, wvb, bv, vpt);
    chunk_state_mfma<<<dim3(64, 16), blk, 0, stream>>>(phik, vpt, st);
    prefix_scan<<<dim3(64, 65), blk, 0, stream>>>(st, stbf);
    causal_fused<<<dim3(2048), dim3(128), 0, stream>>>(phiq, phik, vpt, stbf, attn);
    gemm_bf16<0><<<dim3(64, 8), blk, 0, stream>>>(attn, wob, bo, out);
}

// Round 10
// 291.306 us; speedup vs baseline: 6.4154x; 1.1916x over previous
//
#include <hip/hip_runtime.h>
#include <math.h>

// Dims: L=2048 N=4 E=1024 H=16 D=128 HD=64; 2D=256; M=L*N=8192; B=64
// phi natural (l,n,h,d) flat order == reference's scrambled (b,l',d) view.
// attn row mapping: flat l*4096 + b*64 + hd == (l*4+nb)*1024 + (h16*64+hd), b=nb*16+h16.
// Chunked causal: CHK=256, NC=8. Causal core: LDS-free fused kernel, XCD-grouped.
// rand_project: MFMA (x@rm^T), norms from staging partials, native exp2.

typedef unsigned short u16;
typedef unsigned int u32;
using f32x4v  = __attribute__((ext_vector_type(4))) float;
using f32x16v = __attribute__((ext_vector_type(16))) float;
using s16x8   = __attribute__((ext_vector_type(8))) short;

__device__ __forceinline__ float bf2f(u16 u) { return __uint_as_float(((u32)u) << 16); }
__device__ __forceinline__ u16 f2bf(float x) {
    u32 b = __float_as_uint(x);
    b += 0x7fff + ((b >> 16) & 1);          // RNE
    return (u16)(b >> 16);
}
__device__ __forceinline__ u32 cvtpk(float lo, float hi) {
    u32 r;
    asm("v_cvt_pk_bf16_f32 %0, %1, %2" : "=v"(r) : "v"(lo), "v"(hi));
    return r;
}
__device__ __forceinline__ float exp2f_hw(float x) {
    float r;
    asm("v_exp_f32 %0, %1" : "=v"(r) : "v"(x));
    return r;
}
// async global->LDS, 16B per lane; LDS dest is wave-uniform base + lane*16
__device__ __forceinline__ void gload_lds16(const void* g, void* l) {
    __builtin_amdgcn_global_load_lds(
        (const __attribute__((address_space(1))) void*)g,
        (__attribute__((address_space(3))) void*)l, 16, 0, 0);
}

// ---------------------------------------------------------------------------
// f32 -> bf16 converters
__global__ __launch_bounds__(256) void cvt_x_bf16(
    const float* __restrict__ q, const float* __restrict__ k,
    const float* __restrict__ v, u16* __restrict__ dst)
{
    const float* src = (blockIdx.y == 0) ? q : (blockIdx.y == 1) ? k : v;
    u16* d = dst + (size_t)blockIdx.y * 8388608;
    const size_t i = ((size_t)blockIdx.x * 256 + threadIdx.x) * 8;
    const float4 a = *(const float4*)(src + i);
    const float4 b = *(const float4*)(src + i + 4);
    u16 o[8] = {f2bf(a.x), f2bf(a.y), f2bf(a.z), f2bf(a.w),
                f2bf(b.x), f2bf(b.y), f2bf(b.z), f2bf(b.w)};
    *(uint4*)(d + i) = *(uint4*)o;
}

__global__ __launch_bounds__(256) void cvt_w_bf16(
    const float* __restrict__ w0, const float* __restrict__ w1,
    const float* __restrict__ w2, const float* __restrict__ w3,
    u16* __restrict__ dst)
{
    const float* src = (blockIdx.y == 0) ? w0 : (blockIdx.y == 1) ? w1
                     : (blockIdx.y == 2) ? w2 : w3;
    u16* d = dst + (size_t)blockIdx.y * 1048576;
    const size_t i = ((size_t)blockIdx.x * 256 + threadIdx.x) * 8;
    const float4 a = *(const float4*)(src + i);
    const float4 b = *(const float4*)(src + i + 4);
    u16 o[8] = {f2bf(a.x), f2bf(a.y), f2bf(a.z), f2bf(a.w),
                f2bf(b.x), f2bf(b.y), f2bf(b.z), f2bf(b.w)};
    *(uint4*)(d + i) = *(uint4*)o;
}

__global__ __launch_bounds__(256) void cvt_rm_bf16(
    const float* __restrict__ rm, u16* __restrict__ dst)
{
    const size_t i = ((size_t)blockIdx.x * 256 + threadIdx.x) * 8;
    const float4 a = *(const float4*)(rm + i);
    const float4 b = *(const float4*)(rm + i + 4);
    u16 o[8] = {f2bf(a.x), f2bf(a.y), f2bf(a.z), f2bf(a.w),
                f2bf(b.x), f2bf(b.y), f2bf(b.z), f2bf(b.w)};
    *(uint4*)(dst + i) = *(uint4*)o;
}

// ---------------------------------------------------------------------------
// bf16 NT GEMM body (m97 structure, global_load_lds staging).
// OMODE: 0 = f32 row-major, 1 = bf16 row-major, 2 = bf16 vpt[(b*64+hd)*2048 + k]
template<int OMODE>
__device__ __forceinline__ void gemm_body(
    const u16* __restrict__ A, const u16* __restrict__ Bw,
    const float* __restrict__ bias, void* __restrict__ Cp,
    int m0, int n0, u16* As, u16* Bs)
{
    const int t = threadIdx.x;
    const int wid = t >> 6, lane = t & 63;
    const int wr = wid >> 1, wc = wid & 1;
    const int l15 = lane & 15, l4 = lane >> 4;

    f32x4v acc[4][4];
#pragma unroll
    for (int i = 0; i < 4; ++i)
#pragma unroll
        for (int j = 0; j < 4; ++j)
#pragma unroll
            for (int e = 0; e < 4; ++e) acc[i][j][e] = 0.f;

    const int srow = wid * 32 + (lane >> 2);
    const int scol = (lane & 3) * 8;
    const u16* ga0 = A  + (size_t)(m0 + srow) * 1024 + scol;
    const u16* ga1 = ga0 + 16 * 1024;
    const u16* gb0 = Bw + (size_t)(n0 + srow) * 1024 + scol;
    const u16* gb1 = gb0 + 16 * 1024;
    u16* la0 = &As[wid * 1024];
    u16* la1 = la0 + 512;
    u16* lb0 = &Bs[wid * 1024];
    u16* lb1 = lb0 + 512;

    for (int k0 = 0; k0 < 1024; k0 += 32) {
        __syncthreads();
        gload_lds16(ga0 + k0, la0);
        gload_lds16(ga1 + k0, la1);
        gload_lds16(gb0 + k0, lb0);
        gload_lds16(gb1 + k0, lb1);
        __syncthreads();
        s16x8 af[4], bfr[4];
#pragma unroll
        for (int fi = 0; fi < 4; ++fi)
            af[fi] = *(const s16x8*)&As[(wr * 64 + fi * 16 + l15) * 32 + l4 * 8];
#pragma unroll
        for (int fj = 0; fj < 4; ++fj)
            bfr[fj] = *(const s16x8*)&Bs[(wc * 64 + fj * 16 + l15) * 32 + l4 * 8];
#pragma unroll
        for (int fi = 0; fi < 4; ++fi)
#pragma unroll
            for (int fj = 0; fj < 4; ++fj)
                acc[fi][fj] = __builtin_amdgcn_mfma_f32_16x16x32_bf16(af[fi], bfr[fj], acc[fi][fj], 0, 0, 0);
    }

    const int rl = l4 * 4, cl = l15;
    float bvals[4];
#pragma unroll
    for (int fj = 0; fj < 4; ++fj) bvals[fj] = bias[n0 + wc * 64 + fj * 16 + cl];
#pragma unroll
    for (int fi = 0; fi < 4; ++fi)
#pragma unroll
        for (int j = 0; j < 4; ++j) {
            const size_t m = m0 + wr * 64 + fi * 16 + rl + j;
#pragma unroll
            for (int fj = 0; fj < 4; ++fj) {
                const int n = n0 + wc * 64 + fj * 16 + cl;
                const float v = acc[fi][fj][j] + bvals[fj];
                if (OMODE == 0)      ((float*)Cp)[m * 1024 + n] = v;
                else if (OMODE == 1) ((u16*)Cp)[m * 1024 + n] = f2bf(v);
                else {
                    // vpt[(b*64+hd)*2048 + k]; b=(m&3)*16+(n>>6), hd=n&63, k=m>>2
                    ((u16*)Cp)[((size_t)((m & 3) * 16 + (n >> 6)) * 64 + (n & 63)) * 2048 + (m >> 2)] = f2bf(v);
                }
            }
        }
}

template<int OMODE>
__global__ __launch_bounds__(256) void gemm_bf16(
    const u16* __restrict__ A, const u16* __restrict__ Bw,
    const float* __restrict__ bias, void* __restrict__ Cp)
{
    __shared__ __align__(16) u16 As[4096];
    __shared__ __align__(16) u16 Bs[4096];
    gemm_body<OMODE>(A, Bw, bias, Cp, blockIdx.x * 128, blockIdx.y * 128, As, Bs);
}

// Q and K projections in one launch (z selects)
__global__ __launch_bounds__(256) void gemm_qk(
    const u16* __restrict__ xq, const u16* __restrict__ wq, const float* __restrict__ bq, u16* __restrict__ qp,
    const u16* __restrict__ xk, const u16* __restrict__ wk, const float* __restrict__ bk, u16* __restrict__ kp)
{
    __shared__ __align__(16) u16 As[4096];
    __shared__ __align__(16) u16 Bs[4096];
    const bool isq = (blockIdx.z == 0);
    gemm_body<1>(isq ? xq : xk, isq ? wq : wk, isq ? bq : bk, isq ? (void*)qp : (void*)kp,
                 blockIdx.x * 128, blockIdx.y * 128, As, Bs);
}

// ---------------------------------------------------------------------------
// Random projection via MFMA. Block (h, rb of 128 rows, z = q/k).
// xt[128 r][128 d] = X[r][h-slice] @ rm[h]^T; norms from staging partials;
// phi = exp2(+-xt*rsl - 4), rsl = log2e/||x||.
__global__ __launch_bounds__(256) void rand_project_mfma(
    const u16* __restrict__ QP, const u16* __restrict__ KP,
    const u16* __restrict__ RMB, u16* __restrict__ PHIQ, u16* __restrict__ PHIK)
{
    const u16* X  = (blockIdx.z == 0) ? QP : KP;
    u16* PHI      = (blockIdx.z == 0) ? PHIQ : PHIK;
    __shared__ __align__(16) u16 Xs[128 * 72];
    __shared__ __align__(16) u16 RMs[128 * 72];
    __shared__ float rsl_lds[128];
    const int h  = blockIdx.x;
    const int r0 = blockIdx.y * 128;
    const int t  = threadIdx.x;
    const int w  = t >> 6, lane = t & 63;
    const int l15 = lane & 15, l4 = lane >> 4;

    // stage X slice [128 rows][64 c] + per-row sq partials; stage rm[h] [128 d][64 c]
    float sq[4];
#pragma unroll
    for (int i = 0; i < 4; ++i) {
        const int lin = t + i * 256;              // 1024 = 128 x 8 octets
        const int row = lin >> 3, oct = lin & 7;
        const uint4 xv = *(const uint4*)(X + (size_t)(r0 + row) * 1024 + h * 64 + oct * 8);
        *(uint4*)&Xs[row * 72 + oct * 8] = xv;
        const u16* pv = (const u16*)&xv;
        float s = 0.f;
#pragma unroll
        for (int e = 0; e < 8; ++e) { const float f = bf2f(pv[e]); s += f * f; }
        sq[i] = s;
        const uint4 rv = *(const uint4*)(RMB + (size_t)h * 8192 + lin * 8);
        *(uint4*)&RMs[row * 72 + oct * 8] = rv;
    }
    // reduce 8 octet-partials per row (8 consecutive threads share a row)
#pragma unroll
    for (int i = 0; i < 4; ++i) {
        sq[i] += __shfl_xor(sq[i], 1);
        sq[i] += __shfl_xor(sq[i], 2);
        sq[i] += __shfl_xor(sq[i], 4);
        if ((t & 7) == 0)
            rsl_lds[(t >> 3) + i * 32] = 1.4426950408889634f / fmaxf(sqrtf(sq[i]), 1e-12f);
    }
    __syncthreads();

    // MFMA: wave w -> rows (w>>1)*64, d-cols (w&1)*64
    const int wr = (w >> 1) * 64, wc = (w & 1) * 64;
    f32x4v acc[4][4];
#pragma unroll
    for (int i = 0; i < 4; ++i)
#pragma unroll
        for (int j = 0; j < 4; ++j)
#pragma unroll
            for (int e = 0; e < 4; ++e) acc[i][j][e] = 0.f;
#pragma unroll
    for (int ks = 0; ks < 2; ++ks) {
        s16x8 af[4], bfr[4];
#pragma unroll
        for (int fi = 0; fi < 4; ++fi)
            af[fi] = *(const s16x8*)&Xs[(wr + fi * 16 + l15) * 72 + ks * 32 + l4 * 8];
#pragma unroll
        for (int fj = 0; fj < 4; ++fj)
            bfr[fj] = *(const s16x8*)&RMs[(wc + fj * 16 + l15) * 72 + ks * 32 + l4 * 8];
#pragma unroll
        for (int fi = 0; fi < 4; ++fi)
#pragma unroll
            for (int fj = 0; fj < 4; ++fj)
                acc[fi][fj] = __builtin_amdgcn_mfma_f32_16x16x32_bf16(af[fi], bfr[fj], acc[fi][fj], 0, 0, 0);
    }

    // epilogue: phi = exp2(+-xt*rsl - 4)
#pragma unroll
    for (int fi = 0; fi < 4; ++fi)
#pragma unroll
        for (int reg = 0; reg < 4; ++reg) {
            const int row = wr + fi * 16 + l4 * 4 + reg;
            const float rsl = rsl_lds[row];
            const size_t base = ((size_t)(r0 + row) * 16 + h) * 256;
#pragma unroll
            for (int fj = 0; fj < 4; ++fj) {
                const int d = wc + fj * 16 + l15;
                const float arg = acc[fi][fj][reg] * rsl;
                PHI[base + d]       = f2bf(exp2f_hw(arg - 4.f));
                PHI[base + 128 + d] = f2bf(exp2f_hw(-arg - 4.f));
            }
        }
}

// ---------------------------------------------------------------------------
// Chunk state via MFMA. Block (b, c, dh): OUT[m=h 0..63][n=d 0..127 of half dh]
__global__ __launch_bounds__(256) void chunk_state_mfma(
    const u16* __restrict__ PHIK, const u16* __restrict__ VPT, float* __restrict__ ST)
{
    __shared__ __align__(16) u16 Ks[64 * 136];
    __shared__ float zlds[16][132];
    const int b = blockIdx.x;
    const int c = blockIdx.y >> 1;
    const int dh = blockIdx.y & 1;
    const int t = threadIdx.x;
    const int wid = t >> 6, lane = t & 63;
    const int l15 = lane & 15, l4 = lane >> 4;
    const int wr = wid >> 1, wc = wid & 1;

    const size_t R0 = (size_t)b * 2048 + (size_t)c * 256;
    const int rgrp = t >> 4, d08 = (t & 15) * 8;

    float zpart[8];
#pragma unroll
    for (int i = 0; i < 8; ++i) zpart[i] = 0.f;

    f32x4v acc[2][4];
#pragma unroll
    for (int i = 0; i < 2; ++i)
#pragma unroll
        for (int j = 0; j < 4; ++j)
#pragma unroll
            for (int e = 0; e < 4; ++e) acc[i][j][e] = 0.f;

    for (int stage = 0; stage < 4; ++stage) {
        __syncthreads();
#pragma unroll
        for (int j = 0; j < 4; ++j) {
            const int r = rgrp + 16 * j;
            const uint4 v = *(const uint4*)(PHIK + (R0 + stage * 64 + r) * 256 + dh * 128 + d08);
            const int x = ((r >> 3) & 3) << 1;
            *(uint4*)&Ks[r * 136 + (((d08 >> 3) ^ x) << 3)] = v;
            const u16* pv = (const u16*)&v;
#pragma unroll
            for (int i = 0; i < 8; ++i) zpart[i] += bf2f(pv[i]);
        }
        __syncthreads();
#pragma unroll
        for (int ks = 0; ks < 2; ++ks) {
            const int xk = ((ks * 4 + l4) & 3) << 1;
            const int r0 = ks * 32 + l4 * 8;
            s16x8 af[2], bk[4];
#pragma unroll
            for (int fi = 0; fi < 2; ++fi) {
                const int h = wr * 32 + fi * 16 + l15;
                af[fi] = *(const s16x8*)(VPT + ((size_t)b * 64 + h) * 2048 + c * 256 + stage * 64 + ks * 32 + l4 * 8);
            }
#pragma unroll
            for (int fj = 0; fj < 4; ++fj) {
                const int d = wc * 64 + fj * 16 + l15;
                const int colk = (((d >> 3) ^ xk) << 3) + (d & 7);
#pragma unroll
                for (int e = 0; e < 8; ++e)
                    bk[fj][e] = (short)Ks[(r0 + e) * 136 + colk];
            }
#pragma unroll
            for (int fi = 0; fi < 2; ++fi)
#pragma unroll
                for (int fj = 0; fj < 4; ++fj)
                    acc[fi][fj] = __builtin_amdgcn_mfma_f32_16x16x32_bf16(af[fi], bk[fj], acc[fi][fj], 0, 0, 0);
        }
    }
    __syncthreads();
    *(float4*)&zlds[rgrp][d08]     = *(float4*)&zpart[0];
    *(float4*)&zlds[rgrp][d08 + 4] = *(float4*)&zpart[4];
    __syncthreads();
    float* st = ST + (size_t)(b * 8 + c) * 16640;
    if (t < 128) {
        float z = 0.f;
#pragma unroll
        for (int g = 0; g < 16; ++g) z += zlds[g][t];
        st[16384 + dh * 128 + t] = z;
    }
#pragma unroll
    for (int fi = 0; fi < 2; ++fi)
#pragma unroll
        for (int reg = 0; reg < 4; ++reg) {
            const int h = wr * 32 + fi * 16 + l4 * 4 + reg;
#pragma unroll
            for (int fj = 0; fj < 4; ++fj) {
                const int d = dh * 128 + wc * 64 + fj * 16 + l15;
                st[(size_t)h * 256 + d] = acc[fi][fj][reg];
            }
        }
}

// ---------------------------------------------------------------------------
// Exclusive prefix over 8 chunks -> bf16 stbf[(b*8+c)*16640 + e]
__global__ void prefix_scan(const float* __restrict__ ST, u16* __restrict__ STBF)
{
    const int b = blockIdx.x;
    const int e = blockIdx.y * 256 + threadIdx.x;
    if (e >= 16640) return;
    const size_t base = (size_t)b * 8 * 16640 + e;
    float run = 0.f;
#pragma unroll
    for (int c = 0; c < 8; ++c) {
        const float v = ST[base + (size_t)c * 16640];
        STBF[(size_t)(b * 8 + c) * 16640 + e] = f2bf(run);
        run += v;
    }
}

// ---------------------------------------------------------------------------
// Fused causal kernel. 2-wave blocks; wave w handles rf = pair / 7-pair
// (balanced 9 kb-units/block). XCD-grouped: bid%8 = b-group.
__global__ __launch_bounds__(128) void causal_fused(
    const u16* __restrict__ PHIQ, const u16* __restrict__ PHIK,
    const u16* __restrict__ VPT, const u16* __restrict__ STBF,
    u16* __restrict__ ATT)
{
    const u32 bid = blockIdx.x;
    const int pair = (int)((bid >> 3) & 3);
    const int G  = (int)((bid >> 5) * 8 + (bid & 7));   // = c*64 + b
    const int b  = G & 63;
    const int c  = G >> 6;
    const int w  = threadIdx.x >> 6;
    const int rf = w ? (7 - pair) : pair;
    const int ri = rf >> 1, fi = rf & 1;
    const int lane = threadIdx.x & 63;
    const int l31 = lane & 31, s = lane >> 5;
    const size_t chunk0 = (size_t)b * 2048 + (size_t)c * 256;
    const u16* stb = STBF + (size_t)(b * 8 + c) * 16640;

    const int qc = ri * 64 + fi * 32 + l31;
    s16x8 qf[16];
    const u16* qp = PHIQ + (chunk0 + qc) * 256 + s * 8;
#pragma unroll
    for (int ds = 0; ds < 16; ++ds)
        qf[ds] = *(const s16x8*)(qp + ds * 16);

    f32x16v o[2], o2;
#pragma unroll
    for (int e = 0; e < 16; ++e) { o[0][e] = 0.f; o[1][e] = 0.f; o2[e] = 0.f; }
    float den = 0.f;

    // ---- inter: o += Q.S^T ; o2 += Q.z (den per D-row)
#pragma unroll
    for (int ds = 0; ds < 16; ++ds) {
        const s16x8 zf = *(const s16x8*)(stb + 16384 + ds * 16 + s * 8);
        o2 = __builtin_amdgcn_mfma_f32_32x32x16_bf16(qf[ds], zf, o2, 0, 0, 0);
#pragma unroll
        for (int fh = 0; fh < 2; ++fh) {
            const s16x8 sx = *(const s16x8*)(stb + (fh * 32 + l31) * 256 + ds * 16 + s * 8);
            o[fh] = __builtin_amdgcn_mfma_f32_32x32x16_bf16(qf[ds], sx, o[fh], 0, 0, 0);
        }
    }

    // ---- intra: swapped QK^T over 32-row k-blocks
    const int kbmax = ri * 2 + fi;
    for (int kb = 0; kb <= kbmax; ++kb) {
        s16x8 vf[2][2];
#pragma unroll
        for (int kh = 0; kh < 2; ++kh)
#pragma unroll
            for (int fh = 0; fh < 2; ++fh)
                vf[kh][fh] = *(const s16x8*)(VPT + ((size_t)b * 64 + fh * 32 + l31) * 2048
                                             + c * 256 + kb * 32 + kh * 16 + s * 8);
        f32x16v p0, p1;
#pragma unroll
        for (int e = 0; e < 16; ++e) { p0[e] = 0.f; p1[e] = 0.f; }
        const u16* kptr = PHIK + (chunk0 + kb * 32 + l31) * 256 + s * 8;
#pragma unroll
        for (int ds = 0; ds < 8; ++ds) {
            const s16x8 kf0 = *(const s16x8*)(kptr + (2 * ds) * 16);
            const s16x8 kf1 = *(const s16x8*)(kptr + (2 * ds + 1) * 16);
            p0 = __builtin_amdgcn_mfma_f32_32x32x16_bf16(kf0, qf[2 * ds],     p0, 0, 0, 0);
            p1 = __builtin_amdgcn_mfma_f32_32x32x16_bf16(kf1, qf[2 * ds + 1], p1, 0, 0, 0);
        }
        f32x16v p;
#pragma unroll
        for (int e = 0; e < 16; ++e) p[e] = p0[e] + p1[e];

        const bool diag = (kb == kbmax);
        float rsum = 0.f;
#pragma unroll
        for (int reg = 0; reg < 16; ++reg) {
            if (diag) {
                const int kc = kb * 32 + (reg & 3) + 8 * (reg >> 2) + 4 * s;
                if (kc > qc) p[reg] = 0.f;
            }
            rsum += p[reg];
        }
        den += rsum;
#pragma unroll
        for (int kh = 0; kh < 2; ++kh) {
            const u32 pA_lo = cvtpk(p[8*kh + 0], p[8*kh + 1]);
            const u32 pA_hi = cvtpk(p[8*kh + 2], p[8*kh + 3]);
            const u32 pB_lo = cvtpk(p[8*kh + 4], p[8*kh + 5]);
            const u32 pB_hi = cvtpk(p[8*kh + 6], p[8*kh + 7]);
            const u32 X_lo = s ? pB_lo : pA_lo;
            const u32 X_hi = s ? pB_hi : pA_hi;
            const u32 Y_lo = s ? pA_lo : pB_lo;
            const u32 Y_hi = s ? pA_hi : pB_hi;
            const u32 sY_lo = __shfl_xor((int)Y_lo, 32);
            const u32 sY_hi = __shfl_xor((int)Y_hi, 32);
            u32 wq[4];
            wq[0] = s ? sY_lo : X_lo;
            wq[1] = s ? sY_hi : X_hi;
            wq[2] = s ? X_lo : sY_lo;
            wq[3] = s ? X_hi : sY_hi;
            s16x8 pa;
#pragma unroll
            for (int i = 0; i < 4; ++i) {
                pa[2*i]   = (short)(wq[i] & 0xffff);
                pa[2*i+1] = (short)(wq[i] >> 16);
            }
            o[0] = __builtin_amdgcn_mfma_f32_32x32x16_bf16(pa, vf[kh][0], o[0], 0, 0, 0);
            o[1] = __builtin_amdgcn_mfma_f32_32x32x16_bf16(pa, vf[kh][1], o[1], 0, 0, 0);
        }
    }

    // ---- epilogue
    const float denT = den + __shfl_xor(den, 32);
#pragma unroll
    for (int reg = 0; reg < 16; ++reg) {
        const int q32 = (reg & 3) + 8 * (reg >> 2) + 4 * s;
        const float dv = o2[reg] + __shfl(denT, q32);
        const float inv = 1.f / (dv + 1e-6f);
        const int qrow = c * 256 + ri * 64 + fi * 32 + q32;
        const size_t abase = (size_t)qrow * 4096 + b * 64;
        ATT[abase + l31]      = f2bf(o[0][reg] * inv);
        ATT[abase + 32 + l31] = f2bf(o[1][reg] * inv);
    }
}

// ---------------------------------------------------------------------------
extern "C" void kernel_launch(void* const* d_in, const int* in_sizes, int n_in,
                              void* d_out, int out_size, void* d_ws, size_t ws_size,
                              hipStream_t stream)
{
    const float* query = (const float*)d_in[0];
    const float* key   = (const float*)d_in[1];
    const float* value = (const float*)d_in[2];
    const float* wq    = (const float*)d_in[3];
    const float* bq    = (const float*)d_in[4];
    const float* wk    = (const float*)d_in[5];
    const float* bk    = (const float*)d_in[6];
    const float* wv    = (const float*)d_in[7];
    const float* bv    = (const float*)d_in[8];
    const float* wo    = (const float*)d_in[9];
    const float* bo    = (const float*)d_in[10];
    const float* rm    = (const float*)d_in[11];
    float* out = (float*)d_out;

    // Workspace (227,016,704 B <= proven 235,929,600 B), overlays:
    //   qp (16M) -> vpt slot; kp (16M) -> stbf slot; st/attn -> xbf slot
    char* base = (char*)d_ws;
    u16*   phiq = (u16*)(base);                   //  67,108,864
    u16*   phik = (u16*)(base +  67108864);       //  67,108,864
    u16*   qp   = (u16*)(base + 134217728);       //  16,777,216 (-> vpt)
    u16*   vpt  = (u16*)(base + 134217728);
    u16*   kp   = (u16*)(base + 150994944);       //  16,777,216 (-> stbf 17,039,360)
    u16*   stbf = (u16*)(base + 150994944);
    u16*   xbf  = (u16*)(base + 168034304);       //  50,331,648 (q,k,v bf16)
    float* st   = (float*)(base + 168034304);     //  34,078,720 (overlay, after GEMMs)
    u16*   attn = (u16*)(base + 168034304);       //  16,777,216 (overlay, after prefix)
    u16*   wbf  = (u16*)(base + 218365952);       //   8,388,608 (4 weights bf16)
    u16*   rmb  = (u16*)(base + 226754560);       //     262,144 (rm bf16)

    u16* xq = xbf;
    u16* xk = xbf +  8388608;
    u16* xv = xbf + 16777216;
    u16* wqb = wbf;
    u16* wkb = wbf + 1048576;
    u16* wvb = wbf + 2097152;
    u16* wob = wbf + 3145728;

    const dim3 blk(256);
    cvt_x_bf16<<<dim3(4096, 3), blk, 0, stream>>>(query, key, value, xbf);
    cvt_w_bf16<<<dim3(512, 4), blk, 0, stream>>>(wq, wk, wv, wo, wbf);
    cvt_rm_bf16<<<dim3(64), blk, 0, stream>>>(rm, rmb);
    gemm_qk<<<dim3(64, 8, 2), blk, 0, stream>>>(xq, wqb, bq, qp, xk, wkb, bk, kp);
    rand_project_mfma<<<dim3(16, 64, 2), blk, 0, stream>>>(qp, kp, rmb, phiq, phik);
    gemm_bf16<2><<<dim3(64, 8), blk, 0, stream>>>(xv, wvb, bv, vpt);
    chunk_state_mfma<<<dim3(64, 16), blk, 0, stream>>>(phik, vpt, st);
    prefix_scan<<<dim3(64, 65), blk, 0, stream>>>(st, stbf);
    causal_fused<<<dim3(2048), dim3(128), 0, stream>>>(phiq, phik, vpt, stbf, attn);
    gemm_bf16<0><<<dim3(64, 8), blk, 0, stream>>>(attn, wob, bo, out);
}